// Round 1
// 554.520 us; speedup vs baseline: 1.3934x; 1.3934x over previous
//
#include <hip/hip_runtime.h>
#include <math.h>

// Problem constants
#define BB   2
#define SS   2048
#define DD   1024
#define HH   16
#define DH   64
#define CBS  32
#define STRIDEC 16
#define NBLK 127          // (S - CBS)/STRIDE + 1
#define NSEL 16
#define WIN  16
#define NW   33           // 2*WIN+1
#define SCALE 0.125f      // DH^-0.5
#define MC   254          // BB * NBLK

typedef _Float16 f16;
typedef __attribute__((ext_vector_type(8))) _Float16 f16x8;
typedef __attribute__((ext_vector_type(4))) _Float16 f16x4;
typedef __attribute__((ext_vector_type(4))) float f32x4;

// ---------------------------------------------------------------------------
// fp32 -> f16 elementwise convert (float4 loads, 4 elems/thread)
// ---------------------------------------------------------------------------
__global__ __launch_bounds__(256) void convert_f16(
    const float* __restrict__ src, f16* __restrict__ dst, int n)
{
    const int i = (blockIdx.x * 256 + threadIdx.x) * 4;
    if (i >= n) return;
    float4 v = *(const float4*)(src + i);
    f16x4 o;
    o[0] = (f16)v.x; o[1] = (f16)v.y; o[2] = (f16)v.z; o[3] = (f16)v.w;
    *(f16x4*)(dst + i) = o;
}

// ---------------------------------------------------------------------------
// fp32 (K x N) -> f16 (N x K) transpose-convert, 32x32 LDS tiles
// ---------------------------------------------------------------------------
__global__ __launch_bounds__(256) void transpose_conv(
    const float* __restrict__ src, f16* __restrict__ dst, int K, int N)
{
    __shared__ float t[32][33];
    const int n0 = blockIdx.x * 32, k0 = blockIdx.y * 32;
    const int tx = threadIdx.x & 31, ty = threadIdx.x >> 5;   // 32 x 8
#pragma unroll
    for (int r = 0; r < 32; r += 8)
        t[ty + r][tx] = src[(size_t)(k0 + ty + r) * N + n0 + tx];
    __syncthreads();
#pragma unroll
    for (int r = 0; r < 32; r += 8)
        dst[(size_t)(n0 + ty + r) * K + k0 + tx] = (f16)t[tx][ty + r];
}

// ---------------------------------------------------------------------------
// f16 MFMA GEMM, m97-style: 128x128 tile, BK=64, 4 waves (2x2), each wave
// 64x64 via 4x4 frags of 16x16x32.  A: M x K f16 row-major.  Bt: N x K f16
// row-major (B transposed).  C: M x N fp32 (+bias).  M,N % 128 == 0.
// ---------------------------------------------------------------------------
__global__ __launch_bounds__(256) void gemm_f16(
    const f16* __restrict__ A, const f16* __restrict__ Bt,
    const float* __restrict__ bias, float* __restrict__ C,
    int M, int N, int K)
{
    constexpr int BK = 64;
    __shared__ f16 As[128 * BK];
    __shared__ f16 Bs[128 * BK];
    const int tid  = threadIdx.x;
    const int wid  = tid >> 6, lane = tid & 63;
    const int bm = blockIdx.y * 128, bn = blockIdx.x * 128;
    const int wm = (wid >> 1) * 64, wn = (wid & 1) * 64;

    const int lrow = lane >> 3;        // 0..7 (row within 8-row segment)
    const int lk8  = (lane & 7) * 8;   // k-element offset of this lane's 16B

    f32x4 acc[4][4];
#pragma unroll
    for (int i = 0; i < 4; ++i)
#pragma unroll
        for (int j = 0; j < 4; ++j) acc[i][j] = (f32x4){0.f, 0.f, 0.f, 0.f};

    for (int kt = 0; kt < K; kt += BK) {
#pragma unroll
        for (int c = 0; c < 4; ++c) {
            const int seg = c * 4 + wid;            // 0..15 -> rows seg*8..+8
            const int row = seg * 8 + lrow;
            const f16* ga = A + (size_t)(bm + row) * K + kt + lk8;
            __builtin_amdgcn_global_load_lds(
                (const __attribute__((address_space(1))) void*)(const void*)ga,
                (__attribute__((address_space(3))) void*)(void*)(As + seg * 512),
                16, 0, 0);
            const f16* gb = Bt + (size_t)(bn + row) * K + kt + lk8;
            __builtin_amdgcn_global_load_lds(
                (const __attribute__((address_space(1))) void*)(const void*)gb,
                (__attribute__((address_space(3))) void*)(void*)(Bs + seg * 512),
                16, 0, 0);
        }
        __syncthreads();   // compiler drains vmcnt before s_barrier

#pragma unroll
        for (int kk = 0; kk < 2; ++kk) {
            const int ko = kk * 32 + (lane >> 4) * 8;
            f16x8 a[4], b[4];
#pragma unroll
            for (int i = 0; i < 4; ++i)
                a[i] = *(const f16x8*)(As + (wm + i * 16 + (lane & 15)) * BK + ko);
#pragma unroll
            for (int j = 0; j < 4; ++j)
                b[j] = *(const f16x8*)(Bs + (wn + j * 16 + (lane & 15)) * BK + ko);
#pragma unroll
            for (int i = 0; i < 4; ++i)
#pragma unroll
                for (int j = 0; j < 4; ++j)
                    acc[i][j] = __builtin_amdgcn_mfma_f32_16x16x32_f16(
                        a[i], b[j], acc[i][j], 0, 0, 0);
        }
        __syncthreads();
    }

    const int rr0 = (lane >> 4) * 4;
    const int cc  = lane & 15;
#pragma unroll
    for (int i = 0; i < 4; ++i) {
        const int r = bm + wm + i * 16 + rr0;
#pragma unroll
        for (int j = 0; j < 4; ++j) {
            const int cn = bn + wn + j * 16 + cc;
            const float bv = bias[cn];
#pragma unroll
            for (int q = 0; q < 4; ++q)
                C[(size_t)(r + q) * N + cn] = acc[i][j][q] + bv;
        }
    }
}

// ---------------------------------------------------------------------------
// c1 compression GEMM in f16 MFMA with fp32 split-K accumulate.
// Logical A: (256 x 32768) gathered from xh: row m -> (b=m/127, blk=m%127),
// element k -> x row (b*2048 + blk*16 + (k>>10)), col (k&1023).
// B: WTc1 f16 (1024 x 32768) = c1_w transposed.  Tiles 128x64, BK=64,
// split-K NZ=16 -> partials P[z][254][1024] fp32 (bias+relu in reduce).
// Grid (16, 2, 16) = 512 WGs -> 2 WG/CU (fixes the 1-wave/SIMD occupancy
// hole the fp32 version had).
// ---------------------------------------------------------------------------
#define C1_NZ 16
#define C1_KCHUNK 2048     // 32768 / 16

__global__ __launch_bounds__(256) void gemm_c1(
    const f16* __restrict__ xh, const f16* __restrict__ Wt,
    float* __restrict__ P)
{
    constexpr int BK = 64;
    __shared__ f16 As[128 * BK];   // 16 KB
    __shared__ f16 Bs[64 * BK];    //  8 KB
    const int tid  = threadIdx.x;
    const int wid  = tid >> 6, lane = tid & 63;
    const int bn = blockIdx.x * 64, bm = blockIdx.y * 128;
    const int z  = blockIdx.z;
    const int wm = (wid >> 1) * 64, wn = (wid & 1) * 32;

    const int lrow = lane >> 3;
    const int lk8  = (lane & 7) * 8;

    f32x4 acc[4][2];
#pragma unroll
    for (int i = 0; i < 4; ++i)
#pragma unroll
        for (int j = 0; j < 2; ++j) acc[i][j] = (f32x4){0.f, 0.f, 0.f, 0.f};

    for (int t = 0; t < C1_KCHUNK / BK; ++t) {
        const int ktg = z * C1_KCHUNK + t * BK;
        const int kc  = (ktg + lk8) >> 10;       // x feature-row within block
        const int kd  = (ktg + lk8) & 1023;      // x col
        // stage A: 16 segments of 8 rows x 128B, gathered rows of xh
#pragma unroll
        for (int c = 0; c < 4; ++c) {
            const int seg = c * 4 + wid;
            int row = bm + seg * 8 + lrow;
            if (row > MC - 1) row = MC - 1;       // pad rows 254/255 (dup, unstored)
            const int b   = (row >= NBLK) ? 1 : 0;
            const int blk = row - b * NBLK;
            const f16* ga = xh + ((size_t)(b * SS + blk * STRIDEC + kc) << 10) + kd;
            __builtin_amdgcn_global_load_lds(
                (const __attribute__((address_space(1))) void*)(const void*)ga,
                (__attribute__((address_space(3))) void*)(void*)(As + seg * 512),
                16, 0, 0);
        }
        // stage B: 8 segments (2 per wave)
#pragma unroll
        for (int c = 0; c < 2; ++c) {
            const int seg = wid * 2 + c;
            const int row = bn + seg * 8 + lrow;
            const f16* gb = Wt + (size_t)row * (CBS * DD) + ktg + lk8;
            __builtin_amdgcn_global_load_lds(
                (const __attribute__((address_space(1))) void*)(const void*)gb,
                (__attribute__((address_space(3))) void*)(void*)(Bs + seg * 512),
                16, 0, 0);
        }
        __syncthreads();

#pragma unroll
        for (int kk = 0; kk < 2; ++kk) {
            const int ko = kk * 32 + (lane >> 4) * 8;
            f16x8 a[4], b[2];
#pragma unroll
            for (int i = 0; i < 4; ++i)
                a[i] = *(const f16x8*)(As + (wm + i * 16 + (lane & 15)) * BK + ko);
#pragma unroll
            for (int j = 0; j < 2; ++j)
                b[j] = *(const f16x8*)(Bs + (wn + j * 16 + (lane & 15)) * BK + ko);
#pragma unroll
            for (int i = 0; i < 4; ++i)
#pragma unroll
                for (int j = 0; j < 2; ++j)
                    acc[i][j] = __builtin_amdgcn_mfma_f32_16x16x32_f16(
                        a[i], b[j], acc[i][j], 0, 0, 0);
        }
        __syncthreads();
    }

    // store fp32 partials (no bias/relu here)
    const int rr0 = (lane >> 4) * 4;
    const int cc  = lane & 15;
#pragma unroll
    for (int i = 0; i < 4; ++i) {
        const int r = bm + wm + i * 16 + rr0;
#pragma unroll
        for (int j = 0; j < 2; ++j) {
            const int cn = bn + wn + j * 16 + cc;
#pragma unroll
            for (int q = 0; q < 4; ++q)
                if (r + q < MC)
                    P[((size_t)z * MC + r + q) * DD + cn] = acc[i][j][q];
        }
    }
}

// ---------------------------------------------------------------------------
// fp32 tiled GEMM 128x128 (unchanged) — used for the small fp32-exact
// kernels: c2 (MODE 0) and sqkv (MODE 2).
// ---------------------------------------------------------------------------
template<int MODE>
__global__ __launch_bounds__(256) void gemm128(
    const float* __restrict__ A, const float* __restrict__ Bm,
    const float* __restrict__ bias, float* __restrict__ C,
    int M, int N, int K, const int* __restrict__ selIdx, int flags)
{
    __shared__ float As[8][132];
    __shared__ float Bs[8][132];

    const int tid = threadIdx.x;
    const int bm = blockIdx.y * 128;
    const int bn = blockIdx.x * 128;
    const int nz = gridDim.z;
    const int z  = blockIdx.z;
    const int kchunk = K / nz;
    const int k0 = z * kchunk;
    const int kend = k0 + kchunk;

    const int tx = tid & 15;
    const int ty = tid >> 4;

    const int arow = tid >> 1;
    const int akq  = (tid & 1) * 4;
    const int bkr  = tid >> 5;
    const int bcol = (tid & 31) * 4;

    float acc[2][2][4][4];
#pragma unroll
    for (int qi = 0; qi < 2; ++qi)
#pragma unroll
        for (int qj = 0; qj < 2; ++qj)
#pragma unroll
            for (int i = 0; i < 4; ++i)
#pragma unroll
                for (int j = 0; j < 4; ++j) acc[qi][qj][i][j] = 0.f;

    auto loadA = [&](int kt) -> float4 {
        float4 av = make_float4(0.f, 0.f, 0.f, 0.f);
        const int grow = bm + arow;
        if (grow < M) {
            if constexpr (MODE == 0) {
                av = *(const float4*)(A + (size_t)grow * K + kt + akq);
            } else {
                const int b = grow >> 4;
                const int j = grow & 15;
                const int idx = selIdx[b * NSEL + j];
                av = *(const float4*)(A + (size_t)(b * NBLK + idx) * K + kt + akq);
            }
        }
        return av;
    };
    auto loadB = [&](int kt) -> float4 {
        return *(const float4*)(Bm + (size_t)(kt + bkr) * N + bn + bcol);
    };

    float4 av = loadA(k0);
    float4 bv = loadB(k0);

    for (int kt = k0; kt < kend; kt += 8) {
        As[akq + 0][arow] = av.x;
        As[akq + 1][arow] = av.y;
        As[akq + 2][arow] = av.z;
        As[akq + 3][arow] = av.w;
        *(float4*)&Bs[bkr][bcol] = bv;
        __syncthreads();
        if (kt + 8 < kend) {
            av = loadA(kt + 8);
            bv = loadB(kt + 8);
        }
#pragma unroll
        for (int k = 0; k < 8; ++k) {
            const float4 a0 = *(const float4*)&As[k][ty * 4];
            const float4 a1 = *(const float4*)&As[k][64 + ty * 4];
            const float4 b0 = *(const float4*)&Bs[k][tx * 4];
            const float4 b1 = *(const float4*)&Bs[k][64 + tx * 4];
            const float ar[2][4] = {{a0.x, a0.y, a0.z, a0.w},
                                    {a1.x, a1.y, a1.z, a1.w}};
            const float br[2][4] = {{b0.x, b0.y, b0.z, b0.w},
                                    {b1.x, b1.y, b1.z, b1.w}};
#pragma unroll
            for (int qi = 0; qi < 2; ++qi)
#pragma unroll
                for (int i = 0; i < 4; ++i)
#pragma unroll
                    for (int qj = 0; qj < 2; ++qj)
#pragma unroll
                        for (int j = 0; j < 4; ++j)
                            acc[qi][qj][i][j] += ar[qi][i] * br[qj][j];
        }
        __syncthreads();
    }

    if (nz == 1) {
        const bool hasB   = (flags & 1) != 0;
        const bool doRelu = (flags & 2) != 0;
#pragma unroll
        for (int qi = 0; qi < 2; ++qi)
#pragma unroll
            for (int i = 0; i < 4; ++i) {
                const int r = bm + qi * 64 + ty * 4 + i;
                if (r >= M) continue;
#pragma unroll
                for (int qj = 0; qj < 2; ++qj)
#pragma unroll
                    for (int j = 0; j < 4; ++j) {
                        const int cn = bn + qj * 64 + tx * 4 + j;
                        float v = acc[qi][qj][i][j];
                        if (hasB) v += bias[cn];
                        if (doRelu) v = fmaxf(v, 0.f);
                        C[(size_t)r * N + cn] = v;
                    }
            }
    } else {
        float* P = C + (size_t)z * M * N;
#pragma unroll
        for (int qi = 0; qi < 2; ++qi)
#pragma unroll
            for (int i = 0; i < 4; ++i) {
                const int r = bm + qi * 64 + ty * 4 + i;
                if (r >= M) continue;
#pragma unroll
                for (int qj = 0; qj < 2; ++qj)
#pragma unroll
                    for (int j = 0; j < 4; ++j) {
                        const int cn = bn + qj * 64 + tx * 4 + j;
                        P[(size_t)r * N + cn] = acc[qi][qj][i][j];
                    }
            }
    }
}

// Sum split-K partials + bias (+relu)
__global__ __launch_bounds__(256) void reduce_partials(
    const float* __restrict__ P, const float* __restrict__ bias,
    float* __restrict__ outp, int MN, int N, int nz, int doRelu)
{
    const int i = blockIdx.x * 256 + threadIdx.x;
    if (i >= MN) return;
    float s = 0.f;
    for (int z = 0; z < nz; ++z) s += P[(size_t)z * MN + i];
    s += bias[i % N];
    if (doRelu) s = fmaxf(s, 0.f);
    outp[i] = s;
}

// scores[row] = compressed[row,:] . score_w + score_b
__global__ __launch_bounds__(256) void score_kernel(
    const float* __restrict__ comp, const float* __restrict__ sw,
    const float* __restrict__ sb, float* __restrict__ scores)
{
    const int row = blockIdx.x;
    const float* cp = comp + (size_t)row * DD;
    float s = 0.f;
    for (int k = threadIdx.x; k < DD; k += 256) s += cp[k] * sw[k];
#pragma unroll
    for (int off = 32; off >= 1; off >>= 1) s += __shfl_xor(s, off);
    __shared__ float red[4];
    if ((threadIdx.x & 63) == 0) red[threadIdx.x >> 6] = s;
    __syncthreads();
    if (threadIdx.x == 0) scores[row] = red[0] + red[1] + red[2] + red[3] + sb[0];
}

// top-16 of 127 scores per batch (set semantics; lowest-index tie-break)
__global__ __launch_bounds__(128) void topk_kernel(
    const float* __restrict__ scores, int* __restrict__ top)
{
    const int b = blockIdx.x;
    const int t = threadIdx.x;  // 128
    __shared__ float sval[128];
    __shared__ float sv2[128];
    __shared__ int   si2[128];
    __shared__ unsigned char used[128];
    sval[t] = (t < NBLK) ? scores[b * NBLK + t] : -INFINITY;
    used[t] = 0;
    __syncthreads();
    for (int j = 0; j < NSEL; ++j) {
        sv2[t] = used[t] ? -INFINITY : sval[t];
        si2[t] = t;
        __syncthreads();
        for (int stp = 64; stp >= 1; stp >>= 1) {
            if (t < stp) {
                if (sv2[t + stp] > sv2[t] ||
                    (sv2[t + stp] == sv2[t] && si2[t + stp] < si2[t])) {
                    sv2[t] = sv2[t + stp];
                    si2[t] = si2[t + stp];
                }
            }
            __syncthreads();
        }
        if (t == 0) { top[b * NSEL + j] = si2[0]; used[si2[0]] = 1; }
        __syncthreads();
    }
}

// One wave per query: local window attention (33 pos) + global selected (16).
// Emits f16 directly (feeds the f16 MFMA out-projection GEMM).
__global__ __launch_bounds__(256) void attn_kernel(
    const float* __restrict__ qkv, const float* __restrict__ sqkv,
    f16* __restrict__ attn)
{
    const int wid  = threadIdx.x >> 6;
    const int lane = threadIdx.x & 63;
    const int qg = blockIdx.x * 4 + wid;         // 0 .. B*H*S-1
    const int s  = qg & (SS - 1);
    const int bh = qg >> 11;
    const int h  = bh & (HH - 1);
    const int b  = bh >> 4;

    __shared__ float qs[4][64];
    const size_t rowQ = (size_t)(b * SS + s) * (3 * DD);
    qs[wid][lane] = qkv[rowQ + h * DH + lane];
    __syncthreads();

    // ---- local window ----
    float sc = -INFINITY;
    const int pos = s - WIN + lane;
    if (lane < NW && pos >= 0 && pos < SS) {
        const float* kp = qkv + (size_t)(b * SS + pos) * (3 * DD) + DD + h * DH;
        float a = 0.f;
#pragma unroll
        for (int d = 0; d < DH; ++d) a += qs[wid][d] * kp[d];
        sc = a * SCALE;
    }
    float m = sc;
#pragma unroll
    for (int off = 32; off >= 1; off >>= 1) m = fmaxf(m, __shfl_xor(m, off));
    float p = (sc == -INFINITY) ? 0.f : expf(sc - m);
    float sum = p;
#pragma unroll
    for (int off = 32; off >= 1; off >>= 1) sum += __shfl_xor(sum, off);
    p /= sum;

    float outd = 0.f;
#pragma unroll
    for (int w = 0; w < NW; ++w) {
        const float pw = __shfl(p, w);
        const int pw_pos = s - WIN + w;
        if (pw_pos >= 0 && pw_pos < SS)
            outd += pw * qkv[(size_t)(b * SS + pw_pos) * (3 * DD) + 2 * DD + h * DH + lane];
    }

    // ---- global selected ----
    float sc2 = -INFINITY;
    if (lane < NSEL) {
        const float* kp = sqkv + (size_t)(b * NSEL + lane) * (3 * DD) + DD + h * DH;
        float a = 0.f;
#pragma unroll
        for (int d = 0; d < DH; ++d) a += qs[wid][d] * kp[d];
        sc2 = a * SCALE;
    }
    float m2 = sc2;
#pragma unroll
    for (int off = 32; off >= 1; off >>= 1) m2 = fmaxf(m2, __shfl_xor(m2, off));
    float p2 = (lane < NSEL) ? expf(sc2 - m2) : 0.f;
    float sum2 = p2;
#pragma unroll
    for (int off = 32; off >= 1; off >>= 1) sum2 += __shfl_xor(sum2, off);
    p2 /= sum2;
    float outg = 0.f;
#pragma unroll
    for (int kk = 0; kk < NSEL; ++kk) {
        const float pk = __shfl(p2, kk);
        outg += pk * sqkv[(size_t)(b * NSEL + kk) * (3 * DD) + 2 * DD + h * DH + lane];
    }

    attn[(size_t)(b * SS + s) * DD + h * DH + lane] = (f16)(outd + outg);
}

extern "C" void kernel_launch(void* const* d_in, const int* in_sizes, int n_in,
                              void* d_out, int out_size, void* d_ws, size_t ws_size,
                              hipStream_t stream)
{
    const float* x       = (const float*)d_in[0];
    const float* qkv_w   = (const float*)d_in[1];
    const float* qkv_b   = (const float*)d_in[2];
    const float* c1_w    = (const float*)d_in[3];
    const float* c1_b    = (const float*)d_in[4];
    const float* c2_w    = (const float*)d_in[5];
    const float* c2_b    = (const float*)d_in[6];
    const float* score_w = (const float*)d_in[7];
    const float* score_b = (const float*)d_in[8];
    const float* out_w   = (const float*)d_in[9];
    const float* out_b   = (const float*)d_in[10];
    float* out = (float*)d_out;
    float* ws  = (float*)d_ws;

    // workspace layout (float units) — total 23,654,720 floats (same as prev)
    // [0]         xh      2,097,152   x as f16 (4096x1024), lives all session
    // [A1]        WTc1   16,777,216   c1_w^T f16 (phase A)
    //             -> qkvb 12,582,912 + attnf16 2,097,152 (phase B, aliased)
    // [A2]        c1 partials 4,161,536 (16x254x1024)  /  c2 partials (8x..)
    //             -> qkv_wT 1,572,864 + out_wT 524,288 (phase B, aliased)
    // [tail]      hidden, comp, scores, topIdx, sqkvb
    f16*   xh     = (f16*)ws;
    float* A1     = ws + 2097152;
    f16*   WTc1   = (f16*)A1;
    float* qkvb   = A1;
    f16*   attnf  = (f16*)(A1 + 12582912);
    float* A2     = ws + 18874368;
    float* part   = A2;
    f16*   qkv_wT = (f16*)A2;
    f16*   out_wT = (f16*)(A2 + 1572864);
    float* hidden = ws + 23035904;
    float* comp   = hidden + 260096;
    float* scores = comp + 260096;
    int*   topIdx = (int*)(scores + 256);
    float* sqkvb  = scores + 256 + 64;

    const int MROWS = BB * SS;        // 4096

    // 0. x -> f16 (serves c1 A-gather, qkv GEMM A)
    convert_f16<<<(MROWS * DD) / (256 * 4), 256, 0, stream>>>(x, xh, MROWS * DD);

    // 1. c1_w (32768 x 1024) -> f16 transposed (1024 x 32768)
    transpose_conv<<<dim3(DD / 32, CBS * DD / 32), 256, 0, stream>>>(
        c1_w, WTc1, CBS * DD, DD);

    // 2. c1: hidden partials via f16 MFMA, split-K 16  (was 335 us in fp32)
    gemm_c1<<<dim3(DD / 64, 2, C1_NZ), 256, 0, stream>>>(xh, WTc1, part);

    // 3. hidden = relu(sum partials + c1_b)
    reduce_partials<<<(MC * DD) / 256, 256, 0, stream>>>(
        part, c1_b, hidden, MC * DD, DD, C1_NZ, 1);

    // 4. c2 partials: hidden @ c2_w (254x1024, K=1024, split-K 8) [fp32 exact]
    gemm128<0><<<dim3(DD / 128, 2, 8), 256, 0, stream>>>(
        hidden, c2_w, nullptr, part, MC, DD, DD, nullptr, 0);

    // 5. compressed = sum partials + c2_b
    reduce_partials<<<(MC * DD) / 256, 256, 0, stream>>>(
        part, c2_b, comp, MC * DD, DD, 8, 0);

    // 6. scores
    score_kernel<<<MC, 256, 0, stream>>>(comp, score_w, score_b, scores);

    // 7. top-16 per batch
    topk_kernel<<<BB, 128, 0, stream>>>(scores, topIdx);

    // 8. sqkv = selected @ qkv_w + qkv_b  (32 x 3072, K=1024) [fp32, tiny]
    gemm128<2><<<dim3(3 * DD / 128, 1, 1), 256, 0, stream>>>(
        comp, qkv_w, qkv_b, sqkvb, BB * NSEL, 3 * DD, DD, topIdx, 1);

    // 9. weight transposes for the f16 MFMA GEMMs (A2 partials now dead)
    transpose_conv<<<dim3(3 * DD / 32, DD / 32), 256, 0, stream>>>(
        qkv_w, qkv_wT, DD, 3 * DD);
    transpose_conv<<<dim3(DD / 32, DD / 32), 256, 0, stream>>>(
        out_w, out_wT, DD, DD);

    // 10. qkv = x @ qkv_w + qkv_b (4096 x 3072, K=1024) [f16 MFMA]
    //     (overwrites WTc1 region — dead after step 2)
    gemm_f16<<<dim3(3 * DD / 128, MROWS / 128), 256, 0, stream>>>(
        xh, qkv_wT, qkv_b, qkvb, MROWS, 3 * DD, DD);

    // 11. attention (local window + global selected) -> f16 directly
    attn_kernel<<<BB * HH * SS / 4, 256, 0, stream>>>(qkvb, sqkvb, attnf);

    // 12. out = attn @ out_w + out_b  (4096 x 1024, K=1024) [f16 MFMA]
    gemm_f16<<<dim3(DD / 128, MROWS / 128), 256, 0, stream>>>(
        attnf, out_wT, out_b, out, MROWS, DD, DD);
}

// Round 2
// 479.890 us; speedup vs baseline: 1.6101x; 1.1555x over previous
//
#include <hip/hip_runtime.h>
#include <math.h>

// Problem constants
#define BB   2
#define SS   2048
#define DD   1024
#define HH   16
#define DH   64
#define CBS  32
#define STRIDEC 16
#define NBLK 127          // (S - CBS)/STRIDE + 1
#define NSEL 16
#define WIN  16
#define NW   33           // 2*WIN+1
#define SCALE 0.125f      // DH^-0.5
#define MC   254          // BB * NBLK

typedef _Float16 f16;
typedef __attribute__((ext_vector_type(8))) _Float16 f16x8;
typedef __attribute__((ext_vector_type(4))) _Float16 f16x4;
typedef __attribute__((ext_vector_type(4))) float f32x4;

// ---------------------------------------------------------------------------
// fp32 -> f16 elementwise convert (float4 loads, 4 elems/thread)
// ---------------------------------------------------------------------------
__global__ __launch_bounds__(256) void convert_f16(
    const float* __restrict__ src, f16* __restrict__ dst, int n)
{
    const int i = (blockIdx.x * 256 + threadIdx.x) * 4;
    if (i >= n) return;
    float4 v = *(const float4*)(src + i);
    f16x4 o;
    o[0] = (f16)v.x; o[1] = (f16)v.y; o[2] = (f16)v.z; o[3] = (f16)v.w;
    *(f16x4*)(dst + i) = o;
}

// ---------------------------------------------------------------------------
// fp32 (K x N) -> f16 (N x K) transpose-convert, 32x32 LDS tiles
// ---------------------------------------------------------------------------
__global__ __launch_bounds__(256) void transpose_conv(
    const float* __restrict__ src, f16* __restrict__ dst, int K, int N)
{
    __shared__ float t[32][33];
    const int n0 = blockIdx.x * 32, k0 = blockIdx.y * 32;
    const int tx = threadIdx.x & 31, ty = threadIdx.x >> 5;   // 32 x 8
#pragma unroll
    for (int r = 0; r < 32; r += 8)
        t[ty + r][tx] = src[(size_t)(k0 + ty + r) * N + n0 + tx];
    __syncthreads();
#pragma unroll
    for (int r = 0; r < 32; r += 8)
        dst[(size_t)(n0 + ty + r) * K + k0 + tx] = (f16)t[tx][ty + r];
}

// ---------------------------------------------------------------------------
// f16 MFMA GEMM, m97-style: 128x128 tile, BK=64, 4 waves (2x2), each wave
// 64x64 via 4x4 frags of 16x16x32.  A: M x K f16 row-major.  Bt: N x K f16
// row-major (B transposed).  C: M x N fp32 (+bias).  M,N % 128 == 0.
// ---------------------------------------------------------------------------
__global__ __launch_bounds__(256) void gemm_f16(
    const f16* __restrict__ A, const f16* __restrict__ Bt,
    const float* __restrict__ bias, float* __restrict__ C,
    int M, int N, int K)
{
    constexpr int BK = 64;
    __shared__ f16 As[128 * BK];
    __shared__ f16 Bs[128 * BK];
    const int tid  = threadIdx.x;
    const int wid  = tid >> 6, lane = tid & 63;
    const int bm = blockIdx.y * 128, bn = blockIdx.x * 128;
    const int wm = (wid >> 1) * 64, wn = (wid & 1) * 64;

    const int lrow = lane >> 3;        // 0..7 (row within 8-row segment)
    const int lk8  = (lane & 7) * 8;   // k-element offset of this lane's 16B

    f32x4 acc[4][4];
#pragma unroll
    for (int i = 0; i < 4; ++i)
#pragma unroll
        for (int j = 0; j < 4; ++j) acc[i][j] = (f32x4){0.f, 0.f, 0.f, 0.f};

    for (int kt = 0; kt < K; kt += BK) {
#pragma unroll
        for (int c = 0; c < 4; ++c) {
            const int seg = c * 4 + wid;            // 0..15 -> rows seg*8..+8
            const int row = seg * 8 + lrow;
            const f16* ga = A + (size_t)(bm + row) * K + kt + lk8;
            __builtin_amdgcn_global_load_lds(
                (const __attribute__((address_space(1))) void*)(const void*)ga,
                (__attribute__((address_space(3))) void*)(void*)(As + seg * 512),
                16, 0, 0);
            const f16* gb = Bt + (size_t)(bn + row) * K + kt + lk8;
            __builtin_amdgcn_global_load_lds(
                (const __attribute__((address_space(1))) void*)(const void*)gb,
                (__attribute__((address_space(3))) void*)(void*)(Bs + seg * 512),
                16, 0, 0);
        }
        __syncthreads();   // compiler drains vmcnt before s_barrier

#pragma unroll
        for (int kk = 0; kk < 2; ++kk) {
            const int ko = kk * 32 + (lane >> 4) * 8;
            f16x8 a[4], b[4];
#pragma unroll
            for (int i = 0; i < 4; ++i)
                a[i] = *(const f16x8*)(As + (wm + i * 16 + (lane & 15)) * BK + ko);
#pragma unroll
            for (int j = 0; j < 4; ++j)
                b[j] = *(const f16x8*)(Bs + (wn + j * 16 + (lane & 15)) * BK + ko);
#pragma unroll
            for (int i = 0; i < 4; ++i)
#pragma unroll
                for (int j = 0; j < 4; ++j)
                    acc[i][j] = __builtin_amdgcn_mfma_f32_16x16x32_f16(
                        a[i], b[j], acc[i][j], 0, 0, 0);
        }
        __syncthreads();
    }

    const int rr0 = (lane >> 4) * 4;
    const int cc  = lane & 15;
#pragma unroll
    for (int i = 0; i < 4; ++i) {
        const int r = bm + wm + i * 16 + rr0;
#pragma unroll
        for (int j = 0; j < 4; ++j) {
            const int cn = bn + wn + j * 16 + cc;
            const float bv = bias[cn];
#pragma unroll
            for (int q = 0; q < 4; ++q)
                C[(size_t)(r + q) * N + cn] = acc[i][j][q] + bv;
        }
    }
}

// ---------------------------------------------------------------------------
// c1 compression GEMM in f16 MFMA with fp32 split-K accumulate.
// ---------------------------------------------------------------------------
#define C1_NZ 16
#define C1_KCHUNK 2048     // 32768 / 16

__global__ __launch_bounds__(256) void gemm_c1(
    const f16* __restrict__ xh, const f16* __restrict__ Wt,
    float* __restrict__ P)
{
    constexpr int BK = 64;
    __shared__ f16 As[128 * BK];   // 16 KB
    __shared__ f16 Bs[64 * BK];    //  8 KB
    const int tid  = threadIdx.x;
    const int wid  = tid >> 6, lane = tid & 63;
    const int bn = blockIdx.x * 64, bm = blockIdx.y * 128;
    const int z  = blockIdx.z;
    const int wm = (wid >> 1) * 64, wn = (wid & 1) * 32;

    const int lrow = lane >> 3;
    const int lk8  = (lane & 7) * 8;

    f32x4 acc[4][2];
#pragma unroll
    for (int i = 0; i < 4; ++i)
#pragma unroll
        for (int j = 0; j < 2; ++j) acc[i][j] = (f32x4){0.f, 0.f, 0.f, 0.f};

    for (int t = 0; t < C1_KCHUNK / BK; ++t) {
        const int ktg = z * C1_KCHUNK + t * BK;
        const int kc  = (ktg + lk8) >> 10;       // x feature-row within block
        const int kd  = (ktg + lk8) & 1023;      // x col
#pragma unroll
        for (int c = 0; c < 4; ++c) {
            const int seg = c * 4 + wid;
            int row = bm + seg * 8 + lrow;
            if (row > MC - 1) row = MC - 1;       // pad rows 254/255 (dup, unstored)
            const int b   = (row >= NBLK) ? 1 : 0;
            const int blk = row - b * NBLK;
            const f16* ga = xh + ((size_t)(b * SS + blk * STRIDEC + kc) << 10) + kd;
            __builtin_amdgcn_global_load_lds(
                (const __attribute__((address_space(1))) void*)(const void*)ga,
                (__attribute__((address_space(3))) void*)(void*)(As + seg * 512),
                16, 0, 0);
        }
#pragma unroll
        for (int c = 0; c < 2; ++c) {
            const int seg = wid * 2 + c;
            const int row = bn + seg * 8 + lrow;
            const f16* gb = Wt + (size_t)row * (CBS * DD) + ktg + lk8;
            __builtin_amdgcn_global_load_lds(
                (const __attribute__((address_space(1))) void*)(const void*)gb,
                (__attribute__((address_space(3))) void*)(void*)(Bs + seg * 512),
                16, 0, 0);
        }
        __syncthreads();

#pragma unroll
        for (int kk = 0; kk < 2; ++kk) {
            const int ko = kk * 32 + (lane >> 4) * 8;
            f16x8 a[4], b[2];
#pragma unroll
            for (int i = 0; i < 4; ++i)
                a[i] = *(const f16x8*)(As + (wm + i * 16 + (lane & 15)) * BK + ko);
#pragma unroll
            for (int j = 0; j < 2; ++j)
                b[j] = *(const f16x8*)(Bs + (wn + j * 16 + (lane & 15)) * BK + ko);
#pragma unroll
            for (int i = 0; i < 4; ++i)
#pragma unroll
                for (int j = 0; j < 2; ++j)
                    acc[i][j] = __builtin_amdgcn_mfma_f32_16x16x32_f16(
                        a[i], b[j], acc[i][j], 0, 0, 0);
        }
        __syncthreads();
    }

    const int rr0 = (lane >> 4) * 4;
    const int cc  = lane & 15;
#pragma unroll
    for (int i = 0; i < 4; ++i) {
        const int r = bm + wm + i * 16 + rr0;
#pragma unroll
        for (int j = 0; j < 2; ++j) {
            const int cn = bn + wn + j * 16 + cc;
#pragma unroll
            for (int q = 0; q < 4; ++q)
                if (r + q < MC)
                    P[((size_t)z * MC + r + q) * DD + cn] = acc[i][j][q];
        }
    }
}

// ---------------------------------------------------------------------------
// fp32 tiled GEMM 128x128 — used for the small fp32-exact kernels:
// c2 (MODE 0) and sqkv (MODE 2).
// ---------------------------------------------------------------------------
template<int MODE>
__global__ __launch_bounds__(256) void gemm128(
    const float* __restrict__ A, const float* __restrict__ Bm,
    const float* __restrict__ bias, float* __restrict__ C,
    int M, int N, int K, const int* __restrict__ selIdx, int flags)
{
    __shared__ float As[8][132];
    __shared__ float Bs[8][132];

    const int tid = threadIdx.x;
    const int bm = blockIdx.y * 128;
    const int bn = blockIdx.x * 128;
    const int nz = gridDim.z;
    const int z  = blockIdx.z;
    const int kchunk = K / nz;
    const int k0 = z * kchunk;
    const int kend = k0 + kchunk;

    const int tx = tid & 15;
    const int ty = tid >> 4;

    const int arow = tid >> 1;
    const int akq  = (tid & 1) * 4;
    const int bkr  = tid >> 5;
    const int bcol = (tid & 31) * 4;

    float acc[2][2][4][4];
#pragma unroll
    for (int qi = 0; qi < 2; ++qi)
#pragma unroll
        for (int qj = 0; qj < 2; ++qj)
#pragma unroll
            for (int i = 0; i < 4; ++i)
#pragma unroll
                for (int j = 0; j < 4; ++j) acc[qi][qj][i][j] = 0.f;

    auto loadA = [&](int kt) -> float4 {
        float4 av = make_float4(0.f, 0.f, 0.f, 0.f);
        const int grow = bm + arow;
        if (grow < M) {
            if constexpr (MODE == 0) {
                av = *(const float4*)(A + (size_t)grow * K + kt + akq);
            } else {
                const int b = grow >> 4;
                const int j = grow & 15;
                const int idx = selIdx[b * NSEL + j];
                av = *(const float4*)(A + (size_t)(b * NBLK + idx) * K + kt + akq);
            }
        }
        return av;
    };
    auto loadB = [&](int kt) -> float4 {
        return *(const float4*)(Bm + (size_t)(kt + bkr) * N + bn + bcol);
    };

    float4 av = loadA(k0);
    float4 bv = loadB(k0);

    for (int kt = k0; kt < kend; kt += 8) {
        As[akq + 0][arow] = av.x;
        As[akq + 1][arow] = av.y;
        As[akq + 2][arow] = av.z;
        As[akq + 3][arow] = av.w;
        *(float4*)&Bs[bkr][bcol] = bv;
        __syncthreads();
        if (kt + 8 < kend) {
            av = loadA(kt + 8);
            bv = loadB(kt + 8);
        }
#pragma unroll
        for (int k = 0; k < 8; ++k) {
            const float4 a0 = *(const float4*)&As[k][ty * 4];
            const float4 a1 = *(const float4*)&As[k][64 + ty * 4];
            const float4 b0 = *(const float4*)&Bs[k][tx * 4];
            const float4 b1 = *(const float4*)&Bs[k][64 + tx * 4];
            const float ar[2][4] = {{a0.x, a0.y, a0.z, a0.w},
                                    {a1.x, a1.y, a1.z, a1.w}};
            const float br[2][4] = {{b0.x, b0.y, b0.z, b0.w},
                                    {b1.x, b1.y, b1.z, b1.w}};
#pragma unroll
            for (int qi = 0; qi < 2; ++qi)
#pragma unroll
                for (int i = 0; i < 4; ++i)
#pragma unroll
                    for (int qj = 0; qj < 2; ++qj)
#pragma unroll
                        for (int j = 0; j < 4; ++j)
                            acc[qi][qj][i][j] += ar[qi][i] * br[qj][j];
        }
        __syncthreads();
    }

    if (nz == 1) {
        const bool hasB   = (flags & 1) != 0;
        const bool doRelu = (flags & 2) != 0;
#pragma unroll
        for (int qi = 0; qi < 2; ++qi)
#pragma unroll
            for (int i = 0; i < 4; ++i) {
                const int r = bm + qi * 64 + ty * 4 + i;
                if (r >= M) continue;
#pragma unroll
                for (int qj = 0; qj < 2; ++qj)
#pragma unroll
                    for (int j = 0; j < 4; ++j) {
                        const int cn = bn + qj * 64 + tx * 4 + j;
                        float v = acc[qi][qj][i][j];
                        if (hasB) v += bias[cn];
                        if (doRelu) v = fmaxf(v, 0.f);
                        C[(size_t)r * N + cn] = v;
                    }
            }
    } else {
        float* P = C + (size_t)z * M * N;
#pragma unroll
        for (int qi = 0; qi < 2; ++qi)
#pragma unroll
            for (int i = 0; i < 4; ++i) {
                const int r = bm + qi * 64 + ty * 4 + i;
                if (r >= M) continue;
#pragma unroll
                for (int qj = 0; qj < 2; ++qj)
#pragma unroll
                    for (int j = 0; j < 4; ++j) {
                        const int cn = bn + qj * 64 + tx * 4 + j;
                        P[(size_t)r * N + cn] = acc[qi][qj][i][j];
                    }
            }
    }
}

// Sum split-K partials + bias (+relu)
__global__ __launch_bounds__(256) void reduce_partials(
    const float* __restrict__ P, const float* __restrict__ bias,
    float* __restrict__ outp, int MN, int N, int nz, int doRelu)
{
    const int i = blockIdx.x * 256 + threadIdx.x;
    if (i >= MN) return;
    float s = 0.f;
    for (int z = 0; z < nz; ++z) s += P[(size_t)z * MN + i];
    s += bias[i % N];
    if (doRelu) s = fmaxf(s, 0.f);
    outp[i] = s;
}

// scores[row] = compressed[row,:] . score_w + score_b
__global__ __launch_bounds__(256) void score_kernel(
    const float* __restrict__ comp, const float* __restrict__ sw,
    const float* __restrict__ sb, float* __restrict__ scores)
{
    const int row = blockIdx.x;
    const float* cp = comp + (size_t)row * DD;
    float s = 0.f;
    for (int k = threadIdx.x; k < DD; k += 256) s += cp[k] * sw[k];
#pragma unroll
    for (int off = 32; off >= 1; off >>= 1) s += __shfl_xor(s, off);
    __shared__ float red[4];
    if ((threadIdx.x & 63) == 0) red[threadIdx.x >> 6] = s;
    __syncthreads();
    if (threadIdx.x == 0) scores[row] = red[0] + red[1] + red[2] + red[3] + sb[0];
}

// top-16 of 127 scores per batch (set semantics; lowest-index tie-break)
__global__ __launch_bounds__(128) void topk_kernel(
    const float* __restrict__ scores, int* __restrict__ top)
{
    const int b = blockIdx.x;
    const int t = threadIdx.x;  // 128
    __shared__ float sval[128];
    __shared__ float sv2[128];
    __shared__ int   si2[128];
    __shared__ unsigned char used[128];
    sval[t] = (t < NBLK) ? scores[b * NBLK + t] : -INFINITY;
    used[t] = 0;
    __syncthreads();
    for (int j = 0; j < NSEL; ++j) {
        sv2[t] = used[t] ? -INFINITY : sval[t];
        si2[t] = t;
        __syncthreads();
        for (int stp = 64; stp >= 1; stp >>= 1) {
            if (t < stp) {
                if (sv2[t + stp] > sv2[t] ||
                    (sv2[t + stp] == sv2[t] && si2[t + stp] < si2[t])) {
                    sv2[t] = sv2[t + stp];
                    si2[t] = si2[t + stp];
                }
            }
            __syncthreads();
        }
        if (t == 0) { top[b * NSEL + j] = si2[0]; used[si2[0]] = 1; }
        __syncthreads();
    }
}

// ---------------------------------------------------------------------------
// Tiled attention: one workgroup per (b, h, 64-query tile).  K/V window
// (96 rows), Q tile, selected K/V all staged in LDS.  4 waves x 16 queries.
// Same arithmetic/masking as the per-query version; kills the 2.8x HBM
// over-fetch and the scalar-global-load latency chain.
// ---------------------------------------------------------------------------
#define QT 64
#define KROWS 96   // QT + 2*WIN

__global__ __launch_bounds__(256) void attn_tiled(
    const float* __restrict__ qkv, const float* __restrict__ sqkv,
    f16* __restrict__ attn)
{
    __shared__ float Ks[KROWS][65];   // +1 pad: per-lane row reads ~2-way
    __shared__ float Vs[KROWS][64];   // row-broadcast reads conflict-free
    __shared__ float Qs[QT][64];      // broadcast reads
    __shared__ float sKs[NSEL][65];
    __shared__ float sVs[NSEL][64];

    int bid = blockIdx.x;
    bid = (bid & 7) * (gridDim.x >> 3) + (bid >> 3);   // XCD chunk swizzle (1024%8==0)
    const int t = bid & 31;            // S/QT tiles
    const int h = (bid >> 5) & (HH - 1);
    const int b = bid >> 9;
    const int s0 = t * QT;

    const int tid = threadIdx.x;
    const int wid = tid >> 6, lane = tid & 63;

    // ---- stage K/V window rows (96 x 64 floats each) ----
    for (int i = tid; i < KROWS * 16; i += 256) {
        const int row = i >> 4;
        const int c4  = (i & 15) * 4;
        const int pos = s0 - WIN + row;
        float4 kv = make_float4(0.f, 0.f, 0.f, 0.f), vv = kv;
        if (pos >= 0 && pos < SS) {
            const float* base = qkv + (size_t)(b * SS + pos) * (3 * DD) + h * DH + c4;
            kv = *(const float4*)(base + DD);
            vv = *(const float4*)(base + 2 * DD);
        }
        *(float4*)&Ks[row][c4] = kv;
        *(float4*)&Vs[row][c4] = vv;
    }
    // ---- stage Q tile ----
    for (int i = tid; i < QT * 16; i += 256) {
        const int row = i >> 4;
        const int c4  = (i & 15) * 4;
        *(float4*)&Qs[row][c4] =
            *(const float4*)(qkv + (size_t)(b * SS + s0 + row) * (3 * DD) + h * DH + c4);
    }
    // ---- stage selected K/V ----
    for (int i = tid; i < NSEL * 16; i += 256) {
        const int row = i >> 4;
        const int c4  = (i & 15) * 4;
        const float* base = sqkv + (size_t)(b * NSEL + row) * (3 * DD) + h * DH + c4;
        *(float4*)&sKs[row][c4] = *(const float4*)(base + DD);
        *(float4*)&sVs[row][c4] = *(const float4*)(base + 2 * DD);
    }
    __syncthreads();

    for (int qi = 0; qi < 16; ++qi) {
        const int qr = wid * 16 + qi;       // query row within tile
        const int s  = s0 + qr;

        // ---- local window scores ----
        float sc = -INFINITY;
        const int pos = s - WIN + lane;
        if (lane < NW && pos >= 0 && pos < SS) {
            const int kr = qr + lane;       // row in Ks
            float a = 0.f;
#pragma unroll
            for (int d4 = 0; d4 < 16; ++d4) {
                const float4 kv = *(const float4*)&Ks[kr][d4 * 4];
                const float4 qv = *(const float4*)&Qs[qr][d4 * 4];
                a += qv.x * kv.x + qv.y * kv.y + qv.z * kv.z + qv.w * kv.w;
            }
            sc = a * SCALE;
        }
        float m = sc;
#pragma unroll
        for (int off = 32; off >= 1; off >>= 1) m = fmaxf(m, __shfl_xor(m, off));
        float p = (sc == -INFINITY) ? 0.f : expf(sc - m);
        float sum = p;
#pragma unroll
        for (int off = 32; off >= 1; off >>= 1) sum += __shfl_xor(sum, off);
        p /= sum;

        float outd = 0.f;
#pragma unroll
        for (int w = 0; w < NW; ++w) {
            const float pw = __shfl(p, w);
            outd += pw * Vs[qr + w][lane];   // invalid w: pw==0, Vs zero-filled
        }

        // ---- global selected ----
        float sc2 = -INFINITY;
        if (lane < NSEL) {
            float a = 0.f;
#pragma unroll
            for (int d4 = 0; d4 < 16; ++d4) {
                const float4 kv = *(const float4*)&sKs[lane][d4 * 4];
                const float4 qv = *(const float4*)&Qs[qr][d4 * 4];
                a += qv.x * kv.x + qv.y * kv.y + qv.z * kv.z + qv.w * kv.w;
            }
            sc2 = a * SCALE;
        }
        float m2 = sc2;
#pragma unroll
        for (int off = 32; off >= 1; off >>= 1) m2 = fmaxf(m2, __shfl_xor(m2, off));
        float p2 = (lane < NSEL) ? expf(sc2 - m2) : 0.f;
        float sum2 = p2;
#pragma unroll
        for (int off = 32; off >= 1; off >>= 1) sum2 += __shfl_xor(sum2, off);
        p2 /= sum2;
        float outg = 0.f;
#pragma unroll
        for (int kk = 0; kk < NSEL; ++kk) {
            const float pk = __shfl(p2, kk);
            outg += pk * sVs[kk][lane];
        }

        attn[(size_t)(b * SS + s) * DD + h * DH + lane] = (f16)(outd + outg);
    }
}

extern "C" void kernel_launch(void* const* d_in, const int* in_sizes, int n_in,
                              void* d_out, int out_size, void* d_ws, size_t ws_size,
                              hipStream_t stream)
{
    const float* x       = (const float*)d_in[0];
    const float* qkv_w   = (const float*)d_in[1];
    const float* qkv_b   = (const float*)d_in[2];
    const float* c1_w    = (const float*)d_in[3];
    const float* c1_b    = (const float*)d_in[4];
    const float* c2_w    = (const float*)d_in[5];
    const float* c2_b    = (const float*)d_in[6];
    const float* score_w = (const float*)d_in[7];
    const float* score_b = (const float*)d_in[8];
    const float* out_w   = (const float*)d_in[9];
    const float* out_b   = (const float*)d_in[10];
    float* out = (float*)d_out;
    float* ws  = (float*)d_ws;

    // workspace layout (float units) — total 23,654,720 floats
    f16*   xh     = (f16*)ws;
    float* A1     = ws + 2097152;
    f16*   WTc1   = (f16*)A1;
    float* qkvb   = A1;
    f16*   attnf  = (f16*)(A1 + 12582912);
    float* A2     = ws + 18874368;
    float* part   = A2;
    f16*   qkv_wT = (f16*)A2;
    f16*   out_wT = (f16*)(A2 + 1572864);
    float* hidden = ws + 23035904;
    float* comp   = hidden + 260096;
    float* scores = comp + 260096;
    int*   topIdx = (int*)(scores + 256);
    float* sqkvb  = scores + 256 + 64;

    const int MROWS = BB * SS;        // 4096

    // 0. x -> f16 (serves c1 A-gather, qkv GEMM A)
    convert_f16<<<(MROWS * DD) / (256 * 4), 256, 0, stream>>>(x, xh, MROWS * DD);

    // 1. c1_w (32768 x 1024) -> f16 transposed (1024 x 32768)
    transpose_conv<<<dim3(DD / 32, CBS * DD / 32), 256, 0, stream>>>(
        c1_w, WTc1, CBS * DD, DD);

    // 2. c1: hidden partials via f16 MFMA, split-K 16
    gemm_c1<<<dim3(DD / 64, 2, C1_NZ), 256, 0, stream>>>(xh, WTc1, part);

    // 3. hidden = relu(sum partials + c1_b)
    reduce_partials<<<(MC * DD) / 256, 256, 0, stream>>>(
        part, c1_b, hidden, MC * DD, DD, C1_NZ, 1);

    // 4. c2 partials: hidden @ c2_w (254x1024, K=1024, split-K 8) [fp32 exact]
    gemm128<0><<<dim3(DD / 128, 2, 8), 256, 0, stream>>>(
        hidden, c2_w, nullptr, part, MC, DD, DD, nullptr, 0);

    // 5. compressed = sum partials + c2_b
    reduce_partials<<<(MC * DD) / 256, 256, 0, stream>>>(
        part, c2_b, comp, MC * DD, DD, 8, 0);

    // 6. scores
    score_kernel<<<MC, 256, 0, stream>>>(comp, score_w, score_b, scores);

    // 7. top-16 per batch
    topk_kernel<<<BB, 128, 0, stream>>>(scores, topIdx);

    // 8. sqkv = selected @ qkv_w + qkv_b  (32 x 3072, K=1024) [fp32, tiny]
    gemm128<2><<<dim3(3 * DD / 128, 1, 1), 256, 0, stream>>>(
        comp, qkv_w, qkv_b, sqkvb, BB * NSEL, 3 * DD, DD, topIdx, 1);

    // 9. weight transposes for the f16 MFMA GEMMs (A2 partials now dead)
    transpose_conv<<<dim3(3 * DD / 32, DD / 32), 256, 0, stream>>>(
        qkv_w, qkv_wT, DD, 3 * DD);
    transpose_conv<<<dim3(DD / 32, DD / 32), 256, 0, stream>>>(
        out_w, out_wT, DD, DD);

    // 10. qkv = x @ qkv_w + qkv_b (4096 x 3072, K=1024) [f16 MFMA]
    gemm_f16<<<dim3(3 * DD / 128, MROWS / 128), 256, 0, stream>>>(
        xh, qkv_wT, qkv_b, qkvb, MROWS, 3 * DD, DD);

    // 11. tiled attention -> f16 directly
    attn_tiled<<<BB * HH * (SS / QT), 256, 0, stream>>>(qkvb, sqkvb, attnf);

    // 12. out = attn @ out_w + out_b  (4096 x 1024, K=1024) [f16 MFMA]
    gemm_f16<<<dim3(DD / 128, MROWS / 128), 256, 0, stream>>>(
        attnf, out_wT, out_b, out, MROWS, DD, DD);
}

// Round 3
// 361.943 us; speedup vs baseline: 2.1347x; 1.3259x over previous
//
#include <hip/hip_runtime.h>
#include <math.h>

// Problem constants
#define BB   2
#define SS   2048
#define DD   1024
#define HH   16
#define DH   64
#define CBS  32
#define STRIDEC 16
#define NBLK 127          // (S - CBS)/STRIDE + 1
#define NSEL 16
#define WIN  16
#define NW   33           // 2*WIN+1
#define SCALE 0.125f      // DH^-0.5
#define MC   254          // BB * NBLK

typedef _Float16 f16;
typedef __attribute__((ext_vector_type(8))) _Float16 f16x8;
typedef __attribute__((ext_vector_type(4))) _Float16 f16x4;
typedef __attribute__((ext_vector_type(4))) float f32x4;

// ---------------------------------------------------------------------------
// fp32 -> f16 elementwise convert (float4 loads, 4 elems/thread)
// ---------------------------------------------------------------------------
__global__ __launch_bounds__(256) void convert_f16(
    const float* __restrict__ src, f16* __restrict__ dst, int n)
{
    const int i = (blockIdx.x * 256 + threadIdx.x) * 4;
    if (i >= n) return;
    float4 v = *(const float4*)(src + i);
    f16x4 o;
    o[0] = (f16)v.x; o[1] = (f16)v.y; o[2] = (f16)v.z; o[3] = (f16)v.w;
    *(f16x4*)(dst + i) = o;
}

// ---------------------------------------------------------------------------
// fp32 (K x N) -> f16 (N x K) transpose-convert, 32x32 LDS tiles
// ---------------------------------------------------------------------------
__global__ __launch_bounds__(256) void transpose_conv(
    const float* __restrict__ src, f16* __restrict__ dst, int K, int N)
{
    __shared__ float t[32][33];
    const int n0 = blockIdx.x * 32, k0 = blockIdx.y * 32;
    const int tx = threadIdx.x & 31, ty = threadIdx.x >> 5;   // 32 x 8
#pragma unroll
    for (int r = 0; r < 32; r += 8)
        t[ty + r][tx] = src[(size_t)(k0 + ty + r) * N + n0 + tx];
    __syncthreads();
#pragma unroll
    for (int r = 0; r < 32; r += 8)
        dst[(size_t)(n0 + ty + r) * K + k0 + tx] = (f16)t[tx][ty + r];
}

// ---------------------------------------------------------------------------
// f16 MFMA GEMM, m97-style: 128x128 tile, BK=64, 4 waves (2x2), each wave
// 64x64 via 4x4 frags of 16x16x32.  A: M x K f16 row-major.  Bt: N x K f16
// row-major (B transposed).  C: M x N fp32 (+bias).  M,N % 128 == 0.
// ---------------------------------------------------------------------------
__global__ __launch_bounds__(256) void gemm_f16(
    const f16* __restrict__ A, const f16* __restrict__ Bt,
    const float* __restrict__ bias, float* __restrict__ C,
    int M, int N, int K)
{
    constexpr int BK = 64;
    __shared__ f16 As[128 * BK];
    __shared__ f16 Bs[128 * BK];
    const int tid  = threadIdx.x;
    const int wid  = tid >> 6, lane = tid & 63;
    const int bm = blockIdx.y * 128, bn = blockIdx.x * 128;
    const int wm = (wid >> 1) * 64, wn = (wid & 1) * 64;

    const int lrow = lane >> 3;        // 0..7 (row within 8-row segment)
    const int lk8  = (lane & 7) * 8;   // k-element offset of this lane's 16B

    f32x4 acc[4][4];
#pragma unroll
    for (int i = 0; i < 4; ++i)
#pragma unroll
        for (int j = 0; j < 4; ++j) acc[i][j] = (f32x4){0.f, 0.f, 0.f, 0.f};

    for (int kt = 0; kt < K; kt += BK) {
#pragma unroll
        for (int c = 0; c < 4; ++c) {
            const int seg = c * 4 + wid;            // 0..15 -> rows seg*8..+8
            const int row = seg * 8 + lrow;
            const f16* ga = A + (size_t)(bm + row) * K + kt + lk8;
            __builtin_amdgcn_global_load_lds(
                (const __attribute__((address_space(1))) void*)(const void*)ga,
                (__attribute__((address_space(3))) void*)(void*)(As + seg * 512),
                16, 0, 0);
            const f16* gb = Bt + (size_t)(bn + row) * K + kt + lk8;
            __builtin_amdgcn_global_load_lds(
                (const __attribute__((address_space(1))) void*)(const void*)gb,
                (__attribute__((address_space(3))) void*)(void*)(Bs + seg * 512),
                16, 0, 0);
        }
        __syncthreads();   // compiler drains vmcnt before s_barrier

#pragma unroll
        for (int kk = 0; kk < 2; ++kk) {
            const int ko = kk * 32 + (lane >> 4) * 8;
            f16x8 a[4], b[4];
#pragma unroll
            for (int i = 0; i < 4; ++i)
                a[i] = *(const f16x8*)(As + (wm + i * 16 + (lane & 15)) * BK + ko);
#pragma unroll
            for (int j = 0; j < 4; ++j)
                b[j] = *(const f16x8*)(Bs + (wn + j * 16 + (lane & 15)) * BK + ko);
#pragma unroll
            for (int i = 0; i < 4; ++i)
#pragma unroll
                for (int j = 0; j < 4; ++j)
                    acc[i][j] = __builtin_amdgcn_mfma_f32_16x16x32_f16(
                        a[i], b[j], acc[i][j], 0, 0, 0);
        }
        __syncthreads();
    }

    const int rr0 = (lane >> 4) * 4;
    const int cc  = lane & 15;
#pragma unroll
    for (int i = 0; i < 4; ++i) {
        const int r = bm + wm + i * 16 + rr0;
#pragma unroll
        for (int j = 0; j < 4; ++j) {
            const int cn = bn + wn + j * 16 + cc;
            const float bv = bias[cn];
#pragma unroll
            for (int q = 0; q < 4; ++q)
                C[(size_t)(r + q) * N + cn] = acc[i][j][q] + bv;
        }
    }
}

// ---------------------------------------------------------------------------
// c1 compression GEMM in f16 MFMA with fp32 split-K accumulate.
// ---------------------------------------------------------------------------
#define C1_NZ 16
#define C1_KCHUNK 2048     // 32768 / 16

__global__ __launch_bounds__(256) void gemm_c1(
    const f16* __restrict__ xh, const f16* __restrict__ Wt,
    float* __restrict__ P)
{
    constexpr int BK = 64;
    __shared__ f16 As[128 * BK];   // 16 KB
    __shared__ f16 Bs[64 * BK];    //  8 KB
    const int tid  = threadIdx.x;
    const int wid  = tid >> 6, lane = tid & 63;
    const int bn = blockIdx.x * 64, bm = blockIdx.y * 128;
    const int z  = blockIdx.z;
    const int wm = (wid >> 1) * 64, wn = (wid & 1) * 32;

    const int lrow = lane >> 3;
    const int lk8  = (lane & 7) * 8;

    f32x4 acc[4][2];
#pragma unroll
    for (int i = 0; i < 4; ++i)
#pragma unroll
        for (int j = 0; j < 2; ++j) acc[i][j] = (f32x4){0.f, 0.f, 0.f, 0.f};

    for (int t = 0; t < C1_KCHUNK / BK; ++t) {
        const int ktg = z * C1_KCHUNK + t * BK;
        const int kc  = (ktg + lk8) >> 10;       // x feature-row within block
        const int kd  = (ktg + lk8) & 1023;      // x col
#pragma unroll
        for (int c = 0; c < 4; ++c) {
            const int seg = c * 4 + wid;
            int row = bm + seg * 8 + lrow;
            if (row > MC - 1) row = MC - 1;       // pad rows 254/255 (dup, unstored)
            const int b   = (row >= NBLK) ? 1 : 0;
            const int blk = row - b * NBLK;
            const f16* ga = xh + ((size_t)(b * SS + blk * STRIDEC + kc) << 10) + kd;
            __builtin_amdgcn_global_load_lds(
                (const __attribute__((address_space(1))) void*)(const void*)ga,
                (__attribute__((address_space(3))) void*)(void*)(As + seg * 512),
                16, 0, 0);
        }
#pragma unroll
        for (int c = 0; c < 2; ++c) {
            const int seg = wid * 2 + c;
            const int row = bn + seg * 8 + lrow;
            const f16* gb = Wt + (size_t)row * (CBS * DD) + ktg + lk8;
            __builtin_amdgcn_global_load_lds(
                (const __attribute__((address_space(1))) void*)(const void*)gb,
                (__attribute__((address_space(3))) void*)(void*)(Bs + seg * 512),
                16, 0, 0);
        }
        __syncthreads();

#pragma unroll
        for (int kk = 0; kk < 2; ++kk) {
            const int ko = kk * 32 + (lane >> 4) * 8;
            f16x8 a[4], b[2];
#pragma unroll
            for (int i = 0; i < 4; ++i)
                a[i] = *(const f16x8*)(As + (wm + i * 16 + (lane & 15)) * BK + ko);
#pragma unroll
            for (int j = 0; j < 2; ++j)
                b[j] = *(const f16x8*)(Bs + (wn + j * 16 + (lane & 15)) * BK + ko);
#pragma unroll
            for (int i = 0; i < 4; ++i)
#pragma unroll
                for (int j = 0; j < 2; ++j)
                    acc[i][j] = __builtin_amdgcn_mfma_f32_16x16x32_f16(
                        a[i], b[j], acc[i][j], 0, 0, 0);
        }
        __syncthreads();
    }

    const int rr0 = (lane >> 4) * 4;
    const int cc  = lane & 15;
#pragma unroll
    for (int i = 0; i < 4; ++i) {
        const int r = bm + wm + i * 16 + rr0;
#pragma unroll
        for (int j = 0; j < 2; ++j) {
            const int cn = bn + wn + j * 16 + cc;
#pragma unroll
            for (int q = 0; q < 4; ++q)
                if (r + q < MC)
                    P[((size_t)z * MC + r + q) * DD + cn] = acc[i][j][q];
        }
    }
}

// ---------------------------------------------------------------------------
// fp32 tiled GEMM 128x128 — used for the small fp32-exact kernels:
// c2 (MODE 0) and sqkv (MODE 2), both split-K (gridDim.z partials).
// ---------------------------------------------------------------------------
template<int MODE>
__global__ __launch_bounds__(256) void gemm128(
    const float* __restrict__ A, const float* __restrict__ Bm,
    const float* __restrict__ bias, float* __restrict__ C,
    int M, int N, int K, const int* __restrict__ selIdx, int flags)
{
    __shared__ float As[8][132];
    __shared__ float Bs[8][132];

    const int tid = threadIdx.x;
    const int bm = blockIdx.y * 128;
    const int bn = blockIdx.x * 128;
    const int nz = gridDim.z;
    const int z  = blockIdx.z;
    const int kchunk = K / nz;
    const int k0 = z * kchunk;
    const int kend = k0 + kchunk;

    const int tx = tid & 15;
    const int ty = tid >> 4;

    const int arow = tid >> 1;
    const int akq  = (tid & 1) * 4;
    const int bkr  = tid >> 5;
    const int bcol = (tid & 31) * 4;

    float acc[2][2][4][4];
#pragma unroll
    for (int qi = 0; qi < 2; ++qi)
#pragma unroll
        for (int qj = 0; qj < 2; ++qj)
#pragma unroll
            for (int i = 0; i < 4; ++i)
#pragma unroll
                for (int j = 0; j < 4; ++j) acc[qi][qj][i][j] = 0.f;

    auto loadA = [&](int kt) -> float4 {
        float4 av = make_float4(0.f, 0.f, 0.f, 0.f);
        const int grow = bm + arow;
        if (grow < M) {
            if constexpr (MODE == 0) {
                av = *(const float4*)(A + (size_t)grow * K + kt + akq);
            } else {
                const int b = grow >> 4;
                const int j = grow & 15;
                const int idx = selIdx[b * NSEL + j];
                av = *(const float4*)(A + (size_t)(b * NBLK + idx) * K + kt + akq);
            }
        }
        return av;
    };
    auto loadB = [&](int kt) -> float4 {
        return *(const float4*)(Bm + (size_t)(kt + bkr) * N + bn + bcol);
    };

    float4 av = loadA(k0);
    float4 bv = loadB(k0);

    for (int kt = k0; kt < kend; kt += 8) {
        As[akq + 0][arow] = av.x;
        As[akq + 1][arow] = av.y;
        As[akq + 2][arow] = av.z;
        As[akq + 3][arow] = av.w;
        *(float4*)&Bs[bkr][bcol] = bv;
        __syncthreads();
        if (kt + 8 < kend) {
            av = loadA(kt + 8);
            bv = loadB(kt + 8);
        }
#pragma unroll
        for (int k = 0; k < 8; ++k) {
            const float4 a0 = *(const float4*)&As[k][ty * 4];
            const float4 a1 = *(const float4*)&As[k][64 + ty * 4];
            const float4 b0 = *(const float4*)&Bs[k][tx * 4];
            const float4 b1 = *(const float4*)&Bs[k][64 + tx * 4];
            const float ar[2][4] = {{a0.x, a0.y, a0.z, a0.w},
                                    {a1.x, a1.y, a1.z, a1.w}};
            const float br[2][4] = {{b0.x, b0.y, b0.z, b0.w},
                                    {b1.x, b1.y, b1.z, b1.w}};
#pragma unroll
            for (int qi = 0; qi < 2; ++qi)
#pragma unroll
                for (int i = 0; i < 4; ++i)
#pragma unroll
                    for (int qj = 0; qj < 2; ++qj)
#pragma unroll
                        for (int j = 0; j < 4; ++j)
                            acc[qi][qj][i][j] += ar[qi][i] * br[qj][j];
        }
        __syncthreads();
    }

    if (nz == 1) {
        const bool hasB   = (flags & 1) != 0;
        const bool doRelu = (flags & 2) != 0;
#pragma unroll
        for (int qi = 0; qi < 2; ++qi)
#pragma unroll
            for (int i = 0; i < 4; ++i) {
                const int r = bm + qi * 64 + ty * 4 + i;
                if (r >= M) continue;
#pragma unroll
                for (int qj = 0; qj < 2; ++qj)
#pragma unroll
                    for (int j = 0; j < 4; ++j) {
                        const int cn = bn + qj * 64 + tx * 4 + j;
                        float v = acc[qi][qj][i][j];
                        if (hasB) v += bias[cn];
                        if (doRelu) v = fmaxf(v, 0.f);
                        C[(size_t)r * N + cn] = v;
                    }
            }
    } else {
        float* P = C + (size_t)z * M * N;
#pragma unroll
        for (int qi = 0; qi < 2; ++qi)
#pragma unroll
            for (int i = 0; i < 4; ++i) {
                const int r = bm + qi * 64 + ty * 4 + i;
                if (r >= M) continue;
#pragma unroll
                for (int qj = 0; qj < 2; ++qj)
#pragma unroll
                    for (int j = 0; j < 4; ++j) {
                        const int cn = bn + qj * 64 + tx * 4 + j;
                        P[(size_t)r * N + cn] = acc[qi][qj][i][j];
                    }
            }
    }
}

// Sum split-K partials + bias (+relu)
__global__ __launch_bounds__(256) void reduce_partials(
    const float* __restrict__ P, const float* __restrict__ bias,
    float* __restrict__ outp, int MN, int N, int nz, int doRelu)
{
    const int i = blockIdx.x * 256 + threadIdx.x;
    if (i >= MN) return;
    float s = 0.f;
    for (int z = 0; z < nz; ++z) s += P[(size_t)z * MN + i];
    s += bias[i % N];
    if (doRelu) s = fmaxf(s, 0.f);
    outp[i] = s;
}

// scores[row] = compressed[row,:] . score_w + score_b
__global__ __launch_bounds__(256) void score_kernel(
    const float* __restrict__ comp, const float* __restrict__ sw,
    const float* __restrict__ sb, float* __restrict__ scores)
{
    const int row = blockIdx.x;
    const float* cp = comp + (size_t)row * DD;
    float s = 0.f;
    for (int k = threadIdx.x; k < DD; k += 256) s += cp[k] * sw[k];
#pragma unroll
    for (int off = 32; off >= 1; off >>= 1) s += __shfl_xor(s, off);
    __shared__ float red[4];
    if ((threadIdx.x & 63) == 0) red[threadIdx.x >> 6] = s;
    __syncthreads();
    if (threadIdx.x == 0) scores[row] = red[0] + red[1] + red[2] + red[3] + sb[0];
}

// top-16 of 127 scores per batch (set semantics; lowest-index tie-break)
__global__ __launch_bounds__(128) void topk_kernel(
    const float* __restrict__ scores, int* __restrict__ top)
{
    const int b = blockIdx.x;
    const int t = threadIdx.x;  // 128
    __shared__ float sval[128];
    __shared__ float sv2[128];
    __shared__ int   si2[128];
    __shared__ unsigned char used[128];
    sval[t] = (t < NBLK) ? scores[b * NBLK + t] : -INFINITY;
    used[t] = 0;
    __syncthreads();
    for (int j = 0; j < NSEL; ++j) {
        sv2[t] = used[t] ? -INFINITY : sval[t];
        si2[t] = t;
        __syncthreads();
        for (int stp = 64; stp >= 1; stp >>= 1) {
            if (t < stp) {
                if (sv2[t + stp] > sv2[t] ||
                    (sv2[t + stp] == sv2[t] && si2[t + stp] < si2[t])) {
                    sv2[t] = sv2[t + stp];
                    si2[t] = si2[t + stp];
                }
            }
            __syncthreads();
        }
        if (t == 0) { top[b * NSEL + j] = si2[0]; used[si2[0]] = 1; }
        __syncthreads();
    }
}

// ---------------------------------------------------------------------------
// Tiled attention: one workgroup per (b, h, 64-query tile).
// ---------------------------------------------------------------------------
#define QT 64
#define KROWS 96   // QT + 2*WIN

__global__ __launch_bounds__(256) void attn_tiled(
    const float* __restrict__ qkv, const float* __restrict__ sqkv,
    f16* __restrict__ attn)
{
    __shared__ float Ks[KROWS][65];   // +1 pad: per-lane row reads ~2-way
    __shared__ float Vs[KROWS][64];   // row-broadcast reads conflict-free
    __shared__ float Qs[QT][64];      // broadcast reads
    __shared__ float sKs[NSEL][65];
    __shared__ float sVs[NSEL][64];

    int bid = blockIdx.x;
    bid = (bid & 7) * (gridDim.x >> 3) + (bid >> 3);   // XCD chunk swizzle (1024%8==0)
    const int t = bid & 31;            // S/QT tiles
    const int h = (bid >> 5) & (HH - 1);
    const int b = bid >> 9;
    const int s0 = t * QT;

    const int tid = threadIdx.x;
    const int wid = tid >> 6, lane = tid & 63;

    // ---- stage K/V window rows (96 x 64 floats each) ----
    for (int i = tid; i < KROWS * 16; i += 256) {
        const int row = i >> 4;
        const int c4  = (i & 15) * 4;
        const int pos = s0 - WIN + row;
        float4 kv = make_float4(0.f, 0.f, 0.f, 0.f), vv = kv;
        if (pos >= 0 && pos < SS) {
            const float* base = qkv + (size_t)(b * SS + pos) * (3 * DD) + h * DH + c4;
            kv = *(const float4*)(base + DD);
            vv = *(const float4*)(base + 2 * DD);
        }
        *(float4*)&Ks[row][c4] = kv;
        *(float4*)&Vs[row][c4] = vv;
    }
    // ---- stage Q tile ----
    for (int i = tid; i < QT * 16; i += 256) {
        const int row = i >> 4;
        const int c4  = (i & 15) * 4;
        *(float4*)&Qs[row][c4] =
            *(const float4*)(qkv + (size_t)(b * SS + s0 + row) * (3 * DD) + h * DH + c4);
    }
    // ---- stage selected K/V ----
    for (int i = tid; i < NSEL * 16; i += 256) {
        const int row = i >> 4;
        const int c4  = (i & 15) * 4;
        const float* base = sqkv + (size_t)(b * NSEL + row) * (3 * DD) + h * DH + c4;
        *(float4*)&sKs[row][c4] = *(const float4*)(base + DD);
        *(float4*)&sVs[row][c4] = *(const float4*)(base + 2 * DD);
    }
    __syncthreads();

    for (int qi = 0; qi < 16; ++qi) {
        const int qr = wid * 16 + qi;       // query row within tile
        const int s  = s0 + qr;

        // ---- local window scores ----
        float sc = -INFINITY;
        const int pos = s - WIN + lane;
        if (lane < NW && pos >= 0 && pos < SS) {
            const int kr = qr + lane;       // row in Ks
            float a = 0.f;
#pragma unroll
            for (int d4 = 0; d4 < 16; ++d4) {
                const float4 kv = *(const float4*)&Ks[kr][d4 * 4];
                const float4 qv = *(const float4*)&Qs[qr][d4 * 4];
                a += qv.x * kv.x + qv.y * kv.y + qv.z * kv.z + qv.w * kv.w;
            }
            sc = a * SCALE;
        }
        float m = sc;
#pragma unroll
        for (int off = 32; off >= 1; off >>= 1) m = fmaxf(m, __shfl_xor(m, off));
        float p = (sc == -INFINITY) ? 0.f : expf(sc - m);
        float sum = p;
#pragma unroll
        for (int off = 32; off >= 1; off >>= 1) sum += __shfl_xor(sum, off);
        p /= sum;

        float outd = 0.f;
#pragma unroll
        for (int w = 0; w < NW; ++w) {
            const float pw = __shfl(p, w);
            outd += pw * Vs[qr + w][lane];   // invalid w: pw==0, Vs zero-filled
        }

        // ---- global selected ----
        float sc2 = -INFINITY;
        if (lane < NSEL) {
            float a = 0.f;
#pragma unroll
            for (int d4 = 0; d4 < 16; ++d4) {
                const float4 kv = *(const float4*)&sKs[lane][d4 * 4];
                const float4 qv = *(const float4*)&Qs[qr][d4 * 4];
                a += qv.x * kv.x + qv.y * kv.y + qv.z * kv.z + qv.w * kv.w;
            }
            sc2 = a * SCALE;
        }
        float m2 = sc2;
#pragma unroll
        for (int off = 32; off >= 1; off >>= 1) m2 = fmaxf(m2, __shfl_xor(m2, off));
        float p2 = (lane < NSEL) ? expf(sc2 - m2) : 0.f;
        float sum2 = p2;
#pragma unroll
        for (int off = 32; off >= 1; off >>= 1) sum2 += __shfl_xor(sum2, off);
        p2 /= sum2;
        float outg = 0.f;
#pragma unroll
        for (int kk = 0; kk < NSEL; ++kk) {
            const float pk = __shfl(p2, kk);
            outg += pk * sVs[kk][lane];
        }

        attn[(size_t)(b * SS + s) * DD + h * DH + lane] = (f16)(outd + outg);
    }
}

extern "C" void kernel_launch(void* const* d_in, const int* in_sizes, int n_in,
                              void* d_out, int out_size, void* d_ws, size_t ws_size,
                              hipStream_t stream)
{
    const float* x       = (const float*)d_in[0];
    const float* qkv_w   = (const float*)d_in[1];
    const float* qkv_b   = (const float*)d_in[2];
    const float* c1_w    = (const float*)d_in[3];
    const float* c1_b    = (const float*)d_in[4];
    const float* c2_w    = (const float*)d_in[5];
    const float* c2_b    = (const float*)d_in[6];
    const float* score_w = (const float*)d_in[7];
    const float* score_b = (const float*)d_in[8];
    const float* out_w   = (const float*)d_in[9];
    const float* out_b   = (const float*)d_in[10];
    float* out = (float*)d_out;
    float* ws  = (float*)d_ws;

    // workspace layout (float units) — total 23,654,720 floats
    f16*   xh     = (f16*)ws;
    float* A1     = ws + 2097152;
    f16*   WTc1   = (f16*)A1;
    float* qkvb   = A1;
    f16*   attnf  = (f16*)(A1 + 12582912);
    float* A2     = ws + 18874368;          // 4,161,536 floats scratch
    float* part   = A2;
    f16*   qkv_wT = (f16*)A2;
    f16*   out_wT = (f16*)(A2 + 1572864);
    float* hidden = ws + 23035904;
    float* comp   = hidden + 260096;
    float* scores = comp + 260096;
    int*   topIdx = (int*)(scores + 256);
    float* sqkvb  = scores + 256 + 64;

    const int MROWS = BB * SS;        // 4096
    const int MSEL  = BB * NSEL;      // 32

    // 0. x -> f16 (serves c1 A-gather, qkv GEMM A)
    convert_f16<<<(MROWS * DD) / (256 * 4), 256, 0, stream>>>(x, xh, MROWS * DD);

    // 1. c1_w (32768 x 1024) -> f16 transposed (1024 x 32768)
    transpose_conv<<<dim3(DD / 32, CBS * DD / 32), 256, 0, stream>>>(
        c1_w, WTc1, CBS * DD, DD);

    // 2. c1: hidden partials via f16 MFMA, split-K 16
    gemm_c1<<<dim3(DD / 64, 2, C1_NZ), 256, 0, stream>>>(xh, WTc1, part);

    // 3. hidden = relu(sum partials + c1_b)
    reduce_partials<<<(MC * DD) / 256, 256, 0, stream>>>(
        part, c1_b, hidden, MC * DD, DD, C1_NZ, 1);

    // 4. c2 partials: hidden @ c2_w (254x1024, K=1024, split-K 16) [fp32 exact]
    //    partials: 16 x 254 x 1024 = 4,161,536 floats = full A2 region
    gemm128<0><<<dim3(DD / 128, 2, 16), 256, 0, stream>>>(
        hidden, c2_w, nullptr, part, MC, DD, DD, nullptr, 0);

    // 5. compressed = sum partials + c2_b
    reduce_partials<<<(MC * DD) / 256, 256, 0, stream>>>(
        part, c2_b, comp, MC * DD, DD, 16, 0);

    // 6. scores
    score_kernel<<<MC, 256, 0, stream>>>(comp, score_w, score_b, scores);

    // 7. top-16 per batch
    topk_kernel<<<BB, 128, 0, stream>>>(scores, topIdx);

    // 8. sqkv partials: selected @ qkv_w  (32 x 3072, K=1024, split-K 16)
    //    Was grid (24,1,1) = 24 WGs -> 148 us latency-bound.  Now 384 WGs.
    //    partials: 16 x 32 x 3072 = 1,572,864 floats (fits A2, dead region)
    gemm128<2><<<dim3(3 * DD / 128, 1, 16), 256, 0, stream>>>(
        comp, qkv_w, nullptr, part, MSEL, 3 * DD, DD, topIdx, 0);

    // 8b. sqkv = sum partials + qkv_b
    reduce_partials<<<(MSEL * 3 * DD + 255) / 256, 256, 0, stream>>>(
        part, qkv_b, sqkvb, MSEL * 3 * DD, 3 * DD, 16, 0);

    // 9. weight transposes for the f16 MFMA GEMMs (A2 partials now dead)
    transpose_conv<<<dim3(3 * DD / 32, DD / 32), 256, 0, stream>>>(
        qkv_w, qkv_wT, DD, 3 * DD);
    transpose_conv<<<dim3(DD / 32, DD / 32), 256, 0, stream>>>(
        out_w, out_wT, DD, DD);

    // 10. qkv = x @ qkv_w + qkv_b (4096 x 3072, K=1024) [f16 MFMA]
    gemm_f16<<<dim3(3 * DD / 128, MROWS / 128), 256, 0, stream>>>(
        xh, qkv_wT, qkv_b, qkvb, MROWS, 3 * DD, DD);

    // 11. tiled attention -> f16 directly
    attn_tiled<<<BB * HH * (SS / QT), 256, 0, stream>>>(qkvb, sqkvb, attnf);

    // 12. out = attn @ out_w + out_b  (4096 x 1024, K=1024) [f16 MFMA]
    gemm_f16<<<dim3(DD / 128, MROWS / 128), 256, 0, stream>>>(
        attnf, out_wT, out_b, out, MROWS, DD, DD);
}

// Round 4
// 331.819 us; speedup vs baseline: 2.3285x; 1.0908x over previous
//
#include <hip/hip_runtime.h>
#include <math.h>

// Problem constants
#define BB   2
#define SS   2048
#define DD   1024
#define HH   16
#define DH   64
#define CBS  32
#define STRIDEC 16
#define NBLK 127          // (S - CBS)/STRIDE + 1
#define NSEL 16
#define WIN  16
#define NW   33           // 2*WIN+1
#define SCALE 0.125f      // DH^-0.5
#define MC   254          // BB * NBLK

typedef _Float16 f16;
typedef __attribute__((ext_vector_type(8))) _Float16 f16x8;
typedef __attribute__((ext_vector_type(4))) _Float16 f16x4;
typedef __attribute__((ext_vector_type(2))) _Float16 h2;
typedef __attribute__((ext_vector_type(4))) float f32x4;

// ---------------------------------------------------------------------------
// fp32 -> f16 elementwise convert (float4 loads, 4 elems/thread)
// ---------------------------------------------------------------------------
__global__ __launch_bounds__(256) void convert_f16(
    const float* __restrict__ src, f16* __restrict__ dst, int n)
{
    const int i = (blockIdx.x * 256 + threadIdx.x) * 4;
    if (i >= n) return;
    float4 v = *(const float4*)(src + i);
    f16x4 o;
    o[0] = (f16)v.x; o[1] = (f16)v.y; o[2] = (f16)v.z; o[3] = (f16)v.w;
    *(f16x4*)(dst + i) = o;
}

// ---------------------------------------------------------------------------
// fp32 (K x N) -> f16 (N x K) transpose-convert, 32x32 LDS tiles
// ---------------------------------------------------------------------------
__global__ __launch_bounds__(256) void transpose_conv(
    const float* __restrict__ src, f16* __restrict__ dst, int K, int N)
{
    __shared__ float t[32][33];
    const int n0 = blockIdx.x * 32, k0 = blockIdx.y * 32;
    const int tx = threadIdx.x & 31, ty = threadIdx.x >> 5;   // 32 x 8
#pragma unroll
    for (int r = 0; r < 32; r += 8)
        t[ty + r][tx] = src[(size_t)(k0 + ty + r) * N + n0 + tx];
    __syncthreads();
#pragma unroll
    for (int r = 0; r < 32; r += 8)
        dst[(size_t)(n0 + ty + r) * K + k0 + tx] = (f16)t[tx][ty + r];
}

// ---------------------------------------------------------------------------
// f16 MFMA GEMM, m97-style: 128x128 tile, BK=64, 4 waves (2x2), each wave
// 64x64 via 4x4 frags of 16x16x32.  A: M x K f16 row-major.  Bt: N x K f16
// row-major (B transposed).  C: M x N fp32 (+bias).  M,N % 128 == 0.
// ---------------------------------------------------------------------------
__global__ __launch_bounds__(256) void gemm_f16(
    const f16* __restrict__ A, const f16* __restrict__ Bt,
    const float* __restrict__ bias, float* __restrict__ C,
    int M, int N, int K)
{
    constexpr int BK = 64;
    __shared__ f16 As[128 * BK];
    __shared__ f16 Bs[128 * BK];
    const int tid  = threadIdx.x;
    const int wid  = tid >> 6, lane = tid & 63;
    const int bm = blockIdx.y * 128, bn = blockIdx.x * 128;
    const int wm = (wid >> 1) * 64, wn = (wid & 1) * 64;

    const int lrow = lane >> 3;        // 0..7 (row within 8-row segment)
    const int lk8  = (lane & 7) * 8;   // k-element offset of this lane's 16B

    f32x4 acc[4][4];
#pragma unroll
    for (int i = 0; i < 4; ++i)
#pragma unroll
        for (int j = 0; j < 4; ++j) acc[i][j] = (f32x4){0.f, 0.f, 0.f, 0.f};

    for (int kt = 0; kt < K; kt += BK) {
#pragma unroll
        for (int c = 0; c < 4; ++c) {
            const int seg = c * 4 + wid;            // 0..15 -> rows seg*8..+8
            const int row = seg * 8 + lrow;
            const f16* ga = A + (size_t)(bm + row) * K + kt + lk8;
            __builtin_amdgcn_global_load_lds(
                (const __attribute__((address_space(1))) void*)(const void*)ga,
                (__attribute__((address_space(3))) void*)(void*)(As + seg * 512),
                16, 0, 0);
            const f16* gb = Bt + (size_t)(bn + row) * K + kt + lk8;
            __builtin_amdgcn_global_load_lds(
                (const __attribute__((address_space(1))) void*)(const void*)gb,
                (__attribute__((address_space(3))) void*)(void*)(Bs + seg * 512),
                16, 0, 0);
        }
        __syncthreads();   // compiler drains vmcnt before s_barrier

#pragma unroll
        for (int kk = 0; kk < 2; ++kk) {
            const int ko = kk * 32 + (lane >> 4) * 8;
            f16x8 a[4], b[4];
#pragma unroll
            for (int i = 0; i < 4; ++i)
                a[i] = *(const f16x8*)(As + (wm + i * 16 + (lane & 15)) * BK + ko);
#pragma unroll
            for (int j = 0; j < 4; ++j)
                b[j] = *(const f16x8*)(Bs + (wn + j * 16 + (lane & 15)) * BK + ko);
#pragma unroll
            for (int i = 0; i < 4; ++i)
#pragma unroll
                for (int j = 0; j < 4; ++j)
                    acc[i][j] = __builtin_amdgcn_mfma_f32_16x16x32_f16(
                        a[i], b[j], acc[i][j], 0, 0, 0);
        }
        __syncthreads();
    }

    const int rr0 = (lane >> 4) * 4;
    const int cc  = lane & 15;
#pragma unroll
    for (int i = 0; i < 4; ++i) {
        const int r = bm + wm + i * 16 + rr0;
#pragma unroll
        for (int j = 0; j < 4; ++j) {
            const int cn = bn + wn + j * 16 + cc;
            const float bv = bias[cn];
#pragma unroll
            for (int q = 0; q < 4; ++q)
                C[(size_t)(r + q) * N + cn] = acc[i][j][q] + bv;
        }
    }
}

// ---------------------------------------------------------------------------
// c1 compression GEMM in f16 MFMA with fp32 split-K accumulate.
// ---------------------------------------------------------------------------
#define C1_NZ 16
#define C1_KCHUNK 2048     // 32768 / 16

__global__ __launch_bounds__(256) void gemm_c1(
    const f16* __restrict__ xh, const f16* __restrict__ Wt,
    float* __restrict__ P)
{
    constexpr int BK = 64;
    __shared__ f16 As[128 * BK];   // 16 KB
    __shared__ f16 Bs[64 * BK];    //  8 KB
    const int tid  = threadIdx.x;
    const int wid  = tid >> 6, lane = tid & 63;
    const int bn = blockIdx.x * 64, bm = blockIdx.y * 128;
    const int z  = blockIdx.z;
    const int wm = (wid >> 1) * 64, wn = (wid & 1) * 32;

    const int lrow = lane >> 3;
    const int lk8  = (lane & 7) * 8;

    f32x4 acc[4][2];
#pragma unroll
    for (int i = 0; i < 4; ++i)
#pragma unroll
        for (int j = 0; j < 2; ++j) acc[i][j] = (f32x4){0.f, 0.f, 0.f, 0.f};

    for (int t = 0; t < C1_KCHUNK / BK; ++t) {
        const int ktg = z * C1_KCHUNK + t * BK;
        const int kc  = (ktg + lk8) >> 10;       // x feature-row within block
        const int kd  = (ktg + lk8) & 1023;      // x col
#pragma unroll
        for (int c = 0; c < 4; ++c) {
            const int seg = c * 4 + wid;
            int row = bm + seg * 8 + lrow;
            if (row > MC - 1) row = MC - 1;       // pad rows 254/255 (dup, unstored)
            const int b   = (row >= NBLK) ? 1 : 0;
            const int blk = row - b * NBLK;
            const f16* ga = xh + ((size_t)(b * SS + blk * STRIDEC + kc) << 10) + kd;
            __builtin_amdgcn_global_load_lds(
                (const __attribute__((address_space(1))) void*)(const void*)ga,
                (__attribute__((address_space(3))) void*)(void*)(As + seg * 512),
                16, 0, 0);
        }
#pragma unroll
        for (int c = 0; c < 2; ++c) {
            const int seg = wid * 2 + c;
            const int row = bn + seg * 8 + lrow;
            const f16* gb = Wt + (size_t)row * (CBS * DD) + ktg + lk8;
            __builtin_amdgcn_global_load_lds(
                (const __attribute__((address_space(1))) void*)(const void*)gb,
                (__attribute__((address_space(3))) void*)(void*)(Bs + seg * 512),
                16, 0, 0);
        }
        __syncthreads();

#pragma unroll
        for (int kk = 0; kk < 2; ++kk) {
            const int ko = kk * 32 + (lane >> 4) * 8;
            f16x8 a[4], b[2];
#pragma unroll
            for (int i = 0; i < 4; ++i)
                a[i] = *(const f16x8*)(As + (wm + i * 16 + (lane & 15)) * BK + ko);
#pragma unroll
            for (int j = 0; j < 2; ++j)
                b[j] = *(const f16x8*)(Bs + (wn + j * 16 + (lane & 15)) * BK + ko);
#pragma unroll
            for (int i = 0; i < 4; ++i)
#pragma unroll
                for (int j = 0; j < 2; ++j)
                    acc[i][j] = __builtin_amdgcn_mfma_f32_16x16x32_f16(
                        a[i], b[j], acc[i][j], 0, 0, 0);
        }
        __syncthreads();
    }

    const int rr0 = (lane >> 4) * 4;
    const int cc  = lane & 15;
#pragma unroll
    for (int i = 0; i < 4; ++i) {
        const int r = bm + wm + i * 16 + rr0;
#pragma unroll
        for (int j = 0; j < 2; ++j) {
            const int cn = bn + wn + j * 16 + cc;
#pragma unroll
            for (int q = 0; q < 4; ++q)
                if (r + q < MC)
                    P[((size_t)z * MC + r + q) * DD + cn] = acc[i][j][q];
        }
    }
}

// ---------------------------------------------------------------------------
// fp32 tiled GEMM 128x128 — used for the small fp32-exact kernels:
// c2 (MODE 0) and sqkv (MODE 2), both split-K (gridDim.z partials).
// ---------------------------------------------------------------------------
template<int MODE>
__global__ __launch_bounds__(256) void gemm128(
    const float* __restrict__ A, const float* __restrict__ Bm,
    const float* __restrict__ bias, float* __restrict__ C,
    int M, int N, int K, const int* __restrict__ selIdx, int flags)
{
    __shared__ float As[8][132];
    __shared__ float Bs[8][132];

    const int tid = threadIdx.x;
    const int bm = blockIdx.y * 128;
    const int bn = blockIdx.x * 128;
    const int nz = gridDim.z;
    const int z  = blockIdx.z;
    const int kchunk = K / nz;
    const int k0 = z * kchunk;
    const int kend = k0 + kchunk;

    const int tx = tid & 15;
    const int ty = tid >> 4;

    const int arow = tid >> 1;
    const int akq  = (tid & 1) * 4;
    const int bkr  = tid >> 5;
    const int bcol = (tid & 31) * 4;

    float acc[2][2][4][4];
#pragma unroll
    for (int qi = 0; qi < 2; ++qi)
#pragma unroll
        for (int qj = 0; qj < 2; ++qj)
#pragma unroll
            for (int i = 0; i < 4; ++i)
#pragma unroll
                for (int j = 0; j < 4; ++j) acc[qi][qj][i][j] = 0.f;

    auto loadA = [&](int kt) -> float4 {
        float4 av = make_float4(0.f, 0.f, 0.f, 0.f);
        const int grow = bm + arow;
        if (grow < M) {
            if constexpr (MODE == 0) {
                av = *(const float4*)(A + (size_t)grow * K + kt + akq);
            } else {
                const int b = grow >> 4;
                const int j = grow & 15;
                const int idx = selIdx[b * NSEL + j];
                av = *(const float4*)(A + (size_t)(b * NBLK + idx) * K + kt + akq);
            }
        }
        return av;
    };
    auto loadB = [&](int kt) -> float4 {
        return *(const float4*)(Bm + (size_t)(kt + bkr) * N + bn + bcol);
    };

    float4 av = loadA(k0);
    float4 bv = loadB(k0);

    for (int kt = k0; kt < kend; kt += 8) {
        As[akq + 0][arow] = av.x;
        As[akq + 1][arow] = av.y;
        As[akq + 2][arow] = av.z;
        As[akq + 3][arow] = av.w;
        *(float4*)&Bs[bkr][bcol] = bv;
        __syncthreads();
        if (kt + 8 < kend) {
            av = loadA(kt + 8);
            bv = loadB(kt + 8);
        }
#pragma unroll
        for (int k = 0; k < 8; ++k) {
            const float4 a0 = *(const float4*)&As[k][ty * 4];
            const float4 a1 = *(const float4*)&As[k][64 + ty * 4];
            const float4 b0 = *(const float4*)&Bs[k][tx * 4];
            const float4 b1 = *(const float4*)&Bs[k][64 + tx * 4];
            const float ar[2][4] = {{a0.x, a0.y, a0.z, a0.w},
                                    {a1.x, a1.y, a1.z, a1.w}};
            const float br[2][4] = {{b0.x, b0.y, b0.z, b0.w},
                                    {b1.x, b1.y, b1.z, b1.w}};
#pragma unroll
            for (int qi = 0; qi < 2; ++qi)
#pragma unroll
                for (int i = 0; i < 4; ++i)
#pragma unroll
                    for (int qj = 0; qj < 2; ++qj)
#pragma unroll
                        for (int j = 0; j < 4; ++j)
                            acc[qi][qj][i][j] += ar[qi][i] * br[qj][j];
        }
        __syncthreads();
    }

    if (nz == 1) {
        const bool hasB   = (flags & 1) != 0;
        const bool doRelu = (flags & 2) != 0;
#pragma unroll
        for (int qi = 0; qi < 2; ++qi)
#pragma unroll
            for (int i = 0; i < 4; ++i) {
                const int r = bm + qi * 64 + ty * 4 + i;
                if (r >= M) continue;
#pragma unroll
                for (int qj = 0; qj < 2; ++qj)
#pragma unroll
                    for (int j = 0; j < 4; ++j) {
                        const int cn = bn + qj * 64 + tx * 4 + j;
                        float v = acc[qi][qj][i][j];
                        if (hasB) v += bias[cn];
                        if (doRelu) v = fmaxf(v, 0.f);
                        C[(size_t)r * N + cn] = v;
                    }
            }
    } else {
        float* P = C + (size_t)z * M * N;
#pragma unroll
        for (int qi = 0; qi < 2; ++qi)
#pragma unroll
            for (int i = 0; i < 4; ++i) {
                const int r = bm + qi * 64 + ty * 4 + i;
                if (r >= M) continue;
#pragma unroll
                for (int qj = 0; qj < 2; ++qj)
#pragma unroll
                    for (int j = 0; j < 4; ++j) {
                        const int cn = bn + qj * 64 + tx * 4 + j;
                        P[(size_t)r * N + cn] = acc[qi][qj][i][j];
                    }
            }
    }
}

// Sum split-K partials + bias (+relu)
__global__ __launch_bounds__(256) void reduce_partials(
    const float* __restrict__ P, const float* __restrict__ bias,
    float* __restrict__ outp, int MN, int N, int nz, int doRelu)
{
    const int i = blockIdx.x * 256 + threadIdx.x;
    if (i >= MN) return;
    float s = 0.f;
    for (int z = 0; z < nz; ++z) s += P[(size_t)z * MN + i];
    s += bias[i % N];
    if (doRelu) s = fmaxf(s, 0.f);
    outp[i] = s;
}

// scores[row] = compressed[row,:] . score_w + score_b
__global__ __launch_bounds__(256) void score_kernel(
    const float* __restrict__ comp, const float* __restrict__ sw,
    const float* __restrict__ sb, float* __restrict__ scores)
{
    const int row = blockIdx.x;
    const float* cp = comp + (size_t)row * DD;
    float s = 0.f;
    for (int k = threadIdx.x; k < DD; k += 256) s += cp[k] * sw[k];
#pragma unroll
    for (int off = 32; off >= 1; off >>= 1) s += __shfl_xor(s, off);
    __shared__ float red[4];
    if ((threadIdx.x & 63) == 0) red[threadIdx.x >> 6] = s;
    __syncthreads();
    if (threadIdx.x == 0) scores[row] = red[0] + red[1] + red[2] + red[3] + sb[0];
}

// top-16 of 127 scores per batch (set semantics; lowest-index tie-break)
__global__ __launch_bounds__(128) void topk_kernel(
    const float* __restrict__ scores, int* __restrict__ top)
{
    const int b = blockIdx.x;
    const int t = threadIdx.x;  // 128
    __shared__ float sval[128];
    __shared__ float sv2[128];
    __shared__ int   si2[128];
    __shared__ unsigned char used[128];
    sval[t] = (t < NBLK) ? scores[b * NBLK + t] : -INFINITY;
    used[t] = 0;
    __syncthreads();
    for (int j = 0; j < NSEL; ++j) {
        sv2[t] = used[t] ? -INFINITY : sval[t];
        si2[t] = t;
        __syncthreads();
        for (int stp = 64; stp >= 1; stp >>= 1) {
            if (t < stp) {
                if (sv2[t + stp] > sv2[t] ||
                    (sv2[t + stp] == sv2[t] && si2[t + stp] < si2[t])) {
                    sv2[t] = sv2[t + stp];
                    si2[t] = si2[t + stp];
                }
            }
            __syncthreads();
        }
        if (t == 0) { top[b * NSEL + j] = si2[0]; used[si2[0]] = 1; }
        __syncthreads();
    }
}

// ---------------------------------------------------------------------------
// Tiled attention v2: 512 threads (8 waves x 8 queries), f16 LDS staging
// (40.5 KB -> up to 4 blocks/CU), fdot2 score dots, split accumulators.
// ---------------------------------------------------------------------------
#define QT 64
#define KROWS 96   // QT + 2*WIN
#define KST 76     // Ks/sKs row stride in halves (38 dwords: per-lane row reads <=3-way)

__global__ __launch_bounds__(512) void attn_tiled(
    const float* __restrict__ qkv, const float* __restrict__ sqkv,
    f16* __restrict__ attn)
{
    __shared__ f16 Ks[KROWS][KST];   // 14592 B
    __shared__ f16 Vs[KROWS][64];    // 12288 B (row-broadcast reads: conflict-free)
    __shared__ f16 Qs[QT][72];       //  9216 B (broadcast reads)
    __shared__ f16 sKs[NSEL][KST];   //  2432 B
    __shared__ f16 sVs[NSEL][64];    //  2048 B   -> total 40576 B

    int bid = blockIdx.x;
    bid = (bid & 7) * (gridDim.x >> 3) + (bid >> 3);   // XCD chunk swizzle (1024%8==0)
    const int t = bid & 31;            // S/QT tiles
    const int h = (bid >> 5) & (HH - 1);
    const int b = bid >> 9;
    const int s0 = t * QT;

    const int tid = threadIdx.x;
    const int wid = tid >> 6, lane = tid & 63;

    // ---- stage K/V window rows (96 x 64), fp32 -> f16 ----
    for (int i = tid; i < KROWS * 16; i += 512) {
        const int row = i >> 4;
        const int c4  = (i & 15) * 4;
        const int pos = s0 - WIN + row;
        float4 kv = make_float4(0.f, 0.f, 0.f, 0.f), vv = kv;
        if (pos >= 0 && pos < SS) {
            const float* base = qkv + (size_t)(b * SS + pos) * (3 * DD) + h * DH + c4;
            kv = *(const float4*)(base + DD);
            vv = *(const float4*)(base + 2 * DD);
        }
        f16x4 kh, vh;
        kh[0] = (f16)kv.x; kh[1] = (f16)kv.y; kh[2] = (f16)kv.z; kh[3] = (f16)kv.w;
        vh[0] = (f16)vv.x; vh[1] = (f16)vv.y; vh[2] = (f16)vv.z; vh[3] = (f16)vv.w;
        *(f16x4*)&Ks[row][c4] = kh;
        *(f16x4*)&Vs[row][c4] = vh;
    }
    // ---- stage Q tile ----
    for (int i = tid; i < QT * 16; i += 512) {
        const int row = i >> 4;
        const int c4  = (i & 15) * 4;
        float4 qv = *(const float4*)(qkv + (size_t)(b * SS + s0 + row) * (3 * DD) + h * DH + c4);
        f16x4 qh;
        qh[0] = (f16)qv.x; qh[1] = (f16)qv.y; qh[2] = (f16)qv.z; qh[3] = (f16)qv.w;
        *(f16x4*)&Qs[row][c4] = qh;
    }
    // ---- stage selected K/V ----
    for (int i = tid; i < NSEL * 16; i += 512) {
        const int row = i >> 4;
        const int c4  = (i & 15) * 4;
        const float* base = sqkv + (size_t)(b * NSEL + row) * (3 * DD) + h * DH + c4;
        float4 kv = *(const float4*)(base + DD);
        float4 vv = *(const float4*)(base + 2 * DD);
        f16x4 kh, vh;
        kh[0] = (f16)kv.x; kh[1] = (f16)kv.y; kh[2] = (f16)kv.z; kh[3] = (f16)kv.w;
        vh[0] = (f16)vv.x; vh[1] = (f16)vv.y; vh[2] = (f16)vv.z; vh[3] = (f16)vv.w;
        *(f16x4*)&sKs[row][c4] = kh;
        *(f16x4*)&sVs[row][c4] = vh;
    }
    __syncthreads();

#pragma unroll
    for (int qi = 0; qi < 8; ++qi) {
        const int qr = wid * 8 + qi;        // query row within tile
        const int s  = s0 + qr;

        // ---- local window scores (lane = window position) ----
        float sc = -INFINITY;
        const int pos = s - WIN + lane;
        if (lane < NW && pos >= 0 && pos < SS) {
            const h2* kp = (const h2*)&Ks[qr + lane][0];
            const h2* qp = (const h2*)&Qs[qr][0];
            float a0 = 0.f, a1 = 0.f, a2 = 0.f, a3 = 0.f;
#pragma unroll
            for (int d2 = 0; d2 < 32; d2 += 4) {
                a0 = __builtin_amdgcn_fdot2(kp[d2],     qp[d2],     a0, false);
                a1 = __builtin_amdgcn_fdot2(kp[d2 + 1], qp[d2 + 1], a1, false);
                a2 = __builtin_amdgcn_fdot2(kp[d2 + 2], qp[d2 + 2], a2, false);
                a3 = __builtin_amdgcn_fdot2(kp[d2 + 3], qp[d2 + 3], a3, false);
            }
            sc = ((a0 + a1) + (a2 + a3)) * SCALE;
        }
        float m = sc;
#pragma unroll
        for (int off = 32; off >= 1; off >>= 1) m = fmaxf(m, __shfl_xor(m, off));
        float p = (sc == -INFINITY) ? 0.f : __expf(sc - m);
        float sum = p;
#pragma unroll
        for (int off = 32; off >= 1; off >>= 1) sum += __shfl_xor(sum, off);
        p /= sum;

        // ---- PV local (lane = dim), 4-way split accumulators ----
        float o0 = 0.f, o1 = 0.f, o2 = 0.f, o3 = 0.f;
#pragma unroll
        for (int w = 0; w < 32; w += 4) {
            o0 += __shfl(p, w)     * (float)Vs[qr + w][lane];
            o1 += __shfl(p, w + 1) * (float)Vs[qr + w + 1][lane];
            o2 += __shfl(p, w + 2) * (float)Vs[qr + w + 2][lane];
            o3 += __shfl(p, w + 3) * (float)Vs[qr + w + 3][lane];
        }
        float outd = ((o0 + o1) + (o2 + o3)) + __shfl(p, 32) * (float)Vs[qr + 32][lane];

        // ---- global selected ----
        float sc2 = -INFINITY;
        if (lane < NSEL) {
            const h2* kp = (const h2*)&sKs[lane][0];
            const h2* qp = (const h2*)&Qs[qr][0];
            float a0 = 0.f, a1 = 0.f, a2 = 0.f, a3 = 0.f;
#pragma unroll
            for (int d2 = 0; d2 < 32; d2 += 4) {
                a0 = __builtin_amdgcn_fdot2(kp[d2],     qp[d2],     a0, false);
                a1 = __builtin_amdgcn_fdot2(kp[d2 + 1], qp[d2 + 1], a1, false);
                a2 = __builtin_amdgcn_fdot2(kp[d2 + 2], qp[d2 + 2], a2, false);
                a3 = __builtin_amdgcn_fdot2(kp[d2 + 3], qp[d2 + 3], a3, false);
            }
            sc2 = ((a0 + a1) + (a2 + a3)) * SCALE;
        }
        float m2 = sc2;
#pragma unroll
        for (int off = 32; off >= 1; off >>= 1) m2 = fmaxf(m2, __shfl_xor(m2, off));
        float p2 = (lane < NSEL) ? __expf(sc2 - m2) : 0.f;
        float sum2 = p2;
#pragma unroll
        for (int off = 32; off >= 1; off >>= 1) sum2 += __shfl_xor(sum2, off);
        p2 /= sum2;

        float g0 = 0.f, g1 = 0.f;
#pragma unroll
        for (int kk = 0; kk < NSEL; kk += 2) {
            g0 += __shfl(p2, kk)     * (float)sVs[kk][lane];
            g1 += __shfl(p2, kk + 1) * (float)sVs[kk + 1][lane];
        }

        attn[(size_t)(b * SS + s) * DD + h * DH + lane] = (f16)(outd + (g0 + g1));
    }
}

extern "C" void kernel_launch(void* const* d_in, const int* in_sizes, int n_in,
                              void* d_out, int out_size, void* d_ws, size_t ws_size,
                              hipStream_t stream)
{
    const float* x       = (const float*)d_in[0];
    const float* qkv_w   = (const float*)d_in[1];
    const float* qkv_b   = (const float*)d_in[2];
    const float* c1_w    = (const float*)d_in[3];
    const float* c1_b    = (const float*)d_in[4];
    const float* c2_w    = (const float*)d_in[5];
    const float* c2_b    = (const float*)d_in[6];
    const float* score_w = (const float*)d_in[7];
    const float* score_b = (const float*)d_in[8];
    const float* out_w   = (const float*)d_in[9];
    const float* out_b   = (const float*)d_in[10];
    float* out = (float*)d_out;
    float* ws  = (float*)d_ws;

    // workspace layout (float units) — total 23,654,720 floats
    f16*   xh     = (f16*)ws;
    float* A1     = ws + 2097152;
    f16*   WTc1   = (f16*)A1;
    float* qkvb   = A1;
    f16*   attnf  = (f16*)(A1 + 12582912);
    float* A2     = ws + 18874368;          // 4,161,536 floats scratch
    float* part   = A2;
    f16*   qkv_wT = (f16*)A2;
    f16*   out_wT = (f16*)(A2 + 1572864);
    float* hidden = ws + 23035904;
    float* comp   = hidden + 260096;
    float* scores = comp + 260096;
    int*   topIdx = (int*)(scores + 256);
    float* sqkvb  = scores + 256 + 64;

    const int MROWS = BB * SS;        // 4096
    const int MSEL  = BB * NSEL;      // 32

    // 0. x -> f16 (serves c1 A-gather, qkv GEMM A)
    convert_f16<<<(MROWS * DD) / (256 * 4), 256, 0, stream>>>(x, xh, MROWS * DD);

    // 1. c1_w (32768 x 1024) -> f16 transposed (1024 x 32768)
    transpose_conv<<<dim3(DD / 32, CBS * DD / 32), 256, 0, stream>>>(
        c1_w, WTc1, CBS * DD, DD);

    // 2. c1: hidden partials via f16 MFMA, split-K 16
    gemm_c1<<<dim3(DD / 64, 2, C1_NZ), 256, 0, stream>>>(xh, WTc1, part);

    // 3. hidden = relu(sum partials + c1_b)
    reduce_partials<<<(MC * DD) / 256, 256, 0, stream>>>(
        part, c1_b, hidden, MC * DD, DD, C1_NZ, 1);

    // 4. c2 partials: hidden @ c2_w (254x1024, K=1024, split-K 16) [fp32 exact]
    gemm128<0><<<dim3(DD / 128, 2, 16), 256, 0, stream>>>(
        hidden, c2_w, nullptr, part, MC, DD, DD, nullptr, 0);

    // 5. compressed = sum partials + c2_b
    reduce_partials<<<(MC * DD) / 256, 256, 0, stream>>>(
        part, c2_b, comp, MC * DD, DD, 16, 0);

    // 6. scores
    score_kernel<<<MC, 256, 0, stream>>>(comp, score_w, score_b, scores);

    // 7. top-16 per batch
    topk_kernel<<<BB, 128, 0, stream>>>(scores, topIdx);

    // 8. sqkv partials: selected @ qkv_w  (32 x 3072, K=1024, split-K 16)
    gemm128<2><<<dim3(3 * DD / 128, 1, 16), 256, 0, stream>>>(
        comp, qkv_w, nullptr, part, MSEL, 3 * DD, DD, topIdx, 0);

    // 8b. sqkv = sum partials + qkv_b
    reduce_partials<<<(MSEL * 3 * DD + 255) / 256, 256, 0, stream>>>(
        part, qkv_b, sqkvb, MSEL * 3 * DD, 3 * DD, 16, 0);

    // 9. weight transposes for the f16 MFMA GEMMs (A2 partials now dead)
    transpose_conv<<<dim3(3 * DD / 32, DD / 32), 256, 0, stream>>>(
        qkv_w, qkv_wT, DD, 3 * DD);
    transpose_conv<<<dim3(DD / 32, DD / 32), 256, 0, stream>>>(
        out_w, out_wT, DD, DD);

    // 10. qkv = x @ qkv_w + qkv_b (4096 x 3072, K=1024) [f16 MFMA]
    gemm_f16<<<dim3(3 * DD / 128, MROWS / 128), 256, 0, stream>>>(
        xh, qkv_wT, qkv_b, qkvb, MROWS, 3 * DD, DD);

    // 11. tiled attention (8 waves, f16 staging) -> f16 directly
    attn_tiled<<<BB * HH * (SS / QT), 512, 0, stream>>>(qkvb, sqkvb, attnf);

    // 12. out = attn @ out_w + out_b  (4096 x 1024, K=1024) [f16 MFMA]
    gemm_f16<<<dim3(DD / 128, MROWS / 128), 256, 0, stream>>>(
        attnf, out_wT, out_b, out, MROWS, DD, DD);
}

// Round 5
// 330.164 us; speedup vs baseline: 2.3402x; 1.0050x over previous
//
#include <hip/hip_runtime.h>
#include <math.h>

// Problem constants
#define BB   2
#define SS   2048
#define DD   1024
#define HH   16
#define DH   64
#define CBS  32
#define STRIDEC 16
#define NBLK 127          // (S - CBS)/STRIDE + 1
#define NSEL 16
#define WIN  16
#define NW   33           // 2*WIN+1
#define SCALE 0.125f      // DH^-0.5
#define MC   254          // BB * NBLK

typedef _Float16 f16;
typedef __attribute__((ext_vector_type(8))) _Float16 f16x8;
typedef __attribute__((ext_vector_type(4))) _Float16 f16x4;
typedef __attribute__((ext_vector_type(2))) _Float16 h2;
typedef __attribute__((ext_vector_type(4))) float f32x4;

// ---------------------------------------------------------------------------
// fp32 -> f16 elementwise convert (float4 loads, 4 elems/thread)
// ---------------------------------------------------------------------------
__global__ __launch_bounds__(256) void convert_f16(
    const float* __restrict__ src, f16* __restrict__ dst, int n)
{
    const int i = (blockIdx.x * 256 + threadIdx.x) * 4;
    if (i >= n) return;
    float4 v = *(const float4*)(src + i);
    f16x4 o;
    o[0] = (f16)v.x; o[1] = (f16)v.y; o[2] = (f16)v.z; o[3] = (f16)v.w;
    *(f16x4*)(dst + i) = o;
}

// ---------------------------------------------------------------------------
// fp32 (K x N) -> f16 (N x K) transpose-convert, 32x32 LDS tiles
// ---------------------------------------------------------------------------
__global__ __launch_bounds__(256) void transpose_conv(
    const float* __restrict__ src, f16* __restrict__ dst, int K, int N)
{
    __shared__ float t[32][33];
    const int n0 = blockIdx.x * 32, k0 = blockIdx.y * 32;
    const int tx = threadIdx.x & 31, ty = threadIdx.x >> 5;   // 32 x 8
#pragma unroll
    for (int r = 0; r < 32; r += 8)
        t[ty + r][tx] = src[(size_t)(k0 + ty + r) * N + n0 + tx];
    __syncthreads();
#pragma unroll
    for (int r = 0; r < 32; r += 8)
        dst[(size_t)(n0 + ty + r) * K + k0 + tx] = (f16)t[tx][ty + r];
}

// ---------------------------------------------------------------------------
// f16 MFMA GEMM, m97-style: 128x128 tile, BK=64, 4 waves (2x2), each wave
// 64x64 via 4x4 frags of 16x16x32.  A: M x K f16 row-major.  Bt: N x K f16
// row-major (B transposed).  C: M x N fp32 (+bias).  M,N % 128 == 0.
// ---------------------------------------------------------------------------
__global__ __launch_bounds__(256) void gemm_f16(
    const f16* __restrict__ A, const f16* __restrict__ Bt,
    const float* __restrict__ bias, float* __restrict__ C,
    int M, int N, int K)
{
    constexpr int BK = 64;
    __shared__ f16 As[128 * BK];
    __shared__ f16 Bs[128 * BK];
    const int tid  = threadIdx.x;
    const int wid  = tid >> 6, lane = tid & 63;
    const int bm = blockIdx.y * 128, bn = blockIdx.x * 128;
    const int wm = (wid >> 1) * 64, wn = (wid & 1) * 64;

    const int lrow = lane >> 3;        // 0..7 (row within 8-row segment)
    const int lk8  = (lane & 7) * 8;   // k-element offset of this lane's 16B

    f32x4 acc[4][4];
#pragma unroll
    for (int i = 0; i < 4; ++i)
#pragma unroll
        for (int j = 0; j < 4; ++j) acc[i][j] = (f32x4){0.f, 0.f, 0.f, 0.f};

    for (int kt = 0; kt < K; kt += BK) {
#pragma unroll
        for (int c = 0; c < 4; ++c) {
            const int seg = c * 4 + wid;            // 0..15 -> rows seg*8..+8
            const int row = seg * 8 + lrow;
            const f16* ga = A + (size_t)(bm + row) * K + kt + lk8;
            __builtin_amdgcn_global_load_lds(
                (const __attribute__((address_space(1))) void*)(const void*)ga,
                (__attribute__((address_space(3))) void*)(void*)(As + seg * 512),
                16, 0, 0);
            const f16* gb = Bt + (size_t)(bn + row) * K + kt + lk8;
            __builtin_amdgcn_global_load_lds(
                (const __attribute__((address_space(1))) void*)(const void*)gb,
                (__attribute__((address_space(3))) void*)(void*)(Bs + seg * 512),
                16, 0, 0);
        }
        __syncthreads();   // compiler drains vmcnt before s_barrier

#pragma unroll
        for (int kk = 0; kk < 2; ++kk) {
            const int ko = kk * 32 + (lane >> 4) * 8;
            f16x8 a[4], b[4];
#pragma unroll
            for (int i = 0; i < 4; ++i)
                a[i] = *(const f16x8*)(As + (wm + i * 16 + (lane & 15)) * BK + ko);
#pragma unroll
            for (int j = 0; j < 4; ++j)
                b[j] = *(const f16x8*)(Bs + (wn + j * 16 + (lane & 15)) * BK + ko);
#pragma unroll
            for (int i = 0; i < 4; ++i)
#pragma unroll
                for (int j = 0; j < 4; ++j)
                    acc[i][j] = __builtin_amdgcn_mfma_f32_16x16x32_f16(
                        a[i], b[j], acc[i][j], 0, 0, 0);
        }
        __syncthreads();
    }

    const int rr0 = (lane >> 4) * 4;
    const int cc  = lane & 15;
#pragma unroll
    for (int i = 0; i < 4; ++i) {
        const int r = bm + wm + i * 16 + rr0;
#pragma unroll
        for (int j = 0; j < 4; ++j) {
            const int cn = bn + wn + j * 16 + cc;
            const float bv = bias[cn];
#pragma unroll
            for (int q = 0; q < 4; ++q)
                C[(size_t)(r + q) * N + cn] = acc[i][j][q] + bv;
        }
    }
}

// ---------------------------------------------------------------------------
// c1 compression GEMM in f16 MFMA with fp32 split-K accumulate.
// ---------------------------------------------------------------------------
#define C1_NZ 16
#define C1_KCHUNK 2048     // 32768 / 16

__global__ __launch_bounds__(256) void gemm_c1(
    const f16* __restrict__ xh, const f16* __restrict__ Wt,
    float* __restrict__ P)
{
    constexpr int BK = 64;
    __shared__ f16 As[128 * BK];   // 16 KB
    __shared__ f16 Bs[64 * BK];    //  8 KB
    const int tid  = threadIdx.x;
    const int wid  = tid >> 6, lane = tid & 63;
    const int bn = blockIdx.x * 64, bm = blockIdx.y * 128;
    const int z  = blockIdx.z;
    const int wm = (wid >> 1) * 64, wn = (wid & 1) * 32;

    const int lrow = lane >> 3;
    const int lk8  = (lane & 7) * 8;

    f32x4 acc[4][2];
#pragma unroll
    for (int i = 0; i < 4; ++i)
#pragma unroll
        for (int j = 0; j < 2; ++j) acc[i][j] = (f32x4){0.f, 0.f, 0.f, 0.f};

    for (int t = 0; t < C1_KCHUNK / BK; ++t) {
        const int ktg = z * C1_KCHUNK + t * BK;
        const int kc  = (ktg + lk8) >> 10;       // x feature-row within block
        const int kd  = (ktg + lk8) & 1023;      // x col
#pragma unroll
        for (int c = 0; c < 4; ++c) {
            const int seg = c * 4 + wid;
            int row = bm + seg * 8 + lrow;
            if (row > MC - 1) row = MC - 1;       // pad rows 254/255 (dup, unstored)
            const int b   = (row >= NBLK) ? 1 : 0;
            const int blk = row - b * NBLK;
            const f16* ga = xh + ((size_t)(b * SS + blk * STRIDEC + kc) << 10) + kd;
            __builtin_amdgcn_global_load_lds(
                (const __attribute__((address_space(1))) void*)(const void*)ga,
                (__attribute__((address_space(3))) void*)(void*)(As + seg * 512),
                16, 0, 0);
        }
#pragma unroll
        for (int c = 0; c < 2; ++c) {
            const int seg = wid * 2 + c;
            const int row = bn + seg * 8 + lrow;
            const f16* gb = Wt + (size_t)row * (CBS * DD) + ktg + lk8;
            __builtin_amdgcn_global_load_lds(
                (const __attribute__((address_space(1))) void*)(const void*)gb,
                (__attribute__((address_space(3))) void*)(void*)(Bs + seg * 512),
                16, 0, 0);
        }
        __syncthreads();

#pragma unroll
        for (int kk = 0; kk < 2; ++kk) {
            const int ko = kk * 32 + (lane >> 4) * 8;
            f16x8 a[4], b[2];
#pragma unroll
            for (int i = 0; i < 4; ++i)
                a[i] = *(const f16x8*)(As + (wm + i * 16 + (lane & 15)) * BK + ko);
#pragma unroll
            for (int j = 0; j < 2; ++j)
                b[j] = *(const f16x8*)(Bs + (wn + j * 16 + (lane & 15)) * BK + ko);
#pragma unroll
            for (int i = 0; i < 4; ++i)
#pragma unroll
                for (int j = 0; j < 2; ++j)
                    acc[i][j] = __builtin_amdgcn_mfma_f32_16x16x32_f16(
                        a[i], b[j], acc[i][j], 0, 0, 0);
        }
        __syncthreads();
    }

    const int rr0 = (lane >> 4) * 4;
    const int cc  = lane & 15;
#pragma unroll
    for (int i = 0; i < 4; ++i) {
        const int r = bm + wm + i * 16 + rr0;
#pragma unroll
        for (int j = 0; j < 2; ++j) {
            const int cn = bn + wn + j * 16 + cc;
#pragma unroll
            for (int q = 0; q < 4; ++q)
                if (r + q < MC)
                    P[((size_t)z * MC + r + q) * DD + cn] = acc[i][j][q];
        }
    }
}

// ---------------------------------------------------------------------------
// fp32 tiled GEMM 128x128 — used for the small fp32-exact kernels:
// c2 (MODE 0) and sqkv (MODE 2), both split-K (gridDim.z partials).
// ---------------------------------------------------------------------------
template<int MODE>
__global__ __launch_bounds__(256) void gemm128(
    const float* __restrict__ A, const float* __restrict__ Bm,
    const float* __restrict__ bias, float* __restrict__ C,
    int M, int N, int K, const int* __restrict__ selIdx, int flags)
{
    __shared__ float As[8][132];
    __shared__ float Bs[8][132];

    const int tid = threadIdx.x;
    const int bm = blockIdx.y * 128;
    const int bn = blockIdx.x * 128;
    const int nz = gridDim.z;
    const int z  = blockIdx.z;
    const int kchunk = K / nz;
    const int k0 = z * kchunk;
    const int kend = k0 + kchunk;

    const int tx = tid & 15;
    const int ty = tid >> 4;

    const int arow = tid >> 1;
    const int akq  = (tid & 1) * 4;
    const int bkr  = tid >> 5;
    const int bcol = (tid & 31) * 4;

    float acc[2][2][4][4];
#pragma unroll
    for (int qi = 0; qi < 2; ++qi)
#pragma unroll
        for (int qj = 0; qj < 2; ++qj)
#pragma unroll
            for (int i = 0; i < 4; ++i)
#pragma unroll
                for (int j = 0; j < 4; ++j) acc[qi][qj][i][j] = 0.f;

    auto loadA = [&](int kt) -> float4 {
        float4 av = make_float4(0.f, 0.f, 0.f, 0.f);
        const int grow = bm + arow;
        if (grow < M) {
            if constexpr (MODE == 0) {
                av = *(const float4*)(A + (size_t)grow * K + kt + akq);
            } else {
                const int b = grow >> 4;
                const int j = grow & 15;
                const int idx = selIdx[b * NSEL + j];
                av = *(const float4*)(A + (size_t)(b * NBLK + idx) * K + kt + akq);
            }
        }
        return av;
    };
    auto loadB = [&](int kt) -> float4 {
        return *(const float4*)(Bm + (size_t)(kt + bkr) * N + bn + bcol);
    };

    float4 av = loadA(k0);
    float4 bv = loadB(k0);

    for (int kt = k0; kt < kend; kt += 8) {
        As[akq + 0][arow] = av.x;
        As[akq + 1][arow] = av.y;
        As[akq + 2][arow] = av.z;
        As[akq + 3][arow] = av.w;
        *(float4*)&Bs[bkr][bcol] = bv;
        __syncthreads();
        if (kt + 8 < kend) {
            av = loadA(kt + 8);
            bv = loadB(kt + 8);
        }
#pragma unroll
        for (int k = 0; k < 8; ++k) {
            const float4 a0 = *(const float4*)&As[k][ty * 4];
            const float4 a1 = *(const float4*)&As[k][64 + ty * 4];
            const float4 b0 = *(const float4*)&Bs[k][tx * 4];
            const float4 b1 = *(const float4*)&Bs[k][64 + tx * 4];
            const float ar[2][4] = {{a0.x, a0.y, a0.z, a0.w},
                                    {a1.x, a1.y, a1.z, a1.w}};
            const float br[2][4] = {{b0.x, b0.y, b0.z, b0.w},
                                    {b1.x, b1.y, b1.z, b1.w}};
#pragma unroll
            for (int qi = 0; qi < 2; ++qi)
#pragma unroll
                for (int i = 0; i < 4; ++i)
#pragma unroll
                    for (int qj = 0; qj < 2; ++qj)
#pragma unroll
                        for (int j = 0; j < 4; ++j)
                            acc[qi][qj][i][j] += ar[qi][i] * br[qj][j];
        }
        __syncthreads();
    }

    if (nz == 1) {
        const bool hasB   = (flags & 1) != 0;
        const bool doRelu = (flags & 2) != 0;
#pragma unroll
        for (int qi = 0; qi < 2; ++qi)
#pragma unroll
            for (int i = 0; i < 4; ++i) {
                const int r = bm + qi * 64 + ty * 4 + i;
                if (r >= M) continue;
#pragma unroll
                for (int qj = 0; qj < 2; ++qj)
#pragma unroll
                    for (int j = 0; j < 4; ++j) {
                        const int cn = bn + qj * 64 + tx * 4 + j;
                        float v = acc[qi][qj][i][j];
                        if (hasB) v += bias[cn];
                        if (doRelu) v = fmaxf(v, 0.f);
                        C[(size_t)r * N + cn] = v;
                    }
            }
    } else {
        float* P = C + (size_t)z * M * N;
#pragma unroll
        for (int qi = 0; qi < 2; ++qi)
#pragma unroll
            for (int i = 0; i < 4; ++i) {
                const int r = bm + qi * 64 + ty * 4 + i;
                if (r >= M) continue;
#pragma unroll
                for (int qj = 0; qj < 2; ++qj)
#pragma unroll
                    for (int j = 0; j < 4; ++j) {
                        const int cn = bn + qj * 64 + tx * 4 + j;
                        P[(size_t)r * N + cn] = acc[qi][qj][i][j];
                    }
            }
    }
}

// Sum split-K partials + bias (+relu)
__global__ __launch_bounds__(256) void reduce_partials(
    const float* __restrict__ P, const float* __restrict__ bias,
    float* __restrict__ outp, int MN, int N, int nz, int doRelu)
{
    const int i = blockIdx.x * 256 + threadIdx.x;
    if (i >= MN) return;
    float s = 0.f;
    for (int z = 0; z < nz; ++z) s += P[(size_t)z * MN + i];
    s += bias[i % N];
    if (doRelu) s = fmaxf(s, 0.f);
    outp[i] = s;
}

// scores[row] = compressed[row,:] . score_w + score_b
__global__ __launch_bounds__(256) void score_kernel(
    const float* __restrict__ comp, const float* __restrict__ sw,
    const float* __restrict__ sb, float* __restrict__ scores)
{
    const int row = blockIdx.x;
    const float* cp = comp + (size_t)row * DD;
    float s = 0.f;
    for (int k = threadIdx.x; k < DD; k += 256) s += cp[k] * sw[k];
#pragma unroll
    for (int off = 32; off >= 1; off >>= 1) s += __shfl_xor(s, off);
    __shared__ float red[4];
    if ((threadIdx.x & 63) == 0) red[threadIdx.x >> 6] = s;
    __syncthreads();
    if (threadIdx.x == 0) scores[row] = red[0] + red[1] + red[2] + red[3] + sb[0];
}

// top-16 of 127 scores per batch (set semantics; lowest-index tie-break)
__global__ __launch_bounds__(128) void topk_kernel(
    const float* __restrict__ scores, int* __restrict__ top)
{
    const int b = blockIdx.x;
    const int t = threadIdx.x;  // 128
    __shared__ float sval[128];
    __shared__ float sv2[128];
    __shared__ int   si2[128];
    __shared__ unsigned char used[128];
    sval[t] = (t < NBLK) ? scores[b * NBLK + t] : -INFINITY;
    used[t] = 0;
    __syncthreads();
    for (int j = 0; j < NSEL; ++j) {
        sv2[t] = used[t] ? -INFINITY : sval[t];
        si2[t] = t;
        __syncthreads();
        for (int stp = 64; stp >= 1; stp >>= 1) {
            if (t < stp) {
                if (sv2[t + stp] > sv2[t] ||
                    (sv2[t + stp] == sv2[t] && si2[t + stp] < si2[t])) {
                    sv2[t] = sv2[t + stp];
                    si2[t] = si2[t + stp];
                }
            }
            __syncthreads();
        }
        if (t == 0) { top[b * NSEL + j] = si2[0]; used[si2[0]] = 1; }
        __syncthreads();
    }
}

// ---------------------------------------------------------------------------
// Attention v3: lane = query.  One wave (64 threads) per (b,h,64-query tile).
// Q in registers; K/V/selK/selV in f16 LDS (68-half rows: 8B-aligned, ~2-way
// banks).  ALL softmax math is per-lane register math — zero cross-lane ops.
// ---------------------------------------------------------------------------
#define QT 64
#define KROWS 96   // QT + 2*WIN
#define KPAD 68    // halves per row (136 B)

__global__ __launch_bounds__(64, 2) void attn_lane(
    const float* __restrict__ qkv, const float* __restrict__ sqkv,
    f16* __restrict__ attn)
{
    __shared__ f16 Ks[KROWS][KPAD];   // 13056 B
    __shared__ f16 Vs[KROWS][KPAD];   // 13056 B
    __shared__ f16 sKs[NSEL][KPAD];   //  2176 B
    __shared__ f16 sVs[NSEL][KPAD];   //  2176 B  -> 30464 B total

    int bid = blockIdx.x;
    bid = (bid & 7) * (gridDim.x >> 3) + (bid >> 3);   // XCD chunk swizzle (1024%8==0)
    const int t = bid & 31;            // S/QT tiles
    const int h = (bid >> 5) & (HH - 1);
    const int b = bid >> 9;
    const int s0 = t * QT;

    const int lane = threadIdx.x;      // 0..63 = query row within tile
    const int s = s0 + lane;

    // ---- own Q row -> 32 h2 registers (f16) ----
    h2 q2[32];
    {
        const float* qp = qkv + (size_t)(b * SS + s) * (3 * DD) + h * DH;
#pragma unroll
        for (int d4 = 0; d4 < 16; ++d4) {
            float4 v = *(const float4*)(qp + d4 * 4);
            h2 lo, hi;
            lo[0] = (f16)v.x; lo[1] = (f16)v.y;
            hi[0] = (f16)v.z; hi[1] = (f16)v.w;
            q2[d4 * 2] = lo; q2[d4 * 2 + 1] = hi;
        }
    }

    // ---- stage K/V window rows (zero-filled OOB; zeros keep PV NaN-free) ----
    for (int i = lane; i < KROWS * 16; i += 64) {
        const int row = i >> 4;
        const int c4  = (i & 15) * 4;
        const int pos = s0 - WIN + row;
        float4 kv = make_float4(0.f, 0.f, 0.f, 0.f), vv = kv;
        if (pos >= 0 && pos < SS) {
            const float* base = qkv + (size_t)(b * SS + pos) * (3 * DD) + h * DH + c4;
            kv = *(const float4*)(base + DD);
            vv = *(const float4*)(base + 2 * DD);
        }
        f16x4 kh, vh;
        kh[0] = (f16)kv.x; kh[1] = (f16)kv.y; kh[2] = (f16)kv.z; kh[3] = (f16)kv.w;
        vh[0] = (f16)vv.x; vh[1] = (f16)vv.y; vh[2] = (f16)vv.z; vh[3] = (f16)vv.w;
        *(f16x4*)&Ks[row][c4] = kh;
        *(f16x4*)&Vs[row][c4] = vh;
    }
    // ---- stage selected K/V ----
    for (int i = lane; i < NSEL * 16; i += 64) {
        const int row = i >> 4;
        const int c4  = (i & 15) * 4;
        const float* base = sqkv + (size_t)(b * NSEL + row) * (3 * DD) + h * DH + c4;
        float4 kv = *(const float4*)(base + DD);
        float4 vv = *(const float4*)(base + 2 * DD);
        f16x4 kh, vh;
        kh[0] = (f16)kv.x; kh[1] = (f16)kv.y; kh[2] = (f16)kv.z; kh[3] = (f16)kv.w;
        vh[0] = (f16)vv.x; vh[1] = (f16)vv.y; vh[2] = (f16)vv.z; vh[3] = (f16)vv.w;
        *(f16x4*)&sKs[row][c4] = kh;
        *(f16x4*)&sVs[row][c4] = vh;
    }
    __syncthreads();

    // ---- local window scores (per-lane, 33 rows) ----
    float sc[NW];
#pragma unroll
    for (int w = 0; w < NW; ++w) {
        const f16* kr = &Ks[lane + w][0];
        float a0 = 0.f, a1 = 0.f, a2 = 0.f, a3 = 0.f;
#pragma unroll
        for (int d8 = 0; d8 < 8; ++d8) {
            f16x4 ka = *(const f16x4*)(kr + d8 * 8);
            f16x4 kb = *(const f16x4*)(kr + d8 * 8 + 4);
            h2 k0; k0[0] = ka[0]; k0[1] = ka[1];
            h2 k1; k1[0] = ka[2]; k1[1] = ka[3];
            h2 k2; k2[0] = kb[0]; k2[1] = kb[1];
            h2 k3; k3[0] = kb[2]; k3[1] = kb[3];
            a0 = __builtin_amdgcn_fdot2(k0, q2[d8 * 4 + 0], a0, false);
            a1 = __builtin_amdgcn_fdot2(k1, q2[d8 * 4 + 1], a1, false);
            a2 = __builtin_amdgcn_fdot2(k2, q2[d8 * 4 + 2], a2, false);
            a3 = __builtin_amdgcn_fdot2(k3, q2[d8 * 4 + 3], a3, false);
        }
        const int pos = s - WIN + w;
        sc[w] = (pos >= 0 && pos < SS) ? ((a0 + a1) + (a2 + a3)) * SCALE : -INFINITY;
    }
    // softmax (registers only; exp(-inf)=0 handles masked slots)
    float m = sc[0];
#pragma unroll
    for (int w = 1; w < NW; ++w) m = fmaxf(m, sc[w]);
    float t0 = 0.f, t1 = 0.f, t2 = 0.f, t3 = 0.f;
#pragma unroll
    for (int w = 0; w < 32; w += 4) {
        sc[w]     = __expf(sc[w]     - m); t0 += sc[w];
        sc[w + 1] = __expf(sc[w + 1] - m); t1 += sc[w + 1];
        sc[w + 2] = __expf(sc[w + 2] - m); t2 += sc[w + 2];
        sc[w + 3] = __expf(sc[w + 3] - m); t3 += sc[w + 3];
    }
    sc[32] = __expf(sc[32] - m);
    const float inv1 = 1.f / (((t0 + t1) + (t2 + t3)) + sc[32]);

    // ---- PV local: o[d] = sum_w e[w] * V[lane+w][d] ----
    float o[64];
#pragma unroll
    for (int d = 0; d < 64; ++d) o[d] = 0.f;
#pragma unroll
    for (int w = 0; w < NW; ++w) {
        const f16* vr = &Vs[lane + w][0];
        const float p = sc[w];
#pragma unroll
        for (int d4 = 0; d4 < 16; ++d4) {
            f16x4 v4 = *(const f16x4*)(vr + d4 * 4);
            o[d4 * 4 + 0] += p * (float)v4[0];
            o[d4 * 4 + 1] += p * (float)v4[1];
            o[d4 * 4 + 2] += p * (float)v4[2];
            o[d4 * 4 + 3] += p * (float)v4[3];
        }
    }

    // ---- global selected scores (broadcast rows) ----
    float sc2[NSEL];
#pragma unroll
    for (int k = 0; k < NSEL; ++k) {
        const f16* kr = &sKs[k][0];
        float a0 = 0.f, a1 = 0.f, a2 = 0.f, a3 = 0.f;
#pragma unroll
        for (int d8 = 0; d8 < 8; ++d8) {
            f16x4 ka = *(const f16x4*)(kr + d8 * 8);
            f16x4 kb = *(const f16x4*)(kr + d8 * 8 + 4);
            h2 k0; k0[0] = ka[0]; k0[1] = ka[1];
            h2 k1; k1[0] = ka[2]; k1[1] = ka[3];
            h2 k2; k2[0] = kb[0]; k2[1] = kb[1];
            h2 k3; k3[0] = kb[2]; k3[1] = kb[3];
            a0 = __builtin_amdgcn_fdot2(k0, q2[d8 * 4 + 0], a0, false);
            a1 = __builtin_amdgcn_fdot2(k1, q2[d8 * 4 + 1], a1, false);
            a2 = __builtin_amdgcn_fdot2(k2, q2[d8 * 4 + 2], a2, false);
            a3 = __builtin_amdgcn_fdot2(k3, q2[d8 * 4 + 3], a3, false);
        }
        sc2[k] = ((a0 + a1) + (a2 + a3)) * SCALE;
    }
    float m2 = sc2[0];
#pragma unroll
    for (int k = 1; k < NSEL; ++k) m2 = fmaxf(m2, sc2[k]);
    float u0 = 0.f, u1 = 0.f;
#pragma unroll
    for (int k = 0; k < NSEL; k += 2) {
        sc2[k]     = __expf(sc2[k]     - m2); u0 += sc2[k];
        sc2[k + 1] = __expf(sc2[k + 1] - m2); u1 += sc2[k + 1];
    }
    const float inv2 = 1.f / (u0 + u1);

    // ---- combine: o = o*inv1 + sum_k (e2[k]*inv2) * sV[k] ----
#pragma unroll
    for (int d = 0; d < 64; ++d) o[d] *= inv1;
#pragma unroll
    for (int k = 0; k < NSEL; ++k) {
        const float p = sc2[k] * inv2;
        const f16* vr = &sVs[k][0];
#pragma unroll
        for (int d4 = 0; d4 < 16; ++d4) {
            f16x4 v4 = *(const f16x4*)(vr + d4 * 4);
            o[d4 * 4 + 0] += p * (float)v4[0];
            o[d4 * 4 + 1] += p * (float)v4[1];
            o[d4 * 4 + 2] += p * (float)v4[2];
            o[d4 * 4 + 3] += p * (float)v4[3];
        }
    }

    // ---- write own output row (128B contiguous, f16) ----
    f16* op = attn + (size_t)(b * SS + s) * DD + h * DH;
#pragma unroll
    for (int d8 = 0; d8 < 8; ++d8) {
        f16x8 v;
#pragma unroll
        for (int j = 0; j < 8; ++j) v[j] = (f16)o[d8 * 8 + j];
        *(f16x8*)(op + d8 * 8) = v;
    }
}

extern "C" void kernel_launch(void* const* d_in, const int* in_sizes, int n_in,
                              void* d_out, int out_size, void* d_ws, size_t ws_size,
                              hipStream_t stream)
{
    const float* x       = (const float*)d_in[0];
    const float* qkv_w   = (const float*)d_in[1];
    const float* qkv_b   = (const float*)d_in[2];
    const float* c1_w    = (const float*)d_in[3];
    const float* c1_b    = (const float*)d_in[4];
    const float* c2_w    = (const float*)d_in[5];
    const float* c2_b    = (const float*)d_in[6];
    const float* score_w = (const float*)d_in[7];
    const float* score_b = (const float*)d_in[8];
    const float* out_w   = (const float*)d_in[9];
    const float* out_b   = (const float*)d_in[10];
    float* out = (float*)d_out;
    float* ws  = (float*)d_ws;

    // workspace layout (float units) — total 23,654,720 floats
    f16*   xh     = (f16*)ws;
    float* A1     = ws + 2097152;
    f16*   WTc1   = (f16*)A1;
    float* qkvb   = A1;
    f16*   attnf  = (f16*)(A1 + 12582912);
    float* A2     = ws + 18874368;          // 4,161,536 floats scratch
    float* part   = A2;
    f16*   qkv_wT = (f16*)A2;
    f16*   out_wT = (f16*)(A2 + 1572864);
    float* hidden = ws + 23035904;
    float* comp   = hidden + 260096;
    float* scores = comp + 260096;
    int*   topIdx = (int*)(scores + 256);
    float* sqkvb  = scores + 256 + 64;

    const int MROWS = BB * SS;        // 4096
    const int MSEL  = BB * NSEL;      // 32

    // 0. x -> f16 (serves c1 A-gather, qkv GEMM A)
    convert_f16<<<(MROWS * DD) / (256 * 4), 256, 0, stream>>>(x, xh, MROWS * DD);

    // 1. c1_w (32768 x 1024) -> f16 transposed (1024 x 32768)
    transpose_conv<<<dim3(DD / 32, CBS * DD / 32), 256, 0, stream>>>(
        c1_w, WTc1, CBS * DD, DD);

    // 2. c1: hidden partials via f16 MFMA, split-K 16
    gemm_c1<<<dim3(DD / 64, 2, C1_NZ), 256, 0, stream>>>(xh, WTc1, part);

    // 3. hidden = relu(sum partials + c1_b)
    reduce_partials<<<(MC * DD) / 256, 256, 0, stream>>>(
        part, c1_b, hidden, MC * DD, DD, C1_NZ, 1);

    // 4. c2 partials: hidden @ c2_w (254x1024, K=1024, split-K 16) [fp32 exact]
    gemm128<0><<<dim3(DD / 128, 2, 16), 256, 0, stream>>>(
        hidden, c2_w, nullptr, part, MC, DD, DD, nullptr, 0);

    // 5. compressed = sum partials + c2_b
    reduce_partials<<<(MC * DD) / 256, 256, 0, stream>>>(
        part, c2_b, comp, MC * DD, DD, 16, 0);

    // 6. scores
    score_kernel<<<MC, 256, 0, stream>>>(comp, score_w, score_b, scores);

    // 7. top-16 per batch
    topk_kernel<<<BB, 128, 0, stream>>>(scores, topIdx);

    // 8. sqkv partials: selected @ qkv_w  (32 x 3072, K=1024, split-K 16)
    gemm128<2><<<dim3(3 * DD / 128, 1, 16), 256, 0, stream>>>(
        comp, qkv_w, nullptr, part, MSEL, 3 * DD, DD, topIdx, 0);

    // 8b. sqkv = sum partials + qkv_b
    reduce_partials<<<(MSEL * 3 * DD + 255) / 256, 256, 0, stream>>>(
        part, qkv_b, sqkvb, MSEL * 3 * DD, 3 * DD, 16, 0);

    // 9. weight transposes for the f16 MFMA GEMMs (A2 partials now dead)
    transpose_conv<<<dim3(3 * DD / 32, DD / 32), 256, 0, stream>>>(
        qkv_w, qkv_wT, DD, 3 * DD);
    transpose_conv<<<dim3(DD / 32, DD / 32), 256, 0, stream>>>(
        out_w, out_wT, DD, DD);

    // 10. qkv = x @ qkv_w + qkv_b (4096 x 3072, K=1024) [f16 MFMA]
    gemm_f16<<<dim3(3 * DD / 128, MROWS / 128), 256, 0, stream>>>(
        xh, qkv_wT, qkv_b, qkvb, MROWS, 3 * DD, DD);

    // 11. attention: lane-per-query, zero cross-lane ops -> f16 directly
    attn_lane<<<BB * HH * (SS / QT), 64, 0, stream>>>(qkvb, sqkvb, attnf);

    // 12. out = attn @ out_w + out_b  (4096 x 1024, K=1024) [f16 MFMA]
    gemm_f16<<<dim3(DD / 128, MROWS / 128), 256, 0, stream>>>(
        attnf, out_wT, out_b, out, MROWS, DD, DD);
}

// Round 6
// 258.355 us; speedup vs baseline: 2.9906x; 1.2779x over previous
//
#include <hip/hip_runtime.h>
#include <math.h>

// Problem constants
#define BB   2
#define SS   2048
#define DD   1024
#define HH   16
#define DH   64
#define CBS  32
#define STRIDEC 16
#define NBLK 127          // (S - CBS)/STRIDE + 1
#define NSEL 16
#define WIN  16
#define NW   33           // 2*WIN+1
#define SCALE 0.125f      // DH^-0.5
#define MC   254          // BB * NBLK

typedef _Float16 f16;
typedef __attribute__((ext_vector_type(8))) _Float16 f16x8;
typedef __attribute__((ext_vector_type(4))) _Float16 f16x4;
typedef __attribute__((ext_vector_type(2))) _Float16 h2;
typedef __attribute__((ext_vector_type(4))) float f32x4;

// ---------------------------------------------------------------------------
// fp32 -> f16 elementwise convert (float4 loads, 4 elems/thread)
// ---------------------------------------------------------------------------
__global__ __launch_bounds__(256) void convert_f16(
    const float* __restrict__ src, f16* __restrict__ dst, int n)
{
    const int i = (blockIdx.x * 256 + threadIdx.x) * 4;
    if (i >= n) return;
    float4 v = *(const float4*)(src + i);
    f16x4 o;
    o[0] = (f16)v.x; o[1] = (f16)v.y; o[2] = (f16)v.z; o[3] = (f16)v.w;
    *(f16x4*)(dst + i) = o;
}

// ---------------------------------------------------------------------------
// fp32 (K x N) -> f16 (N x K) transpose-convert, 32x32 LDS tiles
// ---------------------------------------------------------------------------
__global__ __launch_bounds__(256) void transpose_conv(
    const float* __restrict__ src, f16* __restrict__ dst, int K, int N)
{
    __shared__ float t[32][33];
    const int n0 = blockIdx.x * 32, k0 = blockIdx.y * 32;
    const int tx = threadIdx.x & 31, ty = threadIdx.x >> 5;   // 32 x 8
#pragma unroll
    for (int r = 0; r < 32; r += 8)
        t[ty + r][tx] = src[(size_t)(k0 + ty + r) * N + n0 + tx];
    __syncthreads();
#pragma unroll
    for (int r = 0; r < 32; r += 8)
        dst[(size_t)(n0 + ty + r) * K + k0 + tx] = (f16)t[tx][ty + r];
}

// ---------------------------------------------------------------------------
// f16 MFMA GEMM, m97-style: 128x128 tile, BK=64, 4 waves (2x2), each wave
// 64x64 via 4x4 frags of 16x16x32.  A: M x K f16 row-major.  Bt: N x K f16
// row-major (B transposed).  C: M x N fp32 (+bias).  M,N % 128 == 0.
// ---------------------------------------------------------------------------
__global__ __launch_bounds__(256) void gemm_f16(
    const f16* __restrict__ A, const f16* __restrict__ Bt,
    const float* __restrict__ bias, float* __restrict__ C,
    int M, int N, int K)
{
    constexpr int BK = 64;
    __shared__ f16 As[128 * BK];
    __shared__ f16 Bs[128 * BK];
    const int tid  = threadIdx.x;
    const int wid  = tid >> 6, lane = tid & 63;
    const int bm = blockIdx.y * 128, bn = blockIdx.x * 128;
    const int wm = (wid >> 1) * 64, wn = (wid & 1) * 64;

    const int lrow = lane >> 3;        // 0..7 (row within 8-row segment)
    const int lk8  = (lane & 7) * 8;   // k-element offset of this lane's 16B

    f32x4 acc[4][4];
#pragma unroll
    for (int i = 0; i < 4; ++i)
#pragma unroll
        for (int j = 0; j < 4; ++j) acc[i][j] = (f32x4){0.f, 0.f, 0.f, 0.f};

    for (int kt = 0; kt < K; kt += BK) {
#pragma unroll
        for (int c = 0; c < 4; ++c) {
            const int seg = c * 4 + wid;            // 0..15 -> rows seg*8..+8
            const int row = seg * 8 + lrow;
            const f16* ga = A + (size_t)(bm + row) * K + kt + lk8;
            __builtin_amdgcn_global_load_lds(
                (const __attribute__((address_space(1))) void*)(const void*)ga,
                (__attribute__((address_space(3))) void*)(void*)(As + seg * 512),
                16, 0, 0);
            const f16* gb = Bt + (size_t)(bn + row) * K + kt + lk8;
            __builtin_amdgcn_global_load_lds(
                (const __attribute__((address_space(1))) void*)(const void*)gb,
                (__attribute__((address_space(3))) void*)(void*)(Bs + seg * 512),
                16, 0, 0);
        }
        __syncthreads();   // compiler drains vmcnt before s_barrier

#pragma unroll
        for (int kk = 0; kk < 2; ++kk) {
            const int ko = kk * 32 + (lane >> 4) * 8;
            f16x8 a[4], b[4];
#pragma unroll
            for (int i = 0; i < 4; ++i)
                a[i] = *(const f16x8*)(As + (wm + i * 16 + (lane & 15)) * BK + ko);
#pragma unroll
            for (int j = 0; j < 4; ++j)
                b[j] = *(const f16x8*)(Bs + (wn + j * 16 + (lane & 15)) * BK + ko);
#pragma unroll
            for (int i = 0; i < 4; ++i)
#pragma unroll
                for (int j = 0; j < 4; ++j)
                    acc[i][j] = __builtin_amdgcn_mfma_f32_16x16x32_f16(
                        a[i], b[j], acc[i][j], 0, 0, 0);
        }
        __syncthreads();
    }

    const int rr0 = (lane >> 4) * 4;
    const int cc  = lane & 15;
#pragma unroll
    for (int i = 0; i < 4; ++i) {
        const int r = bm + wm + i * 16 + rr0;
#pragma unroll
        for (int j = 0; j < 4; ++j) {
            const int cn = bn + wn + j * 16 + cc;
            const float bv = bias[cn];
#pragma unroll
            for (int q = 0; q < 4; ++q)
                C[(size_t)(r + q) * N + cn] = acc[i][j][q] + bv;
        }
    }
}

// ---------------------------------------------------------------------------
// c1 compression GEMM in f16 MFMA with fp32 split-K accumulate.
// ---------------------------------------------------------------------------
#define C1_NZ 16
#define C1_KCHUNK 2048     // 32768 / 16

__global__ __launch_bounds__(256) void gemm_c1(
    const f16* __restrict__ xh, const f16* __restrict__ Wt,
    float* __restrict__ P)
{
    constexpr int BK = 64;
    __shared__ f16 As[128 * BK];   // 16 KB
    __shared__ f16 Bs[64 * BK];    //  8 KB
    const int tid  = threadIdx.x;
    const int wid  = tid >> 6, lane = tid & 63;
    const int bn = blockIdx.x * 64, bm = blockIdx.y * 128;
    const int z  = blockIdx.z;
    const int wm = (wid >> 1) * 64, wn = (wid & 1) * 32;

    const int lrow = lane >> 3;
    const int lk8  = (lane & 7) * 8;

    f32x4 acc[4][2];
#pragma unroll
    for (int i = 0; i < 4; ++i)
#pragma unroll
        for (int j = 0; j < 2; ++j) acc[i][j] = (f32x4){0.f, 0.f, 0.f, 0.f};

    for (int t = 0; t < C1_KCHUNK / BK; ++t) {
        const int ktg = z * C1_KCHUNK + t * BK;
        const int kc  = (ktg + lk8) >> 10;       // x feature-row within block
        const int kd  = (ktg + lk8) & 1023;      // x col
#pragma unroll
        for (int c = 0; c < 4; ++c) {
            const int seg = c * 4 + wid;
            int row = bm + seg * 8 + lrow;
            if (row > MC - 1) row = MC - 1;       // pad rows 254/255 (dup, unstored)
            const int b   = (row >= NBLK) ? 1 : 0;
            const int blk = row - b * NBLK;
            const f16* ga = xh + ((size_t)(b * SS + blk * STRIDEC + kc) << 10) + kd;
            __builtin_amdgcn_global_load_lds(
                (const __attribute__((address_space(1))) void*)(const void*)ga,
                (__attribute__((address_space(3))) void*)(void*)(As + seg * 512),
                16, 0, 0);
        }
#pragma unroll
        for (int c = 0; c < 2; ++c) {
            const int seg = wid * 2 + c;
            const int row = bn + seg * 8 + lrow;
            const f16* gb = Wt + (size_t)row * (CBS * DD) + ktg + lk8;
            __builtin_amdgcn_global_load_lds(
                (const __attribute__((address_space(1))) void*)(const void*)gb,
                (__attribute__((address_space(3))) void*)(void*)(Bs + seg * 512),
                16, 0, 0);
        }
        __syncthreads();

#pragma unroll
        for (int kk = 0; kk < 2; ++kk) {
            const int ko = kk * 32 + (lane >> 4) * 8;
            f16x8 a[4], b[2];
#pragma unroll
            for (int i = 0; i < 4; ++i)
                a[i] = *(const f16x8*)(As + (wm + i * 16 + (lane & 15)) * BK + ko);
#pragma unroll
            for (int j = 0; j < 2; ++j)
                b[j] = *(const f16x8*)(Bs + (wn + j * 16 + (lane & 15)) * BK + ko);
#pragma unroll
            for (int i = 0; i < 4; ++i)
#pragma unroll
                for (int j = 0; j < 2; ++j)
                    acc[i][j] = __builtin_amdgcn_mfma_f32_16x16x32_f16(
                        a[i], b[j], acc[i][j], 0, 0, 0);
        }
        __syncthreads();
    }

    const int rr0 = (lane >> 4) * 4;
    const int cc  = lane & 15;
#pragma unroll
    for (int i = 0; i < 4; ++i) {
        const int r = bm + wm + i * 16 + rr0;
#pragma unroll
        for (int j = 0; j < 2; ++j) {
            const int cn = bn + wn + j * 16 + cc;
#pragma unroll
            for (int q = 0; q < 4; ++q)
                if (r + q < MC)
                    P[((size_t)z * MC + r + q) * DD + cn] = acc[i][j][q];
        }
    }
}

// ---------------------------------------------------------------------------
// fp32 tiled GEMM 128x128 — used for the small fp32-exact kernels:
// c2 (MODE 0) and sqkv (MODE 2), both split-K (gridDim.z partials).
// ---------------------------------------------------------------------------
template<int MODE>
__global__ __launch_bounds__(256) void gemm128(
    const float* __restrict__ A, const float* __restrict__ Bm,
    const float* __restrict__ bias, float* __restrict__ C,
    int M, int N, int K, const int* __restrict__ selIdx, int flags)
{
    __shared__ float As[8][132];
    __shared__ float Bs[8][132];

    const int tid = threadIdx.x;
    const int bm = blockIdx.y * 128;
    const int bn = blockIdx.x * 128;
    const int nz = gridDim.z;
    const int z  = blockIdx.z;
    const int kchunk = K / nz;
    const int k0 = z * kchunk;
    const int kend = k0 + kchunk;

    const int tx = tid & 15;
    const int ty = tid >> 4;

    const int arow = tid >> 1;
    const int akq  = (tid & 1) * 4;
    const int bkr  = tid >> 5;
    const int bcol = (tid & 31) * 4;

    float acc[2][2][4][4];
#pragma unroll
    for (int qi = 0; qi < 2; ++qi)
#pragma unroll
        for (int qj = 0; qj < 2; ++qj)
#pragma unroll
            for (int i = 0; i < 4; ++i)
#pragma unroll
                for (int j = 0; j < 4; ++j) acc[qi][qj][i][j] = 0.f;

    auto loadA = [&](int kt) -> float4 {
        float4 av = make_float4(0.f, 0.f, 0.f, 0.f);
        const int grow = bm + arow;
        if (grow < M) {
            if constexpr (MODE == 0) {
                av = *(const float4*)(A + (size_t)grow * K + kt + akq);
            } else {
                const int b = grow >> 4;
                const int j = grow & 15;
                const int idx = selIdx[b * NSEL + j];
                av = *(const float4*)(A + (size_t)(b * NBLK + idx) * K + kt + akq);
            }
        }
        return av;
    };
    auto loadB = [&](int kt) -> float4 {
        return *(const float4*)(Bm + (size_t)(kt + bkr) * N + bn + bcol);
    };

    float4 av = loadA(k0);
    float4 bv = loadB(k0);

    for (int kt = k0; kt < kend; kt += 8) {
        As[akq + 0][arow] = av.x;
        As[akq + 1][arow] = av.y;
        As[akq + 2][arow] = av.z;
        As[akq + 3][arow] = av.w;
        *(float4*)&Bs[bkr][bcol] = bv;
        __syncthreads();
        if (kt + 8 < kend) {
            av = loadA(kt + 8);
            bv = loadB(kt + 8);
        }
#pragma unroll
        for (int k = 0; k < 8; ++k) {
            const float4 a0 = *(const float4*)&As[k][ty * 4];
            const float4 a1 = *(const float4*)&As[k][64 + ty * 4];
            const float4 b0 = *(const float4*)&Bs[k][tx * 4];
            const float4 b1 = *(const float4*)&Bs[k][64 + tx * 4];
            const float ar[2][4] = {{a0.x, a0.y, a0.z, a0.w},
                                    {a1.x, a1.y, a1.z, a1.w}};
            const float br[2][4] = {{b0.x, b0.y, b0.z, b0.w},
                                    {b1.x, b1.y, b1.z, b1.w}};
#pragma unroll
            for (int qi = 0; qi < 2; ++qi)
#pragma unroll
                for (int i = 0; i < 4; ++i)
#pragma unroll
                    for (int qj = 0; qj < 2; ++qj)
#pragma unroll
                        for (int j = 0; j < 4; ++j)
                            acc[qi][qj][i][j] += ar[qi][i] * br[qj][j];
        }
        __syncthreads();
    }

    if (nz == 1) {
        const bool hasB   = (flags & 1) != 0;
        const bool doRelu = (flags & 2) != 0;
#pragma unroll
        for (int qi = 0; qi < 2; ++qi)
#pragma unroll
            for (int i = 0; i < 4; ++i) {
                const int r = bm + qi * 64 + ty * 4 + i;
                if (r >= M) continue;
#pragma unroll
                for (int qj = 0; qj < 2; ++qj)
#pragma unroll
                    for (int j = 0; j < 4; ++j) {
                        const int cn = bn + qj * 64 + tx * 4 + j;
                        float v = acc[qi][qj][i][j];
                        if (hasB) v += bias[cn];
                        if (doRelu) v = fmaxf(v, 0.f);
                        C[(size_t)r * N + cn] = v;
                    }
            }
    } else {
        float* P = C + (size_t)z * M * N;
#pragma unroll
        for (int qi = 0; qi < 2; ++qi)
#pragma unroll
            for (int i = 0; i < 4; ++i) {
                const int r = bm + qi * 64 + ty * 4 + i;
                if (r >= M) continue;
#pragma unroll
                for (int qj = 0; qj < 2; ++qj)
#pragma unroll
                    for (int j = 0; j < 4; ++j) {
                        const int cn = bn + qj * 64 + tx * 4 + j;
                        P[(size_t)r * N + cn] = acc[qi][qj][i][j];
                    }
            }
    }
}

// Sum split-K partials + bias (+relu)
__global__ __launch_bounds__(256) void reduce_partials(
    const float* __restrict__ P, const float* __restrict__ bias,
    float* __restrict__ outp, int MN, int N, int nz, int doRelu)
{
    const int i = blockIdx.x * 256 + threadIdx.x;
    if (i >= MN) return;
    float s = 0.f;
    for (int z = 0; z < nz; ++z) s += P[(size_t)z * MN + i];
    s += bias[i % N];
    if (doRelu) s = fmaxf(s, 0.f);
    outp[i] = s;
}

// scores[row] = compressed[row,:] . score_w + score_b
__global__ __launch_bounds__(256) void score_kernel(
    const float* __restrict__ comp, const float* __restrict__ sw,
    const float* __restrict__ sb, float* __restrict__ scores)
{
    const int row = blockIdx.x;
    const float* cp = comp + (size_t)row * DD;
    float s = 0.f;
    for (int k = threadIdx.x; k < DD; k += 256) s += cp[k] * sw[k];
#pragma unroll
    for (int off = 32; off >= 1; off >>= 1) s += __shfl_xor(s, off);
    __shared__ float red[4];
    if ((threadIdx.x & 63) == 0) red[threadIdx.x >> 6] = s;
    __syncthreads();
    if (threadIdx.x == 0) scores[row] = red[0] + red[1] + red[2] + red[3] + sb[0];
}

// top-16 of 127 scores per batch (set semantics; lowest-index tie-break)
__global__ __launch_bounds__(128) void topk_kernel(
    const float* __restrict__ scores, int* __restrict__ top)
{
    const int b = blockIdx.x;
    const int t = threadIdx.x;  // 128
    __shared__ float sval[128];
    __shared__ float sv2[128];
    __shared__ int   si2[128];
    __shared__ unsigned char used[128];
    sval[t] = (t < NBLK) ? scores[b * NBLK + t] : -INFINITY;
    used[t] = 0;
    __syncthreads();
    for (int j = 0; j < NSEL; ++j) {
        sv2[t] = used[t] ? -INFINITY : sval[t];
        si2[t] = t;
        __syncthreads();
        for (int stp = 64; stp >= 1; stp >>= 1) {
            if (t < stp) {
                if (sv2[t + stp] > sv2[t] ||
                    (sv2[t + stp] == sv2[t] && si2[t + stp] < si2[t])) {
                    sv2[t] = sv2[t + stp];
                    si2[t] = si2[t + stp];
                }
            }
            __syncthreads();
        }
        if (t == 0) { top[b * NSEL + j] = si2[0]; used[si2[0]] = 1; }
        __syncthreads();
    }
}

// ---------------------------------------------------------------------------
// Attention v4 (MFMA): block = 4 waves, one (b,h,64-query tile).
// Swapped QK^T -> D[kv][q] (fragment layout identical to gemm_f16's proven
// convention); per-lane softmax + 2 shfl_xor; P pre-normalized into per-wave
// LDS on a unified kv axis (96 window + 16 sel + 16 zeros); V staged
// TRANSPOSED (Vt[d][kv]) so PV = mfma(P[q][kv], Vt[d][kv]) -> O[q][d].
// ---------------------------------------------------------------------------
#define QT 64
#define KROWS 96   // QT + 2*WIN
#define KST2 72    // K/sK row stride in halves (144 B: 16B-aligned, 2-way banks)
#define VST 136    // Vt row stride in halves (272 B)
#define PST 136    // P row stride in halves

__global__ __launch_bounds__(256) void attn_mfma(
    const float* __restrict__ qkv, const float* __restrict__ sqkv,
    f16* __restrict__ attn)
{
    __shared__ f16 Kl[KROWS][KST2];      // 13824 B
    __shared__ f16 sKl[NSEL][KST2];      //  2304 B
    __shared__ f16 Vt[DH][VST];          // 17408 B  (cols: 0..95 win, 96..111 sel, 112..127 zero)
    __shared__ f16 Pl[4][16][PST];       // 17408 B  per-wave P[q16][kv128]

    int bid = blockIdx.x;
    bid = (bid & 7) * (gridDim.x >> 3) + (bid >> 3);   // XCD swizzle (1024%8==0)
    const int t = bid & 31;
    const int h = (bid >> 5) & (HH - 1);
    const int b = bid >> 9;
    const int s0 = t * QT;

    const int tid = threadIdx.x;
    const int wid = tid >> 6, lane = tid & 63;
    const int l15 = lane & 15, lg = lane >> 4;

    // ---- stage K rows + V transposed ----
    for (int i = tid; i < KROWS * 16; i += 256) {
        const int row = i >> 4, c4 = (i & 15) * 4;
        const int pos = s0 - WIN + row;
        float4 kv = make_float4(0.f, 0.f, 0.f, 0.f), vv = kv;
        if (pos >= 0 && pos < SS) {
            const float* base = qkv + (size_t)(b * SS + pos) * (3 * DD) + h * DH + c4;
            kv = *(const float4*)(base + DD);
            vv = *(const float4*)(base + 2 * DD);
        }
        f16x4 kh;
        kh[0] = (f16)kv.x; kh[1] = (f16)kv.y; kh[2] = (f16)kv.z; kh[3] = (f16)kv.w;
        *(f16x4*)&Kl[row][c4] = kh;
        Vt[c4 + 0][row] = (f16)vv.x; Vt[c4 + 1][row] = (f16)vv.y;
        Vt[c4 + 2][row] = (f16)vv.z; Vt[c4 + 3][row] = (f16)vv.w;
    }
    // ---- stage sel K/V (exactly 256 items) ----
    {
        const int si = tid >> 4, c4 = (tid & 15) * 4;
        const float* base = sqkv + (size_t)(b * NSEL + si) * (3 * DD) + h * DH + c4;
        float4 kv = *(const float4*)(base + DD);
        float4 vv = *(const float4*)(base + 2 * DD);
        f16x4 kh;
        kh[0] = (f16)kv.x; kh[1] = (f16)kv.y; kh[2] = (f16)kv.z; kh[3] = (f16)kv.w;
        *(f16x4*)&sKl[si][c4] = kh;
        Vt[c4 + 0][96 + si] = (f16)vv.x; Vt[c4 + 1][96 + si] = (f16)vv.y;
        Vt[c4 + 2][96 + si] = (f16)vv.z; Vt[c4 + 3][96 + si] = (f16)vv.w;
    }
    // ---- zero Vt kv columns 112..127 (0 x garbage would NaN otherwise) ----
    for (int i = tid; i < DH * 16; i += 256)
        Vt[i >> 4][112 + (i & 15)] = (f16)0.f;

    // ---- Q fragments (registers, from fp32 global) ----
    f16x8 qf[2];
    {
        const float* qp = qkv + (size_t)(b * SS + s0 + wid * 16 + l15) * (3 * DD)
                        + h * DH + lg * 8;
#pragma unroll
        for (int kc = 0; kc < 2; ++kc) {
            float4 va = *(const float4*)(qp + kc * 32);
            float4 vb = *(const float4*)(qp + kc * 32 + 4);
            f16x8 q;
            q[0] = (f16)va.x; q[1] = (f16)va.y; q[2] = (f16)va.z; q[3] = (f16)va.w;
            q[4] = (f16)vb.x; q[5] = (f16)vb.y; q[6] = (f16)vb.z; q[7] = (f16)vb.w;
            qf[kc] = q;
        }
    }
    __syncthreads();

    // ---- QK^T swapped: D[kv][q] (rows=kv from K-operand, cols=q) ----
    f32x4 aqk[6], asel;
#pragma unroll
    for (int i = 0; i < 6; ++i) aqk[i] = (f32x4){0.f, 0.f, 0.f, 0.f};
    asel = (f32x4){0.f, 0.f, 0.f, 0.f};
#pragma unroll
    for (int kc = 0; kc < 2; ++kc) {
        const int ko = kc * 32 + lg * 8;
#pragma unroll
        for (int kvb = 0; kvb < 6; ++kvb) {
            f16x8 ka = *(const f16x8*)&Kl[kvb * 16 + l15][ko];
            aqk[kvb] = __builtin_amdgcn_mfma_f32_16x16x32_f16(ka, qf[kc], aqk[kvb], 0, 0, 0);
        }
        f16x8 ks = *(const f16x8*)&sKl[l15][ko];
        asel = __builtin_amdgcn_mfma_f32_16x16x32_f16(ks, qf[kc], asel, 0, 0, 0);
    }

    // ---- local softmax: q = wid*16+l15 (col), kv = kvb*16+lg*4+r (row) ----
    const int qt_ = wid * 16 + l15;
    float sc[6][4];
    float m = -INFINITY;
#pragma unroll
    for (int kvb = 0; kvb < 6; ++kvb)
#pragma unroll
        for (int r = 0; r < 4; ++r) {
            const int kv  = kvb * 16 + lg * 4 + r;
            const int pos = s0 - WIN + kv;
            const int dlt = kv - qt_;
            const bool ok = (dlt >= 0) & (dlt <= 32) & (pos >= 0) & (pos < SS);
            sc[kvb][r] = ok ? aqk[kvb][r] * SCALE : -INFINITY;
            m = fmaxf(m, sc[kvb][r]);
        }
    m = fmaxf(m, __shfl_xor(m, 16));
    m = fmaxf(m, __shfl_xor(m, 32));
    float sum = 0.f;
#pragma unroll
    for (int kvb = 0; kvb < 6; ++kvb)
#pragma unroll
        for (int r = 0; r < 4; ++r) {
            sc[kvb][r] = __expf(sc[kvb][r] - m);
            sum += sc[kvb][r];
        }
    sum += __shfl_xor(sum, 16);
    sum += __shfl_xor(sum, 32);
    const float inv1 = 1.f / sum;

    // ---- sel softmax (all 16 valid) ----
    float s2[4];
    float m2 = -INFINITY;
#pragma unroll
    for (int r = 0; r < 4; ++r) { s2[r] = asel[r] * SCALE; m2 = fmaxf(m2, s2[r]); }
    m2 = fmaxf(m2, __shfl_xor(m2, 16));
    m2 = fmaxf(m2, __shfl_xor(m2, 32));
    float sum2 = 0.f;
#pragma unroll
    for (int r = 0; r < 4; ++r) { s2[r] = __expf(s2[r] - m2); sum2 += s2[r]; }
    sum2 += __shfl_xor(sum2, 16);
    sum2 += __shfl_xor(sum2, 32);
    const float inv2 = 1.f / sum2;

    // ---- write P (pre-normalized), unified kv axis ----
#pragma unroll
    for (int kvb = 0; kvb < 6; ++kvb) {
        h2 p01, p23;
        p01[0] = (f16)(sc[kvb][0] * inv1); p01[1] = (f16)(sc[kvb][1] * inv1);
        p23[0] = (f16)(sc[kvb][2] * inv1); p23[1] = (f16)(sc[kvb][3] * inv1);
        *(h2*)&Pl[wid][l15][kvb * 16 + lg * 4]     = p01;
        *(h2*)&Pl[wid][l15][kvb * 16 + lg * 4 + 2] = p23;
    }
    {
        h2 g01, g23, z0;
        g01[0] = (f16)(s2[0] * inv2); g01[1] = (f16)(s2[1] * inv2);
        g23[0] = (f16)(s2[2] * inv2); g23[1] = (f16)(s2[3] * inv2);
        z0[0] = (f16)0.f; z0[1] = (f16)0.f;
        *(h2*)&Pl[wid][l15][96 + lg * 4]      = g01;
        *(h2*)&Pl[wid][l15][96 + lg * 4 + 2]  = g23;
        *(h2*)&Pl[wid][l15][112 + lg * 4]     = z0;
        *(h2*)&Pl[wid][l15][112 + lg * 4 + 2] = z0;
    }
    __syncthreads();

    // ---- PV: O[q][d] = P[q][kv] . Vt[d][kv], kv = 128 unified ----
    f32x4 ov[4];
#pragma unroll
    for (int i = 0; i < 4; ++i) ov[i] = (f32x4){0.f, 0.f, 0.f, 0.f};
#pragma unroll
    for (int kc = 0; kc < 4; ++kc) {
        const int ko = kc * 32 + lg * 8;
        f16x8 pa = *(const f16x8*)&Pl[wid][l15][ko];
#pragma unroll
        for (int db = 0; db < 4; ++db) {
            f16x8 vb = *(const f16x8*)&Vt[db * 16 + l15][ko];
            ov[db] = __builtin_amdgcn_mfma_f32_16x16x32_f16(pa, vb, ov[db], 0, 0, 0);
        }
    }

    // ---- store O: row q = s0+wid*16+lg*4+r, col d = db*16+l15 ----
    const size_t rbase = (size_t)(b * SS + s0 + wid * 16 + lg * 4);
#pragma unroll
    for (int r = 0; r < 4; ++r) {
        f16* op = attn + (rbase + r) * DD + h * DH + l15;
#pragma unroll
        for (int db = 0; db < 4; ++db)
            op[db * 16] = (f16)ov[db][r];
    }
}

extern "C" void kernel_launch(void* const* d_in, const int* in_sizes, int n_in,
                              void* d_out, int out_size, void* d_ws, size_t ws_size,
                              hipStream_t stream)
{
    const float* x       = (const float*)d_in[0];
    const float* qkv_w   = (const float*)d_in[1];
    const float* qkv_b   = (const float*)d_in[2];
    const float* c1_w    = (const float*)d_in[3];
    const float* c1_b    = (const float*)d_in[4];
    const float* c2_w    = (const float*)d_in[5];
    const float* c2_b    = (const float*)d_in[6];
    const float* score_w = (const float*)d_in[7];
    const float* score_b = (const float*)d_in[8];
    const float* out_w   = (const float*)d_in[9];
    const float* out_b   = (const float*)d_in[10];
    float* out = (float*)d_out;
    float* ws  = (float*)d_ws;

    // workspace layout (float units) — total 23,654,720 floats
    f16*   xh     = (f16*)ws;
    float* A1     = ws + 2097152;
    f16*   WTc1   = (f16*)A1;
    float* qkvb   = A1;
    f16*   attnf  = (f16*)(A1 + 12582912);
    float* A2     = ws + 18874368;          // 4,161,536 floats scratch
    float* part   = A2;
    f16*   qkv_wT = (f16*)A2;
    f16*   out_wT = (f16*)(A2 + 1572864);
    float* hidden = ws + 23035904;
    float* comp   = hidden + 260096;
    float* scores = comp + 260096;
    int*   topIdx = (int*)(scores + 256);
    float* sqkvb  = scores + 256 + 64;

    const int MROWS = BB * SS;        // 4096
    const int MSEL  = BB * NSEL;      // 32

    // 0. x -> f16 (serves c1 A-gather, qkv GEMM A)
    convert_f16<<<(MROWS * DD) / (256 * 4), 256, 0, stream>>>(x, xh, MROWS * DD);

    // 1. c1_w (32768 x 1024) -> f16 transposed (1024 x 32768)
    transpose_conv<<<dim3(DD / 32, CBS * DD / 32), 256, 0, stream>>>(
        c1_w, WTc1, CBS * DD, DD);

    // 2. c1: hidden partials via f16 MFMA, split-K 16
    gemm_c1<<<dim3(DD / 64, 2, C1_NZ), 256, 0, stream>>>(xh, WTc1, part);

    // 3. hidden = relu(sum partials + c1_b)
    reduce_partials<<<(MC * DD) / 256, 256, 0, stream>>>(
        part, c1_b, hidden, MC * DD, DD, C1_NZ, 1);

    // 4. c2 partials: hidden @ c2_w (254x1024, K=1024, split-K 16) [fp32 exact]
    gemm128<0><<<dim3(DD / 128, 2, 16), 256, 0, stream>>>(
        hidden, c2_w, nullptr, part, MC, DD, DD, nullptr, 0);

    // 5. compressed = sum partials + c2_b
    reduce_partials<<<(MC * DD) / 256, 256, 0, stream>>>(
        part, c2_b, comp, MC * DD, DD, 16, 0);

    // 6. scores
    score_kernel<<<MC, 256, 0, stream>>>(comp, score_w, score_b, scores);

    // 7. top-16 per batch
    topk_kernel<<<BB, 128, 0, stream>>>(scores, topIdx);

    // 8. sqkv partials: selected @ qkv_w  (32 x 3072, K=1024, split-K 16)
    gemm128<2><<<dim3(3 * DD / 128, 1, 16), 256, 0, stream>>>(
        comp, qkv_w, nullptr, part, MSEL, 3 * DD, DD, topIdx, 0);

    // 8b. sqkv = sum partials + qkv_b
    reduce_partials<<<(MSEL * 3 * DD + 255) / 256, 256, 0, stream>>>(
        part, qkv_b, sqkvb, MSEL * 3 * DD, 3 * DD, 16, 0);

    // 9. weight transposes for the f16 MFMA GEMMs (A2 partials now dead)
    transpose_conv<<<dim3(3 * DD / 32, DD / 32), 256, 0, stream>>>(
        qkv_w, qkv_wT, DD, 3 * DD);
    transpose_conv<<<dim3(DD / 32, DD / 32), 256, 0, stream>>>(
        out_w, out_wT, DD, DD);

    // 10. qkv = x @ qkv_w + qkv_b (4096 x 3072, K=1024) [f16 MFMA]
    gemm_f16<<<dim3(3 * DD / 128, MROWS / 128), 256, 0, stream>>>(
        xh, qkv_wT, qkv_b, qkvb, MROWS, 3 * DD, DD);

    // 11. attention on matrix cores -> f16 directly
    attn_mfma<<<BB * HH * (SS / QT), 256, 0, stream>>>(qkvb, sqkvb, attnf);

    // 12. out = attn @ out_w + out_b  (4096 x 1024, K=1024) [f16 MFMA]
    gemm_f16<<<dim3(DD / 128, MROWS / 128), 256, 0, stream>>>(
        attnf, out_wT, out_b, out, MROWS, DD, DD);
}

// Round 7
// 220.023 us; speedup vs baseline: 3.5117x; 1.1742x over previous
//
#include <hip/hip_runtime.h>
#include <math.h>

// Problem constants
#define BB   2
#define SS   2048
#define DD   1024
#define HH   16
#define DH   64
#define CBS  32
#define STRIDEC 16
#define NBLK 127          // (S - CBS)/STRIDE + 1
#define NSEL 16
#define WIN  16
#define NW   33           // 2*WIN+1
#define SCALE 0.125f      // DH^-0.5
#define MC   254          // BB * NBLK

typedef _Float16 f16;
typedef __attribute__((ext_vector_type(8))) _Float16 f16x8;
typedef __attribute__((ext_vector_type(4))) _Float16 f16x4;
typedef __attribute__((ext_vector_type(2))) _Float16 h2;
typedef __attribute__((ext_vector_type(4))) float f32x4;

// ---------------------------------------------------------------------------
// fp32 -> f16 elementwise convert (float4 loads, 4 elems/thread)
// ---------------------------------------------------------------------------
__global__ __launch_bounds__(256) void convert_f16(
    const float* __restrict__ src, f16* __restrict__ dst, int n)
{
    const int i = (blockIdx.x * 256 + threadIdx.x) * 4;
    if (i >= n) return;
    float4 v = *(const float4*)(src + i);
    f16x4 o;
    o[0] = (f16)v.x; o[1] = (f16)v.y; o[2] = (f16)v.z; o[3] = (f16)v.w;
    *(f16x4*)(dst + i) = o;
}

// ---------------------------------------------------------------------------
// fp32 (K x N) -> f16 (N x K) transpose-convert, 32x32 LDS tiles
// (still used for the small qkv_w / out_w transposes)
// ---------------------------------------------------------------------------
__global__ __launch_bounds__(256) void transpose_conv(
    const float* __restrict__ src, f16* __restrict__ dst, int K, int N)
{
    __shared__ float t[32][33];
    const int n0 = blockIdx.x * 32, k0 = blockIdx.y * 32;
    const int tx = threadIdx.x & 31, ty = threadIdx.x >> 5;   // 32 x 8
#pragma unroll
    for (int r = 0; r < 32; r += 8)
        t[ty + r][tx] = src[(size_t)(k0 + ty + r) * N + n0 + tx];
    __syncthreads();
#pragma unroll
    for (int r = 0; r < 32; r += 8)
        dst[(size_t)(n0 + ty + r) * K + k0 + tx] = (f16)t[tx][ty + r];
}

// ---------------------------------------------------------------------------
// f16 MFMA GEMM, m97-style: 128x128 tile, BK=64, 4 waves (2x2), each wave
// 64x64 via 4x4 frags of 16x16x32.  A: M x K f16 row-major.  Bt: N x K f16
// row-major (B transposed).  C: fp32 (+bias) or f16 (+bias) per OUT16.
// ---------------------------------------------------------------------------
template<int OUT16>
__global__ __launch_bounds__(256) void gemm_f16(
    const f16* __restrict__ A, const f16* __restrict__ Bt,
    const float* __restrict__ bias, float* __restrict__ C,
    int M, int N, int K)
{
    constexpr int BK = 64;
    __shared__ f16 As[128 * BK];
    __shared__ f16 Bs[128 * BK];
    const int tid  = threadIdx.x;
    const int wid  = tid >> 6, lane = tid & 63;
    const int bm = blockIdx.y * 128, bn = blockIdx.x * 128;
    const int wm = (wid >> 1) * 64, wn = (wid & 1) * 64;

    const int lrow = lane >> 3;        // 0..7 (row within 8-row segment)
    const int lk8  = (lane & 7) * 8;   // k-element offset of this lane's 16B

    f32x4 acc[4][4];
#pragma unroll
    for (int i = 0; i < 4; ++i)
#pragma unroll
        for (int j = 0; j < 4; ++j) acc[i][j] = (f32x4){0.f, 0.f, 0.f, 0.f};

    for (int kt = 0; kt < K; kt += BK) {
#pragma unroll
        for (int c = 0; c < 4; ++c) {
            const int seg = c * 4 + wid;            // 0..15 -> rows seg*8..+8
            const int row = seg * 8 + lrow;
            const f16* ga = A + (size_t)(bm + row) * K + kt + lk8;
            __builtin_amdgcn_global_load_lds(
                (const __attribute__((address_space(1))) void*)(const void*)ga,
                (__attribute__((address_space(3))) void*)(void*)(As + seg * 512),
                16, 0, 0);
            const f16* gb = Bt + (size_t)(bn + row) * K + kt + lk8;
            __builtin_amdgcn_global_load_lds(
                (const __attribute__((address_space(1))) void*)(const void*)gb,
                (__attribute__((address_space(3))) void*)(void*)(Bs + seg * 512),
                16, 0, 0);
        }
        __syncthreads();   // compiler drains vmcnt before s_barrier

#pragma unroll
        for (int kk = 0; kk < 2; ++kk) {
            const int ko = kk * 32 + (lane >> 4) * 8;
            f16x8 a[4], b[4];
#pragma unroll
            for (int i = 0; i < 4; ++i)
                a[i] = *(const f16x8*)(As + (wm + i * 16 + (lane & 15)) * BK + ko);
#pragma unroll
            for (int j = 0; j < 4; ++j)
                b[j] = *(const f16x8*)(Bs + (wn + j * 16 + (lane & 15)) * BK + ko);
#pragma unroll
            for (int i = 0; i < 4; ++i)
#pragma unroll
                for (int j = 0; j < 4; ++j)
                    acc[i][j] = __builtin_amdgcn_mfma_f32_16x16x32_f16(
                        a[i], b[j], acc[i][j], 0, 0, 0);
        }
        __syncthreads();
    }

    const int rr0 = (lane >> 4) * 4;
    const int cc  = lane & 15;
#pragma unroll
    for (int i = 0; i < 4; ++i) {
        const int r = bm + wm + i * 16 + rr0;
#pragma unroll
        for (int j = 0; j < 4; ++j) {
            const int cn = bn + wn + j * 16 + cc;
            const float bv = bias[cn];
#pragma unroll
            for (int q = 0; q < 4; ++q) {
                if constexpr (OUT16)
                    ((f16*)C)[(size_t)(r + q) * N + cn] = (f16)(acc[i][j][q] + bv);
                else
                    C[(size_t)(r + q) * N + cn] = acc[i][j][q] + bv;
            }
        }
    }
}

// ---------------------------------------------------------------------------
// c1 compression GEMM, f16 MFMA, fp32 split-K accumulate.  B (c1_w fp32 KxN)
// is converted + transposed INTO LDS on the fly (kills the 201 MB WTc1
// transpose round-trip).  Bs: stride-72 + XOR swizzle (c ^= ((n>>3)&3)<<3
// in halves) -> staging ds_write_b32 2-way, frag ds_read b128 2-way (free),
// 16B alignment preserved.
// ---------------------------------------------------------------------------
#define C1_NZ 16
#define C1_KCHUNK 2048     // 32768 / 16

__global__ __launch_bounds__(256) void gemm_c1(
    const f16* __restrict__ xh, const float* __restrict__ c1w,
    float* __restrict__ P)
{
    constexpr int BK = 64;
    constexpr int BSTR = 72;          // halves (144 B rows)
    __shared__ f16 As[128 * BK];      // 16 KB
    __shared__ f16 Bs[64 * BSTR];     // 9216 B
    const int tid  = threadIdx.x;
    const int wid  = tid >> 6, lane = tid & 63;
    const int bn = blockIdx.x * 64, bm = blockIdx.y * 128;
    const int z  = blockIdx.z;
    const int wm = (wid >> 1) * 64, wn = (wid & 1) * 32;

    const int lrow = lane >> 3;
    const int lk8  = (lane & 7) * 8;

    f32x4 acc[4][2];
#pragma unroll
    for (int i = 0; i < 4; ++i)
#pragma unroll
        for (int j = 0; j < 2; ++j) acc[i][j] = (f32x4){0.f, 0.f, 0.f, 0.f};

    for (int t = 0; t < C1_KCHUNK / BK; ++t) {
        const int ktg = z * C1_KCHUNK + t * BK;
        const int kc  = (ktg + lk8) >> 10;       // x feature-row within block
        const int kd  = (ktg + lk8) & 1023;      // x col
        // ---- stage A (gathered xh rows, global_load_lds, linear) ----
#pragma unroll
        for (int c = 0; c < 4; ++c) {
            const int seg = c * 4 + wid;
            int row = bm + seg * 8 + lrow;
            if (row > MC - 1) row = MC - 1;       // pad rows 254/255 (dup, unstored)
            const int b   = (row >= NBLK) ? 1 : 0;
            const int blk = row - b * NBLK;
            const f16* ga = xh + ((size_t)(b * SS + blk * STRIDEC + kc) << 10) + kd;
            __builtin_amdgcn_global_load_lds(
                (const __attribute__((address_space(1))) void*)(const void*)ga,
                (__attribute__((address_space(3))) void*)(void*)(As + seg * 512),
                16, 0, 0);
        }
        // ---- stage B: fp32 c1_w (KxN) -> f16 transposed into Bs[n][kk] ----
        {
            const int kk0 = (tid >> 4) * 2;       // 0..30 even
            const int n4  = (tid & 15) * 4;
#pragma unroll
            for (int p = 0; p < 2; ++p) {
                const int kk = kk0 + p * 32;
                const float* gB = c1w + (size_t)(ktg + kk) * DD + bn + n4;
                float4 r0 = *(const float4*)gB;
                float4 r1 = *(const float4*)(gB + DD);
                const float a0[4] = {r0.x, r0.y, r0.z, r0.w};
                const float a1[4] = {r1.x, r1.y, r1.z, r1.w};
#pragma unroll
                for (int u = 0; u < 4; ++u) {
                    const int n = n4 + u;
                    h2 w; w[0] = (f16)a0[u]; w[1] = (f16)a1[u];
                    *(h2*)&Bs[n * BSTR + (kk ^ (((n >> 3) & 3) << 3))] = w;
                }
            }
        }
        __syncthreads();

#pragma unroll
        for (int kk = 0; kk < 2; ++kk) {
            const int ko = kk * 32 + (lane >> 4) * 8;
            f16x8 a[4], b[2];
#pragma unroll
            for (int i = 0; i < 4; ++i)
                a[i] = *(const f16x8*)(As + (wm + i * 16 + (lane & 15)) * BK + ko);
#pragma unroll
            for (int j = 0; j < 2; ++j) {
                const int n = wn + j * 16 + (lane & 15);
                b[j] = *(const f16x8*)&Bs[n * BSTR + (ko ^ (((n >> 3) & 3) << 3))];
            }
#pragma unroll
            for (int i = 0; i < 4; ++i)
#pragma unroll
                for (int j = 0; j < 2; ++j)
                    acc[i][j] = __builtin_amdgcn_mfma_f32_16x16x32_f16(
                        a[i], b[j], acc[i][j], 0, 0, 0);
        }
        __syncthreads();
    }

    const int rr0 = (lane >> 4) * 4;
    const int cc  = lane & 15;
#pragma unroll
    for (int i = 0; i < 4; ++i) {
        const int r = bm + wm + i * 16 + rr0;
#pragma unroll
        for (int j = 0; j < 2; ++j) {
            const int cn = bn + wn + j * 16 + cc;
#pragma unroll
            for (int q = 0; q < 4; ++q)
                if (r + q < MC)
                    P[((size_t)z * MC + r + q) * DD + cn] = acc[i][j][q];
        }
    }
}

// ---------------------------------------------------------------------------
// fp32 tiled GEMM 128x128 — small fp32-exact kernels: c2 (MODE 0) and
// sqkv (MODE 2), both split-K (gridDim.z partials).
// ---------------------------------------------------------------------------
template<int MODE>
__global__ __launch_bounds__(256) void gemm128(
    const float* __restrict__ A, const float* __restrict__ Bm,
    const float* __restrict__ bias, float* __restrict__ C,
    int M, int N, int K, const int* __restrict__ selIdx, int flags)
{
    __shared__ float As[8][132];
    __shared__ float Bs[8][132];

    const int tid = threadIdx.x;
    const int bm = blockIdx.y * 128;
    const int bn = blockIdx.x * 128;
    const int nz = gridDim.z;
    const int z  = blockIdx.z;
    const int kchunk = K / nz;
    const int k0 = z * kchunk;
    const int kend = k0 + kchunk;

    const int tx = tid & 15;
    const int ty = tid >> 4;

    const int arow = tid >> 1;
    const int akq  = (tid & 1) * 4;
    const int bkr  = tid >> 5;
    const int bcol = (tid & 31) * 4;

    float acc[2][2][4][4];
#pragma unroll
    for (int qi = 0; qi < 2; ++qi)
#pragma unroll
        for (int qj = 0; qj < 2; ++qj)
#pragma unroll
            for (int i = 0; i < 4; ++i)
#pragma unroll
                for (int j = 0; j < 4; ++j) acc[qi][qj][i][j] = 0.f;

    auto loadA = [&](int kt) -> float4 {
        float4 av = make_float4(0.f, 0.f, 0.f, 0.f);
        const int grow = bm + arow;
        if (grow < M) {
            if constexpr (MODE == 0) {
                av = *(const float4*)(A + (size_t)grow * K + kt + akq);
            } else {
                const int b = grow >> 4;
                const int j = grow & 15;
                const int idx = selIdx[b * NSEL + j];
                av = *(const float4*)(A + (size_t)(b * NBLK + idx) * K + kt + akq);
            }
        }
        return av;
    };
    auto loadB = [&](int kt) -> float4 {
        return *(const float4*)(Bm + (size_t)(kt + bkr) * N + bn + bcol);
    };

    float4 av = loadA(k0);
    float4 bv = loadB(k0);

    for (int kt = k0; kt < kend; kt += 8) {
        As[akq + 0][arow] = av.x;
        As[akq + 1][arow] = av.y;
        As[akq + 2][arow] = av.z;
        As[akq + 3][arow] = av.w;
        *(float4*)&Bs[bkr][bcol] = bv;
        __syncthreads();
        if (kt + 8 < kend) {
            av = loadA(kt + 8);
            bv = loadB(kt + 8);
        }
#pragma unroll
        for (int k = 0; k < 8; ++k) {
            const float4 a0 = *(const float4*)&As[k][ty * 4];
            const float4 a1 = *(const float4*)&As[k][64 + ty * 4];
            const float4 b0 = *(const float4*)&Bs[k][tx * 4];
            const float4 b1 = *(const float4*)&Bs[k][64 + tx * 4];
            const float ar[2][4] = {{a0.x, a0.y, a0.z, a0.w},
                                    {a1.x, a1.y, a1.z, a1.w}};
            const float br[2][4] = {{b0.x, b0.y, b0.z, b0.w},
                                    {b1.x, b1.y, b1.z, b1.w}};
#pragma unroll
            for (int qi = 0; qi < 2; ++qi)
#pragma unroll
                for (int i = 0; i < 4; ++i)
#pragma unroll
                    for (int qj = 0; qj < 2; ++qj)
#pragma unroll
                        for (int j = 0; j < 4; ++j)
                            acc[qi][qj][i][j] += ar[qi][i] * br[qj][j];
        }
        __syncthreads();
    }

    if (nz == 1) {
        const bool hasB   = (flags & 1) != 0;
        const bool doRelu = (flags & 2) != 0;
#pragma unroll
        for (int qi = 0; qi < 2; ++qi)
#pragma unroll
            for (int i = 0; i < 4; ++i) {
                const int r = bm + qi * 64 + ty * 4 + i;
                if (r >= M) continue;
#pragma unroll
                for (int qj = 0; qj < 2; ++qj)
#pragma unroll
                    for (int j = 0; j < 4; ++j) {
                        const int cn = bn + qj * 64 + tx * 4 + j;
                        float v = acc[qi][qj][i][j];
                        if (hasB) v += bias[cn];
                        if (doRelu) v = fmaxf(v, 0.f);
                        C[(size_t)r * N + cn] = v;
                    }
            }
    } else {
        float* P = C + (size_t)z * M * N;
#pragma unroll
        for (int qi = 0; qi < 2; ++qi)
#pragma unroll
            for (int i = 0; i < 4; ++i) {
                const int r = bm + qi * 64 + ty * 4 + i;
                if (r >= M) continue;
#pragma unroll
                for (int qj = 0; qj < 2; ++qj)
#pragma unroll
                    for (int j = 0; j < 4; ++j) {
                        const int cn = bn + qj * 64 + tx * 4 + j;
                        P[(size_t)r * N + cn] = acc[qi][qj][i][j];
                    }
            }
    }
}

// Sum split-K partials + bias (+relu); halfOut -> write f16
__global__ __launch_bounds__(256) void reduce_partials(
    const float* __restrict__ P, const float* __restrict__ bias,
    float* __restrict__ outp, int MN, int N, int nz, int doRelu, int halfOut)
{
    const int i = blockIdx.x * 256 + threadIdx.x;
    if (i >= MN) return;
    float s = 0.f;
    for (int z = 0; z < nz; ++z) s += P[(size_t)z * MN + i];
    s += bias[i % N];
    if (doRelu) s = fmaxf(s, 0.f);
    if (halfOut) ((f16*)outp)[i] = (f16)s;
    else         outp[i] = s;
}

// scores[row] = compressed[row,:] . score_w + score_b
__global__ __launch_bounds__(256) void score_kernel(
    const float* __restrict__ comp, const float* __restrict__ sw,
    const float* __restrict__ sb, float* __restrict__ scores)
{
    const int row = blockIdx.x;
    const float* cp = comp + (size_t)row * DD;
    float s = 0.f;
    for (int k = threadIdx.x; k < DD; k += 256) s += cp[k] * sw[k];
#pragma unroll
    for (int off = 32; off >= 1; off >>= 1) s += __shfl_xor(s, off);
    __shared__ float red[4];
    if ((threadIdx.x & 63) == 0) red[threadIdx.x >> 6] = s;
    __syncthreads();
    if (threadIdx.x == 0) scores[row] = red[0] + red[1] + red[2] + red[3] + sb[0];
}

// top-16 of 127 scores per batch (set semantics; lowest-index tie-break)
__global__ __launch_bounds__(128) void topk_kernel(
    const float* __restrict__ scores, int* __restrict__ top)
{
    const int b = blockIdx.x;
    const int t = threadIdx.x;  // 128
    __shared__ float sval[128];
    __shared__ float sv2[128];
    __shared__ int   si2[128];
    __shared__ unsigned char used[128];
    sval[t] = (t < NBLK) ? scores[b * NBLK + t] : -INFINITY;
    used[t] = 0;
    __syncthreads();
    for (int j = 0; j < NSEL; ++j) {
        sv2[t] = used[t] ? -INFINITY : sval[t];
        si2[t] = t;
        __syncthreads();
        for (int stp = 64; stp >= 1; stp >>= 1) {
            if (t < stp) {
                if (sv2[t + stp] > sv2[t] ||
                    (sv2[t + stp] == sv2[t] && si2[t + stp] < si2[t])) {
                    sv2[t] = sv2[t + stp];
                    si2[t] = si2[t + stp];
                }
            }
            __syncthreads();
        }
        if (t == 0) { top[b * NSEL + j] = si2[0]; used[si2[0]] = 1; }
        __syncthreads();
    }
}

// ---------------------------------------------------------------------------
// Attention v5 (MFMA, f16 I/O): block = 4 waves, one (b,h,64-query tile).
// qkv/sqkv are f16 now: Q frags are raw f16x8 loads, K/V staging pure copies.
// ---------------------------------------------------------------------------
#define QT 64
#define KROWS 96   // QT + 2*WIN
#define KST2 72    // K/sK row stride in halves (144 B)
#define VST 136    // Vt row stride in halves
#define PST 136    // P row stride in halves

__global__ __launch_bounds__(256) void attn_mfma(
    const f16* __restrict__ qkv, const f16* __restrict__ sqkv,
    f16* __restrict__ attn)
{
    __shared__ f16 Kl[KROWS][KST2];      // 13824 B
    __shared__ f16 sKl[NSEL][KST2];      //  2304 B
    __shared__ f16 Vt[DH][VST];          // 17408 B  (cols: 0..95 win, 96..111 sel, 112..127 zero)
    __shared__ f16 Pl[4][16][PST];       // 17408 B  per-wave P[q16][kv128]

    int bid = blockIdx.x;
    bid = (bid & 7) * (gridDim.x >> 3) + (bid >> 3);   // XCD swizzle (1024%8==0)
    const int t = bid & 31;
    const int h = (bid >> 5) & (HH - 1);
    const int b = bid >> 9;
    const int s0 = t * QT;

    const int tid = threadIdx.x;
    const int wid = tid >> 6, lane = tid & 63;
    const int l15 = lane & 15, lg = lane >> 4;

    // ---- stage K rows + V transposed (f16 -> f16 copies) ----
    for (int i = tid; i < KROWS * 8; i += 256) {
        const int row = i >> 3, c8 = (i & 7) * 8;
        const int pos = s0 - WIN + row;
        f16x8 kv, vv;
#pragma unroll
        for (int u = 0; u < 8; ++u) { kv[u] = (f16)0.f; vv[u] = (f16)0.f; }
        if (pos >= 0 && pos < SS) {
            const f16* base = qkv + (size_t)(b * SS + pos) * (3 * DD) + h * DH + c8;
            kv = *(const f16x8*)(base + DD);
            vv = *(const f16x8*)(base + 2 * DD);
        }
        *(f16x8*)&Kl[row][c8] = kv;
#pragma unroll
        for (int u = 0; u < 8; ++u) Vt[c8 + u][row] = vv[u];
    }
    // ---- stage sel K/V (128 items) ----
    if (tid < NSEL * 8) {
        const int si = tid >> 3, c8 = (tid & 7) * 8;
        const f16* base = sqkv + (size_t)(b * NSEL + si) * (3 * DD) + h * DH + c8;
        f16x8 kv = *(const f16x8*)(base + DD);
        f16x8 vv = *(const f16x8*)(base + 2 * DD);
        *(f16x8*)&sKl[si][c8] = kv;
#pragma unroll
        for (int u = 0; u < 8; ++u) Vt[c8 + u][96 + si] = vv[u];
    }
    // ---- zero Vt kv columns 112..127 ----
    for (int i = tid; i < DH * 16; i += 256)
        Vt[i >> 4][112 + (i & 15)] = (f16)0.f;

    // ---- Q fragments: raw f16x8 loads ----
    f16x8 qf[2];
    {
        const f16* qp = qkv + (size_t)(b * SS + s0 + wid * 16 + l15) * (3 * DD)
                      + h * DH + lg * 8;
        qf[0] = *(const f16x8*)(qp);
        qf[1] = *(const f16x8*)(qp + 32);
    }
    __syncthreads();

    // ---- QK^T swapped: D[kv][q] ----
    f32x4 aqk[6], asel;
#pragma unroll
    for (int i = 0; i < 6; ++i) aqk[i] = (f32x4){0.f, 0.f, 0.f, 0.f};
    asel = (f32x4){0.f, 0.f, 0.f, 0.f};
#pragma unroll
    for (int kc = 0; kc < 2; ++kc) {
        const int ko = kc * 32 + lg * 8;
#pragma unroll
        for (int kvb = 0; kvb < 6; ++kvb) {
            f16x8 ka = *(const f16x8*)&Kl[kvb * 16 + l15][ko];
            aqk[kvb] = __builtin_amdgcn_mfma_f32_16x16x32_f16(ka, qf[kc], aqk[kvb], 0, 0, 0);
        }
        f16x8 ks = *(const f16x8*)&sKl[l15][ko];
        asel = __builtin_amdgcn_mfma_f32_16x16x32_f16(ks, qf[kc], asel, 0, 0, 0);
    }

    // ---- local softmax: q = wid*16+l15 (col), kv = kvb*16+lg*4+r (row) ----
    const int qt_ = wid * 16 + l15;
    float sc[6][4];
    float m = -INFINITY;
#pragma unroll
    for (int kvb = 0; kvb < 6; ++kvb)
#pragma unroll
        for (int r = 0; r < 4; ++r) {
            const int kv  = kvb * 16 + lg * 4 + r;
            const int pos = s0 - WIN + kv;
            const int dlt = kv - qt_;
            const bool ok = (dlt >= 0) & (dlt <= 32) & (pos >= 0) & (pos < SS);
            sc[kvb][r] = ok ? aqk[kvb][r] * SCALE : -INFINITY;
            m = fmaxf(m, sc[kvb][r]);
        }
    m = fmaxf(m, __shfl_xor(m, 16));
    m = fmaxf(m, __shfl_xor(m, 32));
    float sum = 0.f;
#pragma unroll
    for (int kvb = 0; kvb < 6; ++kvb)
#pragma unroll
        for (int r = 0; r < 4; ++r) {
            sc[kvb][r] = __expf(sc[kvb][r] - m);
            sum += sc[kvb][r];
        }
    sum += __shfl_xor(sum, 16);
    sum += __shfl_xor(sum, 32);
    const float inv1 = 1.f / sum;

    // ---- sel softmax (all 16 valid) ----
    float s2[4];
    float m2 = -INFINITY;
#pragma unroll
    for (int r = 0; r < 4; ++r) { s2[r] = asel[r] * SCALE; m2 = fmaxf(m2, s2[r]); }
    m2 = fmaxf(m2, __shfl_xor(m2, 16));
    m2 = fmaxf(m2, __shfl_xor(m2, 32));
    float sum2 = 0.f;
#pragma unroll
    for (int r = 0; r < 4; ++r) { s2[r] = __expf(s2[r] - m2); sum2 += s2[r]; }
    sum2 += __shfl_xor(sum2, 16);
    sum2 += __shfl_xor(sum2, 32);
    const float inv2 = 1.f / sum2;

    // ---- write P (pre-normalized); Pl is wave-private -> no barrier needed ----
#pragma unroll
    for (int kvb = 0; kvb < 6; ++kvb) {
        h2 p01, p23;
        p01[0] = (f16)(sc[kvb][0] * inv1); p01[1] = (f16)(sc[kvb][1] * inv1);
        p23[0] = (f16)(sc[kvb][2] * inv1); p23[1] = (f16)(sc[kvb][3] * inv1);
        *(h2*)&Pl[wid][l15][kvb * 16 + lg * 4]     = p01;
        *(h2*)&Pl[wid][l15][kvb * 16 + lg * 4 + 2] = p23;
    }
    {
        h2 g01, g23, z0;
        g01[0] = (f16)(s2[0] * inv2); g01[1] = (f16)(s2[1] * inv2);
        g23[0] = (f16)(s2[2] * inv2); g23[1] = (f16)(s2[3] * inv2);
        z0[0] = (f16)0.f; z0[1] = (f16)0.f;
        *(h2*)&Pl[wid][l15][96 + lg * 4]      = g01;
        *(h2*)&Pl[wid][l15][96 + lg * 4 + 2]  = g23;
        *(h2*)&Pl[wid][l15][112 + lg * 4]     = z0;
        *(h2*)&Pl[wid][l15][112 + lg * 4 + 2] = z0;
    }
    // (no __syncthreads: per-wave LDS ops complete in order; Vt/Kl reads done)

    // ---- PV: O[q][d] = P[q][kv] . Vt[d][kv], kv = 128 unified ----
    f32x4 ov[4];
#pragma unroll
    for (int i = 0; i < 4; ++i) ov[i] = (f32x4){0.f, 0.f, 0.f, 0.f};
#pragma unroll
    for (int kc = 0; kc < 4; ++kc) {
        const int ko = kc * 32 + lg * 8;
        f16x8 pa = *(const f16x8*)&Pl[wid][l15][ko];
#pragma unroll
        for (int db = 0; db < 4; ++db) {
            f16x8 vb = *(const f16x8*)&Vt[db * 16 + l15][ko];
            ov[db] = __builtin_amdgcn_mfma_f32_16x16x32_f16(pa, vb, ov[db], 0, 0, 0);
        }
    }

    // ---- store O: row q = s0+wid*16+lg*4+r, col d = db*16+l15 ----
    const size_t rbase = (size_t)(b * SS + s0 + wid * 16 + lg * 4);
#pragma unroll
    for (int r = 0; r < 4; ++r) {
        f16* op = attn + (rbase + r) * DD + h * DH + l15;
#pragma unroll
        for (int db = 0; db < 4; ++db)
            op[db * 16] = (f16)ov[db][r];
    }
}

extern "C" void kernel_launch(void* const* d_in, const int* in_sizes, int n_in,
                              void* d_out, int out_size, void* d_ws, size_t ws_size,
                              hipStream_t stream)
{
    const float* x       = (const float*)d_in[0];
    const float* qkv_w   = (const float*)d_in[1];
    const float* qkv_b   = (const float*)d_in[2];
    const float* c1_w    = (const float*)d_in[3];
    const float* c1_b    = (const float*)d_in[4];
    const float* c2_w    = (const float*)d_in[5];
    const float* c2_b    = (const float*)d_in[6];
    const float* score_w = (const float*)d_in[7];
    const float* score_b = (const float*)d_in[8];
    const float* out_w   = (const float*)d_in[9];
    const float* out_b   = (const float*)d_in[10];
    float* out = (float*)d_out;
    float* ws  = (float*)d_ws;

    // workspace layout (float units) — total 23,654,720 floats
    f16*   xh     = (f16*)ws;                   // 4096x1024 halves
    float* A1     = ws + 2097152;
    f16*   qkvb   = (f16*)A1;                   // 4096x3072 halves (6.29M floats)
    f16*   attnf  = (f16*)(A1 + 12582912);      // 4096x1024 halves
    float* A2     = ws + 18874368;              // 4,161,536 floats scratch
    float* part   = A2;
    f16*   qkv_wT = (f16*)A2;
    f16*   out_wT = (f16*)(A2 + 1572864);
    float* hidden = ws + 23035904;
    float* comp   = hidden + 260096;
    float* scores = comp + 260096;
    int*   topIdx = (int*)(scores + 256);
    float* sqkvb  = scores + 256 + 64;          // f16 region now

    const int MROWS = BB * SS;        // 4096
    const int MSEL  = BB * NSEL;      // 32

    // 0. x -> f16 (serves c1 A-gather, qkv GEMM A)
    convert_f16<<<(MROWS * DD) / (256 * 4), 256, 0, stream>>>(x, xh, MROWS * DD);

    // 1. c1: hidden partials via f16 MFMA, split-K 16; B transpose fused
    gemm_c1<<<dim3(DD / 64, 2, C1_NZ), 256, 0, stream>>>(xh, c1_w, part);

    // 2. hidden = relu(sum partials + c1_b)  [fp32 out]
    reduce_partials<<<(MC * DD) / 256, 256, 0, stream>>>(
        part, c1_b, hidden, MC * DD, DD, C1_NZ, 1, 0);

    // 3. c2 partials: hidden @ c2_w (254x1024, K=1024, split-K 16) [fp32 exact]
    gemm128<0><<<dim3(DD / 128, 2, 16), 256, 0, stream>>>(
        hidden, c2_w, nullptr, part, MC, DD, DD, nullptr, 0);

    // 4. compressed = sum partials + c2_b  [fp32 out]
    reduce_partials<<<(MC * DD) / 256, 256, 0, stream>>>(
        part, c2_b, comp, MC * DD, DD, 16, 0, 0);

    // 5. scores
    score_kernel<<<MC, 256, 0, stream>>>(comp, score_w, score_b, scores);

    // 6. top-16 per batch
    topk_kernel<<<BB, 128, 0, stream>>>(scores, topIdx);

    // 7. sqkv partials: selected @ qkv_w  (32 x 3072, K=1024, split-K 16)
    gemm128<2><<<dim3(3 * DD / 128, 1, 16), 256, 0, stream>>>(
        comp, qkv_w, nullptr, part, MSEL, 3 * DD, DD, topIdx, 0);

    // 7b. sqkv = sum partials + qkv_b  [f16 out]
    reduce_partials<<<(MSEL * 3 * DD + 255) / 256, 256, 0, stream>>>(
        part, qkv_b, sqkvb, MSEL * 3 * DD, 3 * DD, 16, 0, 1);

    // 8. weight transposes for the f16 MFMA GEMMs (A2 partials now dead)
    transpose_conv<<<dim3(3 * DD / 32, DD / 32), 256, 0, stream>>>(
        qkv_w, qkv_wT, DD, 3 * DD);
    transpose_conv<<<dim3(DD / 32, DD / 32), 256, 0, stream>>>(
        out_w, out_wT, DD, DD);

    // 9. qkv = x @ qkv_w + qkv_b (4096 x 3072, K=1024) [f16 MFMA, f16 out]
    gemm_f16<1><<<dim3(3 * DD / 128, MROWS / 128), 256, 0, stream>>>(
        xh, qkv_wT, qkv_b, (float*)qkvb, MROWS, 3 * DD, DD);

    // 10. attention on matrix cores (f16 I/O)
    attn_mfma<<<BB * HH * (SS / QT), 256, 0, stream>>>(
        qkvb, (const f16*)sqkvb, attnf);

    // 11. out = attn @ out_w + out_b  (4096 x 1024, K=1024) [f16 MFMA, fp32 out]
    gemm_f16<0><<<dim3(DD / 128, MROWS / 128), 256, 0, stream>>>(
        attnf, out_wT, out_b, out, MROWS, DD, DD);
}

// Round 9
// 218.458 us; speedup vs baseline: 3.5368x; 1.0072x over previous
//
#include <hip/hip_runtime.h>
#include <math.h>

// Problem constants
#define BB   2
#define SS   2048
#define DD   1024
#define HH   16
#define DH   64
#define CBS  32
#define STRIDEC 16
#define NBLK 127          // (S - CBS)/STRIDE + 1
#define NSEL 16
#define WIN  16
#define NW   33           // 2*WIN+1
#define SCALE 0.125f      // DH^-0.5
#define MC   254          // BB * NBLK

typedef _Float16 f16;
typedef __attribute__((ext_vector_type(8))) _Float16 f16x8;
typedef __attribute__((ext_vector_type(4))) _Float16 f16x4;
typedef __attribute__((ext_vector_type(2))) _Float16 h2;
typedef __attribute__((ext_vector_type(4))) float f32x4;

// ---------------------------------------------------------------------------
// fp32 -> f16 elementwise convert (float4 loads, 4 elems/thread)
// ---------------------------------------------------------------------------
__global__ __launch_bounds__(256) void convert_f16(
    const float* __restrict__ src, f16* __restrict__ dst, int n)
{
    const int i = (blockIdx.x * 256 + threadIdx.x) * 4;
    if (i >= n) return;
    float4 v = *(const float4*)(src + i);
    f16x4 o;
    o[0] = (f16)v.x; o[1] = (f16)v.y; o[2] = (f16)v.z; o[3] = (f16)v.w;
    *(f16x4*)(dst + i) = o;
}

// ---------------------------------------------------------------------------
// fp32 (K x N) -> f16 (N x K) transpose-convert, 32x32 LDS tiles
// ---------------------------------------------------------------------------
__global__ __launch_bounds__(256) void transpose_conv(
    const float* __restrict__ src, f16* __restrict__ dst, int K, int N)
{
    __shared__ float t[32][33];
    const int n0 = blockIdx.x * 32, k0 = blockIdx.y * 32;
    const int tx = threadIdx.x & 31, ty = threadIdx.x >> 5;   // 32 x 8
#pragma unroll
    for (int r = 0; r < 32; r += 8)
        t[ty + r][tx] = src[(size_t)(k0 + ty + r) * N + n0 + tx];
    __syncthreads();
#pragma unroll
    for (int r = 0; r < 32; r += 8)
        dst[(size_t)(n0 + ty + r) * K + k0 + tx] = (f16)t[tx][ty + r];
}

// ---------------------------------------------------------------------------
// f16 MFMA GEMM, m97-style: 128x128 tile, BK=64, 4 waves (2x2).  XCD-aware
// block swizzle (grid total % 8 == 0 for both call sites: 768, 256).
// ---------------------------------------------------------------------------
template<int OUT16>
__global__ __launch_bounds__(256) void gemm_f16(
    const f16* __restrict__ A, const f16* __restrict__ Bt,
    const float* __restrict__ bias, float* __restrict__ C,
    int M, int N, int K)
{
    constexpr int BK = 64;
    __shared__ f16 As[128 * BK];
    __shared__ f16 Bs[128 * BK];
    const int tid  = threadIdx.x;
    const int wid  = tid >> 6, lane = tid & 63;

    // XCD chunk swizzle on the linearized block id (bijective: nb % 8 == 0)
    int lin = blockIdx.y * gridDim.x + blockIdx.x;
    const int nb = gridDim.x * gridDim.y;
    lin = (lin & 7) * (nb >> 3) + (lin >> 3);
    const int bx = lin % gridDim.x, by = lin / gridDim.x;

    const int bm = by * 128, bn = bx * 128;
    const int wm = (wid >> 1) * 64, wn = (wid & 1) * 64;

    const int lrow = lane >> 3;        // 0..7 (row within 8-row segment)
    const int lk8  = (lane & 7) * 8;   // k-element offset of this lane's 16B

    f32x4 acc[4][4];
#pragma unroll
    for (int i = 0; i < 4; ++i)
#pragma unroll
        for (int j = 0; j < 4; ++j) acc[i][j] = (f32x4){0.f, 0.f, 0.f, 0.f};

    for (int kt = 0; kt < K; kt += BK) {
#pragma unroll
        for (int c = 0; c < 4; ++c) {
            const int seg = c * 4 + wid;            // 0..15 -> rows seg*8..+8
            const int row = seg * 8 + lrow;
            const f16* ga = A + (size_t)(bm + row) * K + kt + lk8;
            __builtin_amdgcn_global_load_lds(
                (const __attribute__((address_space(1))) void*)(const void*)ga,
                (__attribute__((address_space(3))) void*)(void*)(As + seg * 512),
                16, 0, 0);
            const f16* gb = Bt + (size_t)(bn + row) * K + kt + lk8;
            __builtin_amdgcn_global_load_lds(
                (const __attribute__((address_space(1))) void*)(const void*)gb,
                (__attribute__((address_space(3))) void*)(void*)(Bs + seg * 512),
                16, 0, 0);
        }
        __syncthreads();   // compiler drains vmcnt before s_barrier

#pragma unroll
        for (int kk = 0; kk < 2; ++kk) {
            const int ko = kk * 32 + (lane >> 4) * 8;
            f16x8 a[4], b[4];
#pragma unroll
            for (int i = 0; i < 4; ++i)
                a[i] = *(const f16x8*)(As + (wm + i * 16 + (lane & 15)) * BK + ko);
#pragma unroll
            for (int j = 0; j < 4; ++j)
                b[j] = *(const f16x8*)(Bs + (wn + j * 16 + (lane & 15)) * BK + ko);
#pragma unroll
            for (int i = 0; i < 4; ++i)
#pragma unroll
                for (int j = 0; j < 4; ++j)
                    acc[i][j] = __builtin_amdgcn_mfma_f32_16x16x32_f16(
                        a[i], b[j], acc[i][j], 0, 0, 0);
        }
        __syncthreads();
    }

    const int rr0 = (lane >> 4) * 4;
    const int cc  = lane & 15;
#pragma unroll
    for (int i = 0; i < 4; ++i) {
        const int r = bm + wm + i * 16 + rr0;
#pragma unroll
        for (int j = 0; j < 4; ++j) {
            const int cn = bn + wn + j * 16 + cc;
            const float bv = bias[cn];
#pragma unroll
            for (int q = 0; q < 4; ++q) {
                if constexpr (OUT16)
                    ((f16*)C)[(size_t)(r + q) * N + cn] = (f16)(acc[i][j][q] + bv);
                else
                    C[(size_t)(r + q) * N + cn] = acc[i][j][q] + bv;
            }
        }
    }
}

// ---------------------------------------------------------------------------
// c1 compression GEMM, f16 MFMA, fp32 split-K accumulate, B transpose fused.
// ---------------------------------------------------------------------------
#define C1_NZ 16
#define C1_KCHUNK 2048     // 32768 / 16

__global__ __launch_bounds__(256) void gemm_c1(
    const f16* __restrict__ xh, const float* __restrict__ c1w,
    float* __restrict__ P)
{
    constexpr int BK = 64;
    constexpr int BSTR = 72;          // halves (144 B rows)
    __shared__ f16 As[128 * BK];      // 16 KB
    __shared__ f16 Bs[64 * BSTR];     // 9216 B
    const int tid  = threadIdx.x;
    const int wid  = tid >> 6, lane = tid & 63;
    const int bn = blockIdx.x * 64, bm = blockIdx.y * 128;
    const int z  = blockIdx.z;
    const int wm = (wid >> 1) * 64, wn = (wid & 1) * 32;

    const int lrow = lane >> 3;
    const int lk8  = (lane & 7) * 8;

    f32x4 acc[4][2];
#pragma unroll
    for (int i = 0; i < 4; ++i)
#pragma unroll
        for (int j = 0; j < 2; ++j) acc[i][j] = (f32x4){0.f, 0.f, 0.f, 0.f};

    for (int t = 0; t < C1_KCHUNK / BK; ++t) {
        const int ktg = z * C1_KCHUNK + t * BK;
        const int kc  = (ktg + lk8) >> 10;       // x feature-row within block
        const int kd  = (ktg + lk8) & 1023;      // x col
#pragma unroll
        for (int c = 0; c < 4; ++c) {
            const int seg = c * 4 + wid;
            int row = bm + seg * 8 + lrow;
            if (row > MC - 1) row = MC - 1;       // pad rows 254/255 (dup, unstored)
            const int b   = (row >= NBLK) ? 1 : 0;
            const int blk = row - b * NBLK;
            const f16* ga = xh + ((size_t)(b * SS + blk * STRIDEC + kc) << 10) + kd;
            __builtin_amdgcn_global_load_lds(
                (const __attribute__((address_space(1))) void*)(const void*)ga,
                (__attribute__((address_space(3))) void*)(void*)(As + seg * 512),
                16, 0, 0);
        }
        // stage B: fp32 c1_w (KxN) -> f16 transposed into Bs[n][kk], XOR swz
        {
            const int kk0 = (tid >> 4) * 2;       // 0..30 even
            const int n4  = (tid & 15) * 4;
#pragma unroll
            for (int p = 0; p < 2; ++p) {
                const int kk = kk0 + p * 32;
                const float* gB = c1w + (size_t)(ktg + kk) * DD + bn + n4;
                float4 r0 = *(const float4*)gB;
                float4 r1 = *(const float4*)(gB + DD);
                const float a0[4] = {r0.x, r0.y, r0.z, r0.w};
                const float a1[4] = {r1.x, r1.y, r1.z, r1.w};
#pragma unroll
                for (int u = 0; u < 4; ++u) {
                    const int n = n4 + u;
                    h2 w; w[0] = (f16)a0[u]; w[1] = (f16)a1[u];
                    *(h2*)&Bs[n * BSTR + (kk ^ (((n >> 3) & 3) << 3))] = w;
                }
            }
        }
        __syncthreads();

#pragma unroll
        for (int kk = 0; kk < 2; ++kk) {
            const int ko = kk * 32 + (lane >> 4) * 8;
            f16x8 a[4], b[2];
#pragma unroll
            for (int i = 0; i < 4; ++i)
                a[i] = *(const f16x8*)(As + (wm + i * 16 + (lane & 15)) * BK + ko);
#pragma unroll
            for (int j = 0; j < 2; ++j) {
                const int n = wn + j * 16 + (lane & 15);
                b[j] = *(const f16x8*)&Bs[n * BSTR + (ko ^ (((n >> 3) & 3) << 3))];
            }
#pragma unroll
            for (int i = 0; i < 4; ++i)
#pragma unroll
                for (int j = 0; j < 2; ++j)
                    acc[i][j] = __builtin_amdgcn_mfma_f32_16x16x32_f16(
                        a[i], b[j], acc[i][j], 0, 0, 0);
        }
        __syncthreads();
    }

    const int rr0 = (lane >> 4) * 4;
    const int cc  = lane & 15;
#pragma unroll
    for (int i = 0; i < 4; ++i) {
        const int r = bm + wm + i * 16 + rr0;
#pragma unroll
        for (int j = 0; j < 2; ++j) {
            const int cn = bn + wn + j * 16 + cc;
#pragma unroll
            for (int q = 0; q < 4; ++q)
                if (r + q < MC)
                    P[((size_t)z * MC + r + q) * DD + cn] = acc[i][j][q];
        }
    }
}

// ---------------------------------------------------------------------------
// fp32 tiled GEMM 128x128 — small fp32-exact kernels: compSel (MODE 2,
// gather rows of `hidden` by topIdx) and sqkv (MODE 0), split-K partials.
// ---------------------------------------------------------------------------
template<int MODE>
__global__ __launch_bounds__(256) void gemm128(
    const float* __restrict__ A, const float* __restrict__ Bm,
    const float* __restrict__ bias, float* __restrict__ C,
    int M, int N, int K, const int* __restrict__ selIdx, int flags)
{
    __shared__ float As[8][132];
    __shared__ float Bs[8][132];

    const int tid = threadIdx.x;
    const int bm = blockIdx.y * 128;
    const int bn = blockIdx.x * 128;
    const int nz = gridDim.z;
    const int z  = blockIdx.z;
    const int kchunk = K / nz;
    const int k0 = z * kchunk;
    const int kend = k0 + kchunk;

    const int tx = tid & 15;
    const int ty = tid >> 4;

    const int arow = tid >> 1;
    const int akq  = (tid & 1) * 4;
    const int bkr  = tid >> 5;
    const int bcol = (tid & 31) * 4;

    float acc[2][2][4][4];
#pragma unroll
    for (int qi = 0; qi < 2; ++qi)
#pragma unroll
        for (int qj = 0; qj < 2; ++qj)
#pragma unroll
            for (int i = 0; i < 4; ++i)
#pragma unroll
                for (int j = 0; j < 4; ++j) acc[qi][qj][i][j] = 0.f;

    auto loadA = [&](int kt) -> float4 {
        float4 av = make_float4(0.f, 0.f, 0.f, 0.f);
        const int grow = bm + arow;
        if (grow < M) {
            if constexpr (MODE == 0) {
                av = *(const float4*)(A + (size_t)grow * K + kt + akq);
            } else {
                const int b = grow >> 4;
                const int j = grow & 15;
                const int idx = selIdx[b * NSEL + j];
                av = *(const float4*)(A + (size_t)(b * NBLK + idx) * K + kt + akq);
            }
        }
        return av;
    };
    auto loadB = [&](int kt) -> float4 {
        return *(const float4*)(Bm + (size_t)(kt + bkr) * N + bn + bcol);
    };

    float4 av = loadA(k0);
    float4 bv = loadB(k0);

    for (int kt = k0; kt < kend; kt += 8) {
        As[akq + 0][arow] = av.x;
        As[akq + 1][arow] = av.y;
        As[akq + 2][arow] = av.z;
        As[akq + 3][arow] = av.w;
        *(float4*)&Bs[bkr][bcol] = bv;
        __syncthreads();
        if (kt + 8 < kend) {
            av = loadA(kt + 8);
            bv = loadB(kt + 8);
        }
#pragma unroll
        for (int k = 0; k < 8; ++k) {
            const float4 a0 = *(const float4*)&As[k][ty * 4];
            const float4 a1 = *(const float4*)&As[k][64 + ty * 4];
            const float4 b0 = *(const float4*)&Bs[k][tx * 4];
            const float4 b1 = *(const float4*)&Bs[k][64 + tx * 4];
            const float ar[2][4] = {{a0.x, a0.y, a0.z, a0.w},
                                    {a1.x, a1.y, a1.z, a1.w}};
            const float br[2][4] = {{b0.x, b0.y, b0.z, b0.w},
                                    {b1.x, b1.y, b1.z, b1.w}};
#pragma unroll
            for (int qi = 0; qi < 2; ++qi)
#pragma unroll
                for (int i = 0; i < 4; ++i)
#pragma unroll
                    for (int qj = 0; qj < 2; ++qj)
#pragma unroll
                        for (int j = 0; j < 4; ++j)
                            acc[qi][qj][i][j] += ar[qi][i] * br[qj][j];
        }
        __syncthreads();
    }

    if (nz == 1) {
        const bool hasB   = (flags & 1) != 0;
        const bool doRelu = (flags & 2) != 0;
#pragma unroll
        for (int qi = 0; qi < 2; ++qi)
#pragma unroll
            for (int i = 0; i < 4; ++i) {
                const int r = bm + qi * 64 + ty * 4 + i;
                if (r >= M) continue;
#pragma unroll
                for (int qj = 0; qj < 2; ++qj)
#pragma unroll
                    for (int j = 0; j < 4; ++j) {
                        const int cn = bn + qj * 64 + tx * 4 + j;
                        float v = acc[qi][qj][i][j];
                        if (hasB) v += bias[cn];
                        if (doRelu) v = fmaxf(v, 0.f);
                        C[(size_t)r * N + cn] = v;
                    }
            }
    } else {
        float* P = C + (size_t)z * M * N;
#pragma unroll
        for (int qi = 0; qi < 2; ++qi)
#pragma unroll
            for (int i = 0; i < 4; ++i) {
                const int r = bm + qi * 64 + ty * 4 + i;
                if (r >= M) continue;
#pragma unroll
                for (int qj = 0; qj < 2; ++qj)
#pragma unroll
                    for (int j = 0; j < 4; ++j) {
                        const int cn = bn + qj * 64 + tx * 4 + j;
                        P[(size_t)r * N + cn] = acc[qi][qj][i][j];
                    }
            }
    }
}

// Sum split-K partials + bias (+relu); halfOut -> write f16
__global__ __launch_bounds__(256) void reduce_partials(
    const float* __restrict__ P, const float* __restrict__ bias,
    float* __restrict__ outp, int MN, int N, int nz, int doRelu, int halfOut)
{
    const int i = blockIdx.x * 256 + threadIdx.x;
    if (i >= MN) return;
    float s = 0.f;
    for (int z = 0; z < nz; ++z) s += P[(size_t)z * MN + i];
    s += bias[i % N];
    if (doRelu) s = fmaxf(s, 0.f);
    if (halfOut) ((f16*)outp)[i] = (f16)s;
    else         outp[i] = s;
}

// w2s[k] = c2_w[k,:] . score_w   (row-dot; one block per k, coalesced)
// NOTE: this is (c2_w @ score_w) -- sum over COLUMNS weighted by score_w.
__global__ __launch_bounds__(256) void w2s_kernel(
    const float* __restrict__ c2w, const float* __restrict__ sw,
    float* __restrict__ w2s)
{
    const int k = blockIdx.x;
    const float* rp = c2w + (size_t)k * DD;
    float s = 0.f;
    for (int n = threadIdx.x; n < DD; n += 256) s += rp[n] * sw[n];
#pragma unroll
    for (int off = 32; off >= 1; off >>= 1) s += __shfl_xor(s, off);
    __shared__ float red[4];
    if ((threadIdx.x & 63) == 0) red[threadIdx.x >> 6] = s;
    __syncthreads();
    if (threadIdx.x == 0) w2s[k] = red[0] + red[1] + red[2] + red[3];
}

// scores[row] = hidden[row,:] . w2s   (constant offset c2_b.sw + score_b
// dropped: identical for all rows -> rank-invariant)
__global__ __launch_bounds__(256) void score2_kernel(
    const float* __restrict__ hidden, const float* __restrict__ w2s,
    float* __restrict__ scores)
{
    const int row = blockIdx.x;
    const float* hp = hidden + (size_t)row * DD;
    float s = 0.f;
    for (int k = threadIdx.x; k < DD; k += 256) s += hp[k] * w2s[k];
#pragma unroll
    for (int off = 32; off >= 1; off >>= 1) s += __shfl_xor(s, off);
    __shared__ float red[4];
    if ((threadIdx.x & 63) == 0) red[threadIdx.x >> 6] = s;
    __syncthreads();
    if (threadIdx.x == 0) scores[row] = red[0] + red[1] + red[2] + red[3];
}

// top-16 of 127 scores per batch (set semantics; lowest-index tie-break)
__global__ __launch_bounds__(128) void topk_kernel(
    const float* __restrict__ scores, int* __restrict__ top)
{
    const int b = blockIdx.x;
    const int t = threadIdx.x;  // 128
    __shared__ float sval[128];
    __shared__ float sv2[128];
    __shared__ int   si2[128];
    __shared__ unsigned char used[128];
    sval[t] = (t < NBLK) ? scores[b * NBLK + t] : -INFINITY;
    used[t] = 0;
    __syncthreads();
    for (int j = 0; j < NSEL; ++j) {
        sv2[t] = used[t] ? -INFINITY : sval[t];
        si2[t] = t;
        __syncthreads();
        for (int stp = 64; stp >= 1; stp >>= 1) {
            if (t < stp) {
                if (sv2[t + stp] > sv2[t] ||
                    (sv2[t + stp] == sv2[t] && si2[t + stp] < si2[t])) {
                    sv2[t] = sv2[t + stp];
                    si2[t] = si2[t + stp];
                }
            }
            __syncthreads();
        }
        if (t == 0) { top[b * NSEL + j] = si2[0]; used[si2[0]] = 1; }
        __syncthreads();
    }
}

// ---------------------------------------------------------------------------
// Attention (MFMA, f16 I/O): block = 4 waves, one (b,h,64-query tile).
// ---------------------------------------------------------------------------
#define QT 64
#define KROWS 96   // QT + 2*WIN
#define KST2 72    // K/sK row stride in halves (144 B)
#define VST 136    // Vt row stride in halves
#define PST 136    // P row stride in halves

__global__ __launch_bounds__(256) void attn_mfma(
    const f16* __restrict__ qkv, const f16* __restrict__ sqkv,
    f16* __restrict__ attn)
{
    __shared__ f16 Kl[KROWS][KST2];      // 13824 B
    __shared__ f16 sKl[NSEL][KST2];      //  2304 B
    __shared__ f16 Vt[DH][VST];          // 17408 B  (cols: 0..95 win, 96..111 sel, 112..127 zero)
    __shared__ f16 Pl[4][16][PST];       // 17408 B  per-wave P[q16][kv128]

    int bid = blockIdx.x;
    bid = (bid & 7) * (gridDim.x >> 3) + (bid >> 3);   // XCD swizzle (1024%8==0)
    const int t = bid & 31;
    const int h = (bid >> 5) & (HH - 1);
    const int b = bid >> 9;
    const int s0 = t * QT;

    const int tid = threadIdx.x;
    const int wid = tid >> 6, lane = tid & 63;
    const int l15 = lane & 15, lg = lane >> 4;

    // ---- stage K rows + V transposed ----
    for (int i = tid; i < KROWS * 8; i += 256) {
        const int row = i >> 3, c8 = (i & 7) * 8;
        const int pos = s0 - WIN + row;
        f16x8 kv, vv;
#pragma unroll
        for (int u = 0; u < 8; ++u) { kv[u] = (f16)0.f; vv[u] = (f16)0.f; }
        if (pos >= 0 && pos < SS) {
            const f16* base = qkv + (size_t)(b * SS + pos) * (3 * DD) + h * DH + c8;
            kv = *(const f16x8*)(base + DD);
            vv = *(const f16x8*)(base + 2 * DD);
        }
        *(f16x8*)&Kl[row][c8] = kv;
#pragma unroll
        for (int u = 0; u < 8; ++u) Vt[c8 + u][row] = vv[u];
    }
    // ---- stage sel K/V ----
    if (tid < NSEL * 8) {
        const int si = tid >> 3, c8 = (tid & 7) * 8;
        const f16* base = sqkv + (size_t)(b * NSEL + si) * (3 * DD) + h * DH + c8;
        f16x8 kv = *(const f16x8*)(base + DD);
        f16x8 vv = *(const f16x8*)(base + 2 * DD);
        *(f16x8*)&sKl[si][c8] = kv;
#pragma unroll
        for (int u = 0; u < 8; ++u) Vt[c8 + u][96 + si] = vv[u];
    }
    // ---- zero Vt kv columns 112..127 ----
    for (int i = tid; i < DH * 16; i += 256)
        Vt[i >> 4][112 + (i & 15)] = (f16)0.f;

    // ---- Q fragments: raw f16x8 loads ----
    f16x8 qf[2];
    {
        const f16* qp = qkv + (size_t)(b * SS + s0 + wid * 16 + l15) * (3 * DD)
                      + h * DH + lg * 8;
        qf[0] = *(const f16x8*)(qp);
        qf[1] = *(const f16x8*)(qp + 32);
    }
    __syncthreads();

    // ---- QK^T swapped: D[kv][q] ----
    f32x4 aqk[6], asel;
#pragma unroll
    for (int i = 0; i < 6; ++i) aqk[i] = (f32x4){0.f, 0.f, 0.f, 0.f};
    asel = (f32x4){0.f, 0.f, 0.f, 0.f};
#pragma unroll
    for (int kc = 0; kc < 2; ++kc) {
        const int ko = kc * 32 + lg * 8;
#pragma unroll
        for (int kvb = 0; kvb < 6; ++kvb) {
            f16x8 ka = *(const f16x8*)&Kl[kvb * 16 + l15][ko];
            aqk[kvb] = __builtin_amdgcn_mfma_f32_16x16x32_f16(ka, qf[kc], aqk[kvb], 0, 0, 0);
        }
        f16x8 ks = *(const f16x8*)&sKl[l15][ko];
        asel = __builtin_amdgcn_mfma_f32_16x16x32_f16(ks, qf[kc], asel, 0, 0, 0);
    }

    // ---- local softmax ----
    const int qt_ = wid * 16 + l15;
    float sc[6][4];
    float m = -INFINITY;
#pragma unroll
    for (int kvb = 0; kvb < 6; ++kvb)
#pragma unroll
        for (int r = 0; r < 4; ++r) {
            const int kv  = kvb * 16 + lg * 4 + r;
            const int pos = s0 - WIN + kv;
            const int dlt = kv - qt_;
            const bool ok = (dlt >= 0) & (dlt <= 32) & (pos >= 0) & (pos < SS);
            sc[kvb][r] = ok ? aqk[kvb][r] * SCALE : -INFINITY;
            m = fmaxf(m, sc[kvb][r]);
        }
    m = fmaxf(m, __shfl_xor(m, 16));
    m = fmaxf(m, __shfl_xor(m, 32));
    float sum = 0.f;
#pragma unroll
    for (int kvb = 0; kvb < 6; ++kvb)
#pragma unroll
        for (int r = 0; r < 4; ++r) {
            sc[kvb][r] = __expf(sc[kvb][r] - m);
            sum += sc[kvb][r];
        }
    sum += __shfl_xor(sum, 16);
    sum += __shfl_xor(sum, 32);
    const float inv1 = 1.f / sum;

    // ---- sel softmax ----
    float s2[4];
    float m2 = -INFINITY;
#pragma unroll
    for (int r = 0; r < 4; ++r) { s2[r] = asel[r] * SCALE; m2 = fmaxf(m2, s2[r]); }
    m2 = fmaxf(m2, __shfl_xor(m2, 16));
    m2 = fmaxf(m2, __shfl_xor(m2, 32));
    float sum2 = 0.f;
#pragma unroll
    for (int r = 0; r < 4; ++r) { s2[r] = __expf(s2[r] - m2); sum2 += s2[r]; }
    sum2 += __shfl_xor(sum2, 16);
    sum2 += __shfl_xor(sum2, 32);
    const float inv2 = 1.f / sum2;

    // ---- write P (pre-normalized); Pl is wave-private -> no barrier ----
#pragma unroll
    for (int kvb = 0; kvb < 6; ++kvb) {
        h2 p01, p23;
        p01[0] = (f16)(sc[kvb][0] * inv1); p01[1] = (f16)(sc[kvb][1] * inv1);
        p23[0] = (f16)(sc[kvb][2] * inv1); p23[1] = (f16)(sc[kvb][3] * inv1);
        *(h2*)&Pl[wid][l15][kvb * 16 + lg * 4]     = p01;
        *(h2*)&Pl[wid][l15][kvb * 16 + lg * 4 + 2] = p23;
    }
    {
        h2 g01, g23, z0;
        g01[0] = (f16)(s2[0] * inv2); g01[1] = (f16)(s2[1] * inv2);
        g23[0] = (f16)(s2[2] * inv2); g23[1] = (f16)(s2[3] * inv2);
        z0[0] = (f16)0.f; z0[1] = (f16)0.f;
        *(h2*)&Pl[wid][l15][96 + lg * 4]      = g01;
        *(h2*)&Pl[wid][l15][96 + lg * 4 + 2]  = g23;
        *(h2*)&Pl[wid][l15][112 + lg * 4]     = z0;
        *(h2*)&Pl[wid][l15][112 + lg * 4 + 2] = z0;
    }

    // ---- PV: O[q][d] = P[q][kv] . Vt[d][kv] ----
    f32x4 ov[4];
#pragma unroll
    for (int i = 0; i < 4; ++i) ov[i] = (f32x4){0.f, 0.f, 0.f, 0.f};
#pragma unroll
    for (int kc = 0; kc < 4; ++kc) {
        const int ko = kc * 32 + lg * 8;
        f16x8 pa = *(const f16x8*)&Pl[wid][l15][ko];
#pragma unroll
        for (int db = 0; db < 4; ++db) {
            f16x8 vb = *(const f16x8*)&Vt[db * 16 + l15][ko];
            ov[db] = __builtin_amdgcn_mfma_f32_16x16x32_f16(pa, vb, ov[db], 0, 0, 0);
        }
    }

    // ---- store O ----
    const size_t rbase = (size_t)(b * SS + s0 + wid * 16 + lg * 4);
#pragma unroll
    for (int r = 0; r < 4; ++r) {
        f16* op = attn + (rbase + r) * DD + h * DH + l15;
#pragma unroll
        for (int db = 0; db < 4; ++db)
            op[db * 16] = (f16)ov[db][r];
    }
}

extern "C" void kernel_launch(void* const* d_in, const int* in_sizes, int n_in,
                              void* d_out, int out_size, void* d_ws, size_t ws_size,
                              hipStream_t stream)
{
    const float* x       = (const float*)d_in[0];
    const float* qkv_w   = (const float*)d_in[1];
    const float* qkv_b   = (const float*)d_in[2];
    const float* c1_w    = (const float*)d_in[3];
    const float* c1_b    = (const float*)d_in[4];
    const float* c2_w    = (const float*)d_in[5];
    const float* c2_b    = (const float*)d_in[6];
    const float* score_w = (const float*)d_in[7];
    const float* score_b = (const float*)d_in[8];
    const float* out_w   = (const float*)d_in[9];
    const float* out_b   = (const float*)d_in[10];
    float* out = (float*)d_out;
    float* ws  = (float*)d_ws;
    (void)score_b;   // rank-invariant constant (c2_b.score_w + score_b) dropped

    // workspace layout (float units)
    f16*   xh      = (f16*)ws;                   // 4096x1024 halves
    float* A1      = ws + 2097152;
    f16*   qkvb    = (f16*)A1;                   // 4096x3072 halves
    f16*   attnf   = (f16*)(A1 + 12582912);      // 4096x1024 halves
    float* A2      = ws + 18874368;              // 4,161,536 floats scratch
    float* part    = A2;
    f16*   qkv_wT  = (f16*)A2;                   // alias (partials dead first)
    f16*   out_wT  = (f16*)(A2 + 1572864);
    float* hidden  = ws + 23035904;              // 260,096
    float* scores  = hidden + 260096;            // 256
    int*   topIdx  = (int*)(scores + 256);       // 32 ints
    float* sqkvb   = scores + 256 + 64;          // f16 region, 49,152 floats
    float* w2s     = sqkvb + 49152;              // 1024
    float* compSel = w2s + 1024;                 // 32 x 1024 fp32

    const int MROWS = BB * SS;        // 4096
    const int MSEL  = BB * NSEL;      // 32

    // 0. x -> f16
    convert_f16<<<(MROWS * DD) / (256 * 4), 256, 0, stream>>>(x, xh, MROWS * DD);

    // 1. c1: hidden partials via f16 MFMA, split-K 16; B transpose fused
    gemm_c1<<<dim3(DD / 64, 2, C1_NZ), 256, 0, stream>>>(xh, c1_w, part);

    // 2. hidden = relu(sum partials + c1_b)  [fp32]
    reduce_partials<<<(MC * DD) / 256, 256, 0, stream>>>(
        part, c1_b, hidden, MC * DD, DD, C1_NZ, 1, 0);

    // 3. w2s = c2_w @ score_w  (row-dots; fixes round-8's transposed bug)
    w2s_kernel<<<DD, 256, 0, stream>>>(c2_w, score_w, w2s);

    // 4. scores = hidden @ w2s  (constant offset dropped; rank-invariant)
    score2_kernel<<<MC, 256, 0, stream>>>(hidden, w2s, scores);

    // 5. top-16 per batch
    topk_kernel<<<BB, 128, 0, stream>>>(scores, topIdx);

    // 6. compSel partials: hidden[sel] @ c2_w  (32 x 1024, K=1024, split-K 16)
    gemm128<2><<<dim3(DD / 128, 1, 16), 256, 0, stream>>>(
        hidden, c2_w, nullptr, part, MSEL, DD, DD, topIdx, 0);

    // 6b. compSel = sum partials + c2_b  [fp32]
    reduce_partials<<<(MSEL * DD) / 256, 256, 0, stream>>>(
        part, c2_b, compSel, MSEL * DD, DD, 16, 0, 0);

    // 7. sqkv partials: compSel @ qkv_w  (32 x 3072, K=1024, split-K 16)
    gemm128<0><<<dim3(3 * DD / 128, 1, 16), 256, 0, stream>>>(
        compSel, qkv_w, nullptr, part, MSEL, 3 * DD, DD, nullptr, 0);

    // 7b. sqkv = sum partials + qkv_b  [f16]
    reduce_partials<<<(MSEL * 3 * DD + 255) / 256, 256, 0, stream>>>(
        part, qkv_b, sqkvb, MSEL * 3 * DD, 3 * DD, 16, 0, 1);

    // 8. weight transposes (A2 partials now dead)
    transpose_conv<<<dim3(3 * DD / 32, DD / 32), 256, 0, stream>>>(
        qkv_w, qkv_wT, DD, 3 * DD);
    transpose_conv<<<dim3(DD / 32, DD / 32), 256, 0, stream>>>(
        out_w, out_wT, DD, DD);

    // 9. qkv = x @ qkv_w + qkv_b  [f16 MFMA, f16 out, XCD-swizzled]
    gemm_f16<1><<<dim3(3 * DD / 128, MROWS / 128), 256, 0, stream>>>(
        xh, qkv_wT, qkv_b, (float*)qkvb, MROWS, 3 * DD, DD);

    // 10. attention on matrix cores (f16 I/O)
    attn_mfma<<<BB * HH * (SS / QT), 256, 0, stream>>>(
        qkvb, (const f16*)sqkvb, attnf);

    // 11. out = attn @ out_w + out_b  [f16 MFMA, fp32 out, XCD-swizzled]
    gemm_f16<0><<<dim3(DD / 128, MROWS / 128), 256, 0, stream>>>(
        attnf, out_wT, out_b, out, MROWS, DD, DD);
}